// Round 13
// baseline (515.233 us; speedup 1.0000x reference)
//
#include <hip/hip_runtime.h>
#include <hip/hip_fp16.h>

#define FIN 64
#define HID 256
#define DEMB 128
#define NLAYERS 3

typedef __attribute__((ext_vector_type(8))) short bf16x8;
typedef __attribute__((ext_vector_type(4))) float f32x4;

__device__ inline short f2bf(float x) {               // RNE fp32 -> bf16 bits
    unsigned u = __float_as_uint(x);
    u += 0x7fff + ((u >> 16) & 1);
    return (short)(u >> 16);
}
__device__ inline float bf2f(short h) {
    return __uint_as_float(((unsigned)(unsigned short)h) << 16);
}

// Activation layout "hpack": per row r, 256 fp16 (512B contiguous), linear cols.
// Values PRE-SCALED by dinv[row] except after the last layer.

// add 8 fp16 cols (uint4) into fp32 acc[8]
#define HADD8(V) do { \
    __half2 p0 = *(__half2*)&(V).x, p1 = *(__half2*)&(V).y; \
    __half2 p2 = *(__half2*)&(V).z, p3 = *(__half2*)&(V).w; \
    float2 f0 = __half22float2(p0), f1 = __half22float2(p1); \
    float2 f2 = __half22float2(p2), f3 = __half22float2(p3); \
    acc[0] += f0.x; acc[1] += f0.y; acc[2] += f1.x; acc[3] += f1.y; \
    acc[4] += f2.x; acc[5] += f2.y; acc[6] += f3.x; acc[7] += f3.y; } while (0)

__device__ inline void split2(float a0, float a1, float a2, float a3, uint2& hw, uint2& lw) {
    short h0 = f2bf(a0), h1 = f2bf(a1), h2 = f2bf(a2), h3 = f2bf(a3);
    short l0 = f2bf(a0 - bf2f(h0)), l1 = f2bf(a1 - bf2f(h1));
    short l2 = f2bf(a2 - bf2f(h2)), l3 = f2bf(a3 - bf2f(h3));
    hw.x = (unsigned short)h0 | ((unsigned)(unsigned short)h1 << 16);
    hw.y = (unsigned short)h2 | ((unsigned)(unsigned short)h3 << 16);
    lw.x = (unsigned short)l0 | ((unsigned)(unsigned short)l1 << 16);
    lw.y = (unsigned short)l2 | ((unsigned)(unsigned short)l3 << 16);
}

// ---------------- small graph-prep kernels ----------------

__global__ __launch_bounds__(256) void zero_kernel(int* counts, int n, float* pool_sum, int* pool_max) {
    int i = blockIdx.x * 256 + threadIdx.x;
    if (i < n) counts[i] = 0;
    if (i < HID) { pool_sum[i] = 0.0f; pool_max[i] = 0; }
}

__global__ __launch_bounds__(256) void hist_kernel(const int* __restrict__ ei, int E, int* __restrict__ counts) {
    int e = blockIdx.x * 256 + threadIdx.x;
    if (e < E) atomicAdd(&counts[ei[E + e]], 1);
}

__global__ __launch_bounds__(256) void scan_partial(const int* __restrict__ counts, int n,
                                                    int* __restrict__ chunkSums, float* __restrict__ dinv) {
    __shared__ int s[256];
    int t = threadIdx.x, base = blockIdx.x * 1024;
    int sum = 0;
#pragma unroll
    for (int j = 0; j < 4; j++) {
        int i = base + t * 4 + j;
        if (i < n) {
            int c = counts[i];
            sum += c;
            dinv[i] = rsqrtf((float)(c + 1));
        }
    }
    s[t] = sum; __syncthreads();
    for (int off = 128; off > 0; off >>= 1) { if (t < off) s[t] += s[t + off]; __syncthreads(); }
    if (t == 0) chunkSums[blockIdx.x] = s[0];
}

__global__ void scan_sums(int* cs, int nch) {
    int l = threadIdx.x;
    int orig = (l < nch) ? cs[l] : 0;
    int v = orig;
    for (int off = 1; off < 64; off <<= 1) {
        int x = __shfl_up(v, off, 64);
        if (l >= off) v += x;
    }
    if (l < nch) cs[l] = v - orig;
}

__global__ __launch_bounds__(256) void scan_final(const int* __restrict__ counts, int n,
                                                  const int* __restrict__ chunkOff, int* __restrict__ row_ptr,
                                                  int* __restrict__ cursor) {
    __shared__ int s[256];
    int t = threadIdx.x, base = blockIdx.x * 1024;
    int v[4]; int sum = 0;
#pragma unroll
    for (int j = 0; j < 4; j++) { int i = base + t * 4 + j; v[j] = (i < n) ? counts[i] : 0; sum += v[j]; }
    s[t] = sum; __syncthreads();
    for (int off = 1; off < 256; off <<= 1) {
        int x = (t >= off) ? s[t - off] : 0;
        __syncthreads();
        s[t] += x;
        __syncthreads();
    }
    int run = chunkOff[blockIdx.x] + (s[t] - sum);
#pragma unroll
    for (int j = 0; j < 4; j++) {
        int i = base + t * 4 + j;
        if (i < n) {
            row_ptr[i] = run; cursor[i] = run; run += v[j];
            if (i == n - 1) row_ptr[n] = run;
        }
    }
}

__global__ __launch_bounds__(256) void fill_kernel(const int* __restrict__ ei, int E,
                                                   int* __restrict__ cursor, int* __restrict__ adj) {
    int e = blockIdx.x * 256 + threadIdx.x;
    if (e < E) {
        int s = ei[e], d = ei[E + e];
        int p = atomicAdd(&cursor[d], 1);
        adj[p] = s;
    }
}

// ---------------- weight packing (slab-major bf16 split) ----------------

__global__ __launch_bounds__(256) void pack_all(const float* __restrict__ W1, const float* __restrict__ W2,
                                                const float* __restrict__ Wc,
                                                short* __restrict__ PH, short* __restrict__ PL) {
    int b = blockIdx.x, n = threadIdx.x;
    const float* src; int k; size_t dst;
    if (b < 64) { src = W1; k = b; dst = 0; }
    else {
        int m = (b - 64) >> 8; k = (b - 64) & 255;
        src = (m == 0) ? W2 : (Wc + (size_t)(m - 1) * 65536);
        dst = 16384 + (size_t)m * 65536;
    }
    float w = src[(size_t)k * 256 + n];
    short h = f2bf(w);
    short l = f2bf(w - bf2f(h));
    int o = ((k >> 3) * 256 + n) * 8 + (k & 7);
    PH[dst + o] = h; PL[dst + o] = l;
}

// ---------------- fused encoder: out = hpack(dinv * (relu(x@W1+b1)@W2 + b2)) --
// BM=32 rows/block, 4 waves. LDS aliased LB[16896] shorts.

__global__ __launch_bounds__(256) void encoder_fused(const float* __restrict__ x,
                                                     const short* __restrict__ PB1h, const short* __restrict__ PB1l,
                                                     const short* __restrict__ PB2h, const short* __restrict__ PB2l,
                                                     const float* __restrict__ b1, const float* __restrict__ b2,
                                                     const float* __restrict__ dinv,
                                                     short* __restrict__ Aout, int n) {
    __shared__ short LB[16896];
    int t = threadIdx.x, lane = t & 63, wv = t >> 6;
    int lr = lane & 15, lg = lane >> 4;
    int brow = blockIdx.x * 32;
    int bcol = wv * 64;

    // ---- stage 1 load: x tile 32x64 -> split-bf16 A frags ----
#pragma unroll
    for (int l = 0; l < 2; l++) {
        int lin = t + l * 256;
        int r = lin >> 4, kq = (lin & 15) * 4;
        int row = brow + r;
        float4 v = (row < n) ? *(const float4*)(x + (size_t)row * FIN + kq)
                             : make_float4(0.f, 0.f, 0.f, 0.f);
        uint2 hw, lw; split2(v.x, v.y, v.z, v.w, hw, lw);
        int g = kq >> 3, i0 = kq & 7;
        *(uint2*)&LB[(g * 33 + r) * 8 + i0] = hw;
        *(uint2*)&LB[2112 + (g * 33 + r) * 8 + i0] = lw;
    }
    __syncthreads();

    // ---- stage 1 MFMA: t = x@W1, K=64 ----
    f32x4 acc1[2][4] = {};
#pragma unroll
    for (int s = 0; s < 2; s++) {
        int sl = s * 4 + lg;
        bf16x8 ah[2], al[2], bh[4], bl[4];
#pragma unroll
        for (int mi = 0; mi < 2; mi++) {
            ah[mi] = *(bf16x8*)&LB[(sl * 33 + mi * 16 + lr) * 8];
            al[mi] = *(bf16x8*)&LB[2112 + (sl * 33 + mi * 16 + lr) * 8];
        }
        const short* pbh = PB1h + ((size_t)sl * 256 + bcol + lr) * 8;
        const short* pbl = PB1l + ((size_t)sl * 256 + bcol + lr) * 8;
#pragma unroll
        for (int ni = 0; ni < 4; ni++) {
            bh[ni] = *(const bf16x8*)(pbh + ni * 128);
            bl[ni] = *(const bf16x8*)(pbl + ni * 128);
        }
#pragma unroll
        for (int mi = 0; mi < 2; mi++)
#pragma unroll
            for (int ni = 0; ni < 4; ni++) {
                acc1[mi][ni] = __builtin_amdgcn_mfma_f32_16x16x32_bf16(ah[mi], bh[ni], acc1[mi][ni], 0, 0, 0);
                acc1[mi][ni] = __builtin_amdgcn_mfma_f32_16x16x32_bf16(ah[mi], bl[ni], acc1[mi][ni], 0, 0, 0);
                acc1[mi][ni] = __builtin_amdgcn_mfma_f32_16x16x32_bf16(al[mi], bh[ni], acc1[mi][ni], 0, 0, 0);
            }
    }
    __syncthreads();

    // ---- t = relu(acc1 + b1) -> split-bf16 t-frags in LDS ----
#pragma unroll
    for (int ni = 0; ni < 4; ni++) {
        int col = bcol + ni * 16 + lr;
        float bv = b1[col];
        int sl2 = col >> 3, i = col & 7;
#pragma unroll
        for (int mi = 0; mi < 2; mi++)
#pragma unroll
            for (int j = 0; j < 4; j++) {
                int r = mi * 16 + lg * 4 + j;
                float o = fmaxf(acc1[mi][ni][j] + bv, 0.f);
                short hh = f2bf(o);
                short hl = f2bf(o - bf2f(hh));
                LB[(sl2 * 33 + r) * 8 + i] = hh;
                LB[8448 + (sl2 * 33 + r) * 8 + i] = hl;
            }
    }
    __syncthreads();

    // ---- stage 2 MFMA: out = t@W2, K=256 ----
    f32x4 acc2[2][4] = {};
#pragma unroll
    for (int s = 0; s < 8; s++) {
        int sl = s * 4 + lg;
        bf16x8 ah[2], al[2], bh[4], bl[4];
#pragma unroll
        for (int mi = 0; mi < 2; mi++) {
            ah[mi] = *(bf16x8*)&LB[(sl * 33 + mi * 16 + lr) * 8];
            al[mi] = *(bf16x8*)&LB[8448 + (sl * 33 + mi * 16 + lr) * 8];
        }
        const short* pbh = PB2h + ((size_t)sl * 256 + bcol + lr) * 8;
        const short* pbl = PB2l + ((size_t)sl * 256 + bcol + lr) * 8;
#pragma unroll
        for (int ni = 0; ni < 4; ni++) {
            bh[ni] = *(const bf16x8*)(pbh + ni * 128);
            bl[ni] = *(const bf16x8*)(pbl + ni * 128);
        }
#pragma unroll
        for (int mi = 0; mi < 2; mi++)
#pragma unroll
            for (int ni = 0; ni < 4; ni++) {
                acc2[mi][ni] = __builtin_amdgcn_mfma_f32_16x16x32_bf16(ah[mi], bh[ni], acc2[mi][ni], 0, 0, 0);
                acc2[mi][ni] = __builtin_amdgcn_mfma_f32_16x16x32_bf16(ah[mi], bl[ni], acc2[mi][ni], 0, 0, 0);
                acc2[mi][ni] = __builtin_amdgcn_mfma_f32_16x16x32_bf16(al[mi], bh[ni], acc2[mi][ni], 0, 0, 0);
            }
    }
    __syncthreads();

    // ---- epilogue: dinv * (acc2 + b2) -> fp16 tile [32][256] in LDS ----
    float dvo[2][4];
#pragma unroll
    for (int mi = 0; mi < 2; mi++)
#pragma unroll
        for (int j = 0; j < 4; j++) {
            int row = brow + mi * 16 + lg * 4 + j;
            dvo[mi][j] = (row < n) ? dinv[row] : 0.f;
        }
#pragma unroll
    for (int ni = 0; ni < 4; ni++) {
        int col = bcol + ni * 16 + lr;
        float bv = b2[col];
#pragma unroll
        for (int mi = 0; mi < 2; mi++)
#pragma unroll
            for (int j = 0; j < 4; j++) {
                int r = mi * 16 + lg * 4 + j;
                float o = (acc2[mi][ni][j] + bv) * dvo[mi][j];
                *(__half*)&LB[r * 256 + col] = __float2half_rn(o);
            }
    }
    __syncthreads();

    // ---- cooperative write-out: 1024 x 16B chunks (512B/row) ----
#pragma unroll
    for (int q = 0; q < 4; q++) {
        int idx = t + q * 256;          // [0,1024)
        int row = idx >> 5, c = idx & 31;
        int vv = brow + row;
        if (vv < n)
            *(uint4*)(Aout + (size_t)vv * 256 + c * 8) = *(const uint4*)&LB[row * 256 + c * 8];
    }
}

// ---------------- fused GCN layer: out = relu((S@h)@Wc + b) -------------------
// Input hpack fp16 PRE-SCALED by dinv => gather is a pure fp16 row sum.
// BM=16 rows/block, 4 waves. DUAL-EDGE gather: 32-lane halves process alternate
// edges, 16B (8-col uint4) per lane -> 2 rows fetched per wave-step, 8-deep
// (16 edges / 8KB in flight per wave). Halves combined via shfl_xor(32).
// LDS aliased: bf16 A-frags (8704 sh) / fp16 out tile (4096 sh).

template<bool SCALE_OUT>
__global__ __launch_bounds__(256) void layer_fused(const short* __restrict__ Ain,
                                                   const int* __restrict__ row_ptr, const int* __restrict__ adj,
                                                   const float* __restrict__ dinv,
                                                   const short* __restrict__ PBh, const short* __restrict__ PBl,
                                                   const float* __restrict__ bias,
                                                   short* __restrict__ Aout, int n) {
    __shared__ short LB[8704];
    int t = threadIdx.x, lane = t & 63, wv = t >> 6;
    int lr = lane & 15, lg = lane >> 4;
    int brow = blockIdx.x * 16;
    int half = lane >> 5;           // 0|1 : even|odd edges
    int c8 = lane & 31;             // col-octet = k-slab
    int boff = c8 * 8;              // fp16 col base (8 cols/lane)

    // ---- phase 1: gather + sum (each wave: 4 dst rows) ----
    for (int it = 0; it < 4; ++it) {
        int r = wv * 4 + it, v = brow + r;
        if (v >= n) break;                          // wave-uniform
        float dv = dinv[v];
        float acc[8] = {};
        if (half == 0) {                            // self row (once)
            uint4 V0 = *(const uint4*)(Ain + (size_t)v * 256 + boff);
            HADD8(V0);
        }
        int e = row_ptr[v], end = row_ptr[v + 1];
        for (; e + 16 <= end; e += 16) {            // 8 pairs in flight
            int s8[8]; uint4 V[8];
#pragma unroll
            for (int j = 0; j < 8; j++) s8[j] = adj[e + 2 * j + half];
#pragma unroll
            for (int j = 0; j < 8; j++) V[j] = *(const uint4*)(Ain + (size_t)s8[j] * 256 + boff);
#pragma unroll
            for (int j = 0; j < 8; j++) HADD8(V[j]);
        }
        for (; e + 8 <= end; e += 8) {              // 4 pairs
            int s4[4]; uint4 V[4];
#pragma unroll
            for (int j = 0; j < 4; j++) s4[j] = adj[e + 2 * j + half];
#pragma unroll
            for (int j = 0; j < 4; j++) V[j] = *(const uint4*)(Ain + (size_t)s4[j] * 256 + boff);
#pragma unroll
            for (int j = 0; j < 4; j++) HADD8(V[j]);
        }
        for (; e + 2 <= end; e += 2) {              // 1 pair
            uint4 V = *(const uint4*)(Ain + (size_t)adj[e + half] * 256 + boff);
            HADD8(V);
        }
        if (e < end && half == 0) {                 // odd tail edge
            uint4 V = *(const uint4*)(Ain + (size_t)adj[e] * 256 + boff);
            HADD8(V);
        }
        // combine halves (lane i <-> i+32 hold same cols, disjoint edges)
#pragma unroll
        for (int k = 0; k < 8; k++) acc[k] += __shfl_xor(acc[k], 32);
        // split to bf16 h/l; lane's 8 cols = slab c8 -> one uint4 each
        uint2 hw0, lw0, hw1, lw1;
        split2(dv * acc[0], dv * acc[1], dv * acc[2], dv * acc[3], hw0, lw0);
        split2(dv * acc[4], dv * acc[5], dv * acc[6], dv * acc[7], hw1, lw1);
        if (half == 0) {
            uint4 hq = make_uint4(hw0.x, hw0.y, hw1.x, hw1.y);
            uint4 lq = make_uint4(lw0.x, lw0.y, lw1.x, lw1.y);
            *(uint4*)&LB[(c8 * 17 + r) * 8] = hq;
            *(uint4*)&LB[4352 + (c8 * 17 + r) * 8] = lq;
        }
    }
    __syncthreads();

    // ---- phase 2: 3-term MFMA, wave wv -> cols [wv*64, wv*64+64) ----
    int bcol = wv * 64;
    f32x4 acc2[4] = {};
#pragma unroll
    for (int s = 0; s < 8; ++s) {
        int sl = s * 4 + lg;
        bf16x8 ah = *(bf16x8*)&LB[(sl * 17 + lr) * 8];
        bf16x8 al = *(bf16x8*)&LB[4352 + (sl * 17 + lr) * 8];
        const short* pbh = PBh + ((size_t)sl * 256 + bcol + lr) * 8;
        const short* pbl = PBl + ((size_t)sl * 256 + bcol + lr) * 8;
        bf16x8 bh[4], bl[4];
#pragma unroll
        for (int ni = 0; ni < 4; ni++) {
            bh[ni] = *(const bf16x8*)(pbh + ni * 128);
            bl[ni] = *(const bf16x8*)(pbl + ni * 128);
        }
#pragma unroll
        for (int ni = 0; ni < 4; ni++) {
            acc2[ni] = __builtin_amdgcn_mfma_f32_16x16x32_bf16(ah, bh[ni], acc2[ni], 0, 0, 0);
            acc2[ni] = __builtin_amdgcn_mfma_f32_16x16x32_bf16(ah, bl[ni], acc2[ni], 0, 0, 0);
            acc2[ni] = __builtin_amdgcn_mfma_f32_16x16x32_bf16(al, bh[ni], acc2[ni], 0, 0, 0);
        }
    }
    __syncthreads();   // all LDS A-frag reads done; safe to reuse buffer

    // ---- epilogue: relu(acc+bias) [*dinv] -> fp16 tile [16][256] in LDS ----
    float dvo[4];
    if (SCALE_OUT) {
#pragma unroll
        for (int j = 0; j < 4; j++) {
            int row = brow + lg * 4 + j;
            dvo[j] = (row < n) ? dinv[row] : 0.f;
        }
    }
#pragma unroll
    for (int ni = 0; ni < 4; ni++) {
        int col = bcol + ni * 16 + lr;
        float bv = bias[col];
#pragma unroll
        for (int j = 0; j < 4; j++) {
            int r = lg * 4 + j;
            float o = fmaxf(acc2[ni][j] + bv, 0.f);
            if (SCALE_OUT) o *= dvo[j];
            *(__half*)&LB[r * 256 + col] = __float2half_rn(o);
        }
    }
    __syncthreads();

    // ---- cooperative write-out: 512 x 16B chunks (512B/row) ----
#pragma unroll
    for (int q = 0; q < 2; q++) {
        int idx = t + q * 256;          // [0,512)
        int row = idx >> 5, c = idx & 31;
        int vv = brow + row;
        if (vv < n)
            *(uint4*)(Aout + (size_t)vv * 256 + c * 8) = *(const uint4*)&LB[row * 256 + c * 8];
    }
}

// ---------------- pooling (mean + max over rows) from hpack fp16 --------------

__global__ __launch_bounds__(256) void pool_packed(const short* __restrict__ P, int n,
                                                   float* __restrict__ pool_sum, int* __restrict__ pool_max) {
    int t = threadIdx.x;   // column
    int chunk = (n + gridDim.x - 1) / gridDim.x;
    int r0 = blockIdx.x * chunk, r1 = min(n, r0 + chunk);
    float s = 0.f, mx = 0.f;
    for (int r = r0; r < r1; r++) {
        float v = __half2float(*(const __half*)&P[(size_t)r * 256 + t]);
        s += v;
        mx = fmaxf(mx, v);
    }
    atomicAdd(&pool_sum[t], s);
    atomicMax(&pool_max[t], __float_as_int(mx));
}

// ---------------- final MLP head (single block) ----------------

__global__ __launch_bounds__(256) void mlp_head(const float* __restrict__ pool_sum, const int* __restrict__ pool_max,
                                                const float* __restrict__ Wp1, const float* __restrict__ bp1,
                                                const float* __restrict__ Wp2, const float* __restrict__ bp2,
                                                float* __restrict__ out, float invn) {
    __shared__ float g[2 * HID];
    __shared__ float hid[HID];
    int t = threadIdx.x;
    g[t] = pool_sum[t] * invn;
    g[HID + t] = __int_as_float(pool_max[t]);
    __syncthreads();
    float acc = bp1[t];
#pragma unroll 8
    for (int j = 0; j < 2 * HID; j++) acc = fmaf(g[j], Wp1[j * HID + t], acc);
    hid[t] = fmaxf(acc, 0.f);
    __syncthreads();
    if (t < DEMB) {
        float a2 = bp2[t];
#pragma unroll 8
        for (int j = 0; j < HID; j++) a2 = fmaf(hid[j], Wp2[j * DEMB + t], a2);
        out[t] = a2;
    }
}

// ---------------- launcher ----------------

extern "C" void kernel_launch(void* const* d_in, const int* in_sizes, int n_in,
                              void* d_out, int out_size, void* d_ws, size_t ws_size,
                              hipStream_t stream) {
    const float* x   = (const float*)d_in[0];
    const int*   ei  = (const int*)d_in[1];
    const float* W1  = (const float*)d_in[2];
    const float* b1  = (const float*)d_in[3];
    const float* W2  = (const float*)d_in[4];
    const float* b2  = (const float*)d_in[5];
    const float* Wc  = (const float*)d_in[6];
    const float* bc  = (const float*)d_in[7];
    const float* Wp1 = (const float*)d_in[8];
    const float* bp1 = (const float*)d_in[9];
    const float* Wp2 = (const float*)d_in[10];
    const float* bp2 = (const float*)d_in[11];
    float* out = (float*)d_out;

    int N = in_sizes[0] / FIN;
    int E = in_sizes[1] / 2;
    int nb32 = (N + 31) / 32;
    int nb16 = (N + 15) / 16;
    int R = nb32 * 32;                   // padded rows for hpack buffers

    char* base = (char*)d_ws;
    short* actA = (short*)base;                          // [R,256] fp16 hpack
    short* actB = (short*)(base + (size_t)R * 512);      // [R,256] fp16 hpack
    int*   counts  = (int*)(base + 2 * (size_t)R * 512); // [N]
    int*   row_ptr = counts + N;                         // [N+1]
    int*   cursor  = row_ptr + (N + 1);                  // [N]
    int*   adj     = cursor + N;                         // [E]
    float* dinvp   = (float*)(adj + E);                  // [N]
    float* pool_sum = dinvp + N;                         // [HID]
    int*   pool_max = (int*)(pool_sum + HID);            // [HID]
    int*   chunkSums = pool_max + HID;                   // [<=64]
    short* PH = (short*)((((uintptr_t)(chunkSums + 64)) + 15) & ~(uintptr_t)15);
    short* PL = PH + 278528;
    const int oW1 = 0, oW2 = 16384, oC0 = 81920, oC1 = 147456, oC2 = 212992;

    int nch = (N + 1023) / 1024;
    int nb256 = (N + 255) / 256;
    int eb256 = (E + 255) / 256;

    zero_kernel<<<nb256, 256, 0, stream>>>(counts, N, pool_sum, pool_max);
    hist_kernel<<<eb256, 256, 0, stream>>>(ei, E, counts);
    scan_partial<<<nch, 256, 0, stream>>>(counts, N, chunkSums, dinvp);
    scan_sums<<<1, 64, 0, stream>>>(chunkSums, nch);
    scan_final<<<nch, 256, 0, stream>>>(counts, N, chunkSums, row_ptr, cursor);
    fill_kernel<<<eb256, 256, 0, stream>>>(ei, E, cursor, adj);

    pack_all<<<64 + 4 * 256, 256, 0, stream>>>(W1, W2, Wc, PH, PL);

    // fused encoder: actA = hpack(dinv * (relu(x@W1+b1)@W2 + b2))
    encoder_fused<<<nb32, 256, 0, stream>>>(x, PH + oW1, PL + oW1, PH + oW2, PL + oW2,
                                            b1, b2, dinvp, actA, N);

    // fused GCN layers: out = relu((S@h)@Wc + bc); pre-scaled except last
    layer_fused<true><<<nb16, 256, 0, stream>>>(actA, row_ptr, adj, dinvp, PH + oC0, PL + oC0, bc + 0 * HID, actB, N);
    layer_fused<true><<<nb16, 256, 0, stream>>>(actB, row_ptr, adj, dinvp, PH + oC1, PL + oC1, bc + 1 * HID, actA, N);
    layer_fused<false><<<nb16, 256, 0, stream>>>(actA, row_ptr, adj, dinvp, PH + oC2, PL + oC2, bc + 2 * HID, actB, N);

    // pooling + head
    pool_packed<<<256, 256, 0, stream>>>(actB, N, pool_sum, pool_max);
    mlp_head<<<1, 256, 0, stream>>>(pool_sum, pool_max, Wp1, bp1, Wp2, bp2, out, 1.0f / (float)N);
}

// Round 14
// 481.998 us; speedup vs baseline: 1.0690x; 1.0690x over previous
//
#include <hip/hip_runtime.h>
#include <hip/hip_fp16.h>

#define FIN 64
#define HID 256
#define DEMB 128
#define NLAYERS 3

typedef __attribute__((ext_vector_type(8))) short bf16x8;
typedef __attribute__((ext_vector_type(4))) float f32x4;

__device__ inline short f2bf(float x) {               // RNE fp32 -> bf16 bits
    unsigned u = __float_as_uint(x);
    u += 0x7fff + ((u >> 16) & 1);
    return (short)(u >> 16);
}
__device__ inline float bf2f(short h) {
    return __uint_as_float(((unsigned)(unsigned short)h) << 16);
}

// Activation layout "hpack": per row r, 256 fp16 (512B contiguous), linear cols.
// Values PRE-SCALED by dinv[row] except after the last layer.

// add 4 fp16 cols (uint2) into fp32 acc
#define HADD(V) do { \
    __half2 p0 = *(__half2*)&(V).x, p1 = *(__half2*)&(V).y; \
    float2 f0 = __half22float2(p0), f1 = __half22float2(p1); \
    acc.x += f0.x; acc.y += f0.y; acc.z += f1.x; acc.w += f1.y; } while (0)

__device__ inline void split2(float a0, float a1, float a2, float a3, uint2& hw, uint2& lw) {
    short h0 = f2bf(a0), h1 = f2bf(a1), h2 = f2bf(a2), h3 = f2bf(a3);
    short l0 = f2bf(a0 - bf2f(h0)), l1 = f2bf(a1 - bf2f(h1));
    short l2 = f2bf(a2 - bf2f(h2)), l3 = f2bf(a3 - bf2f(h3));
    hw.x = (unsigned short)h0 | ((unsigned)(unsigned short)h1 << 16);
    hw.y = (unsigned short)h2 | ((unsigned)(unsigned short)h3 << 16);
    lw.x = (unsigned short)l0 | ((unsigned)(unsigned short)l1 << 16);
    lw.y = (unsigned short)l2 | ((unsigned)(unsigned short)l3 << 16);
}

// 8 fp16 (uint4) -> split-bf16 pair (ah, al), exact (fp16 subset of fp32)
__device__ inline void h8_to_bf16pair(uint4 V, bf16x8& ah, bf16x8& al) {
    const unsigned* w = (const unsigned*)&V;
    short hh[8], ll[8];
#pragma unroll
    for (int q = 0; q < 4; q++) {
        __half2 p = *(__half2*)&w[q];
        float2 f = __half22float2(p);
        short h0 = f2bf(f.x), h1 = f2bf(f.y);
        hh[2 * q] = h0; hh[2 * q + 1] = h1;
        ll[2 * q] = f2bf(f.x - bf2f(h0));
        ll[2 * q + 1] = f2bf(f.y - bf2f(h1));
    }
#pragma unroll
    for (int q = 0; q < 8; q++) { ah[q] = hh[q]; al[q] = ll[q]; }
}

// ---------------- small graph-prep kernels ----------------

__global__ __launch_bounds__(256) void zero_kernel(int* counts, int n, float* pool_sum, int* pool_max) {
    int i = blockIdx.x * 256 + threadIdx.x;
    if (i < n) counts[i] = 0;
    if (i < HID) { pool_sum[i] = 0.0f; pool_max[i] = 0; }
}

__global__ __launch_bounds__(256) void hist_kernel(const int* __restrict__ ei, int E, int* __restrict__ counts) {
    int e = blockIdx.x * 256 + threadIdx.x;
    if (e < E) atomicAdd(&counts[ei[E + e]], 1);
}

__global__ __launch_bounds__(256) void scan_partial(const int* __restrict__ counts, int n,
                                                    int* __restrict__ chunkSums, float* __restrict__ dinv) {
    __shared__ int s[256];
    int t = threadIdx.x, base = blockIdx.x * 1024;
    int sum = 0;
#pragma unroll
    for (int j = 0; j < 4; j++) {
        int i = base + t * 4 + j;
        if (i < n) {
            int c = counts[i];
            sum += c;
            dinv[i] = rsqrtf((float)(c + 1));
        }
    }
    s[t] = sum; __syncthreads();
    for (int off = 128; off > 0; off >>= 1) { if (t < off) s[t] += s[t + off]; __syncthreads(); }
    if (t == 0) chunkSums[blockIdx.x] = s[0];
}

__global__ void scan_sums(int* cs, int nch) {
    int l = threadIdx.x;
    int orig = (l < nch) ? cs[l] : 0;
    int v = orig;
    for (int off = 1; off < 64; off <<= 1) {
        int x = __shfl_up(v, off, 64);
        if (l >= off) v += x;
    }
    if (l < nch) cs[l] = v - orig;
}

__global__ __launch_bounds__(256) void scan_final(const int* __restrict__ counts, int n,
                                                  const int* __restrict__ chunkOff, int* __restrict__ row_ptr,
                                                  int* __restrict__ cursor) {
    __shared__ int s[256];
    int t = threadIdx.x, base = blockIdx.x * 1024;
    int v[4]; int sum = 0;
#pragma unroll
    for (int j = 0; j < 4; j++) { int i = base + t * 4 + j; v[j] = (i < n) ? counts[i] : 0; sum += v[j]; }
    s[t] = sum; __syncthreads();
    for (int off = 1; off < 256; off <<= 1) {
        int x = (t >= off) ? s[t - off] : 0;
        __syncthreads();
        s[t] += x;
        __syncthreads();
    }
    int run = chunkOff[blockIdx.x] + (s[t] - sum);
#pragma unroll
    for (int j = 0; j < 4; j++) {
        int i = base + t * 4 + j;
        if (i < n) {
            row_ptr[i] = run; cursor[i] = run; run += v[j];
            if (i == n - 1) row_ptr[n] = run;
        }
    }
}

__global__ __launch_bounds__(256) void fill_kernel(const int* __restrict__ ei, int E,
                                                   int* __restrict__ cursor, int* __restrict__ adj) {
    int e = blockIdx.x * 256 + threadIdx.x;
    if (e < E) {
        int s = ei[e], d = ei[E + e];
        int p = atomicAdd(&cursor[d], 1);
        adj[p] = s;
    }
}

// ---------------- weight packing (slab-major bf16 split) ----------------

__global__ __launch_bounds__(256) void pack_all(const float* __restrict__ W1, const float* __restrict__ W2,
                                                const float* __restrict__ Wc,
                                                short* __restrict__ PH, short* __restrict__ PL) {
    int b = blockIdx.x, n = threadIdx.x;
    const float* src; int k; size_t dst;
    if (b < 64) { src = W1; k = b; dst = 0; }
    else {
        int m = (b - 64) >> 8; k = (b - 64) & 255;
        src = (m == 0) ? W2 : (Wc + (size_t)(m - 1) * 65536);
        dst = 16384 + (size_t)m * 65536;
    }
    float w = src[(size_t)k * 256 + n];
    short h = f2bf(w);
    short l = f2bf(w - bf2f(h));
    int o = ((k >> 3) * 256 + n) * 8 + (k & 7);
    PH[dst + o] = h; PL[dst + o] = l;
}

// ---------------- fused encoder: out = hpack(dinv * (relu(x@W1+b1)@W2 + b2)) --
// BM=32 rows/block, 4 waves. LDS LB[8448] shorts (16896 B):
//   stage1 frags: Ah1 at 0 ([8][33][8]=2112 sh), Al1 at 2112 (reads done pre-sync)
//   t (fp16):     [32][264] = 8448 sh (aliases stage-1 region after barrier)
//   epilogue:     fp16 out tile reuses the t region layout [32][264]

#define TPAD 264

__global__ __launch_bounds__(256) void encoder_fused(const float* __restrict__ x,
                                                     const short* __restrict__ PB1h, const short* __restrict__ PB1l,
                                                     const short* __restrict__ PB2h, const short* __restrict__ PB2l,
                                                     const float* __restrict__ b1, const float* __restrict__ b2,
                                                     const float* __restrict__ dinv,
                                                     short* __restrict__ Aout, int n) {
    __shared__ short LB[8448];
    int t = threadIdx.x, lane = t & 63, wv = t >> 6;
    int lr = lane & 15, lg = lane >> 4;
    int brow = blockIdx.x * 32;
    int bcol = wv * 64;

    // ---- stage 1 load: x tile 32x64 -> split-bf16 A frags ----
#pragma unroll
    for (int l = 0; l < 2; l++) {
        int lin = t + l * 256;
        int r = lin >> 4, kq = (lin & 15) * 4;
        int row = brow + r;
        float4 v = (row < n) ? *(const float4*)(x + (size_t)row * FIN + kq)
                             : make_float4(0.f, 0.f, 0.f, 0.f);
        uint2 hw, lw; split2(v.x, v.y, v.z, v.w, hw, lw);
        int g = kq >> 3, i0 = kq & 7;
        *(uint2*)&LB[(g * 33 + r) * 8 + i0] = hw;
        *(uint2*)&LB[2112 + (g * 33 + r) * 8 + i0] = lw;
    }
    __syncthreads();

    // ---- stage 1 MFMA: t = x@W1, K=64 ----
    f32x4 acc1[2][4] = {};
#pragma unroll
    for (int s = 0; s < 2; s++) {
        int sl = s * 4 + lg;
        bf16x8 ah[2], al[2], bh[4], bl[4];
#pragma unroll
        for (int mi = 0; mi < 2; mi++) {
            ah[mi] = *(bf16x8*)&LB[(sl * 33 + mi * 16 + lr) * 8];
            al[mi] = *(bf16x8*)&LB[2112 + (sl * 33 + mi * 16 + lr) * 8];
        }
        const short* pbh = PB1h + ((size_t)sl * 256 + bcol + lr) * 8;
        const short* pbl = PB1l + ((size_t)sl * 256 + bcol + lr) * 8;
#pragma unroll
        for (int ni = 0; ni < 4; ni++) {
            bh[ni] = *(const bf16x8*)(pbh + ni * 128);
            bl[ni] = *(const bf16x8*)(pbl + ni * 128);
        }
#pragma unroll
        for (int mi = 0; mi < 2; mi++)
#pragma unroll
            for (int ni = 0; ni < 4; ni++) {
                acc1[mi][ni] = __builtin_amdgcn_mfma_f32_16x16x32_bf16(ah[mi], bh[ni], acc1[mi][ni], 0, 0, 0);
                acc1[mi][ni] = __builtin_amdgcn_mfma_f32_16x16x32_bf16(ah[mi], bl[ni], acc1[mi][ni], 0, 0, 0);
                acc1[mi][ni] = __builtin_amdgcn_mfma_f32_16x16x32_bf16(al[mi], bh[ni], acc1[mi][ni], 0, 0, 0);
            }
    }
    __syncthreads();   // stage-1 frag reads done; LB reusable

    // ---- t = relu(acc1 + b1) -> fp16 [32][TPAD] in LDS ----
#pragma unroll
    for (int ni = 0; ni < 4; ni++) {
        int col = bcol + ni * 16 + lr;
        float bv = b1[col];
#pragma unroll
        for (int mi = 0; mi < 2; mi++)
#pragma unroll
            for (int j = 0; j < 4; j++) {
                int r = mi * 16 + lg * 4 + j;
                float o = fmaxf(acc1[mi][ni][j] + bv, 0.f);
                *(__half*)&LB[r * TPAD + col] = __float2half_rn(o);
            }
    }
    __syncthreads();

    // ---- stage 2 MFMA: out = t@W2, K=256 (t split fp16->bf16 pair at read) ----
    f32x4 acc2[2][4] = {};
#pragma unroll
    for (int s = 0; s < 8; s++) {
        int sl = s * 4 + lg;
        bf16x8 ah[2], al[2], bh[4], bl[4];
#pragma unroll
        for (int mi = 0; mi < 2; mi++) {
            uint4 V = *(uint4*)&LB[(mi * 16 + lr) * TPAD + sl * 8];
            h8_to_bf16pair(V, ah[mi], al[mi]);
        }
        const short* pbh = PB2h + ((size_t)sl * 256 + bcol + lr) * 8;
        const short* pbl = PB2l + ((size_t)sl * 256 + bcol + lr) * 8;
#pragma unroll
        for (int ni = 0; ni < 4; ni++) {
            bh[ni] = *(const bf16x8*)(pbh + ni * 128);
            bl[ni] = *(const bf16x8*)(pbl + ni * 128);
        }
#pragma unroll
        for (int mi = 0; mi < 2; mi++)
#pragma unroll
            for (int ni = 0; ni < 4; ni++) {
                acc2[mi][ni] = __builtin_amdgcn_mfma_f32_16x16x32_bf16(ah[mi], bh[ni], acc2[mi][ni], 0, 0, 0);
                acc2[mi][ni] = __builtin_amdgcn_mfma_f32_16x16x32_bf16(ah[mi], bl[ni], acc2[mi][ni], 0, 0, 0);
                acc2[mi][ni] = __builtin_amdgcn_mfma_f32_16x16x32_bf16(al[mi], bh[ni], acc2[mi][ni], 0, 0, 0);
            }
    }
    __syncthreads();   // t reads done; LB reusable

    // ---- epilogue: dinv * (acc2 + b2) -> fp16 tile [32][TPAD] in LDS ----
    float dvo[2][4];
#pragma unroll
    for (int mi = 0; mi < 2; mi++)
#pragma unroll
        for (int j = 0; j < 4; j++) {
            int row = brow + mi * 16 + lg * 4 + j;
            dvo[mi][j] = (row < n) ? dinv[row] : 0.f;
        }
#pragma unroll
    for (int ni = 0; ni < 4; ni++) {
        int col = bcol + ni * 16 + lr;
        float bv = b2[col];
#pragma unroll
        for (int mi = 0; mi < 2; mi++)
#pragma unroll
            for (int j = 0; j < 4; j++) {
                int r = mi * 16 + lg * 4 + j;
                float o = (acc2[mi][ni][j] + bv) * dvo[mi][j];
                *(__half*)&LB[r * TPAD + col] = __float2half_rn(o);
            }
    }
    __syncthreads();

    // ---- cooperative write-out: 1024 x 16B chunks (512B/row) ----
#pragma unroll
    for (int q = 0; q < 4; q++) {
        int idx = t + q * 256;          // [0,1024)
        int row = idx >> 5, c = idx & 31;
        int vv = brow + row;
        if (vv < n)
            *(uint4*)(Aout + (size_t)vv * 256 + c * 8) = *(const uint4*)&LB[row * TPAD + c * 8];
    }
}

// ---------------- fused GCN layer: out = relu((S@h)@Wc + b) -------------------
// Input hpack fp16 PRE-SCALED by dinv => gather is a pure fp16 row sum.
// BM=16 rows/block, 4 waves; 8-deep gather (R11 config: uint2/lane, VGPR~36).
// LDS aliased: bf16 A-frags (8704 sh) / fp16 out tile (4096 sh).

template<bool SCALE_OUT>
__global__ __launch_bounds__(256) void layer_fused(const short* __restrict__ Ain,
                                                   const int* __restrict__ row_ptr, const int* __restrict__ adj,
                                                   const float* __restrict__ dinv,
                                                   const short* __restrict__ PBh, const short* __restrict__ PBl,
                                                   const float* __restrict__ bias,
                                                   short* __restrict__ Aout, int n) {
    __shared__ short LB[8704];
    int t = threadIdx.x, lane = t & 63, wv = t >> 6;
    int lr = lane & 15, lg = lane >> 4;
    int brow = blockIdx.x * 16;
    int slab = lane >> 1, i0 = (lane & 1) * 4;
    int loff = lane * 4;                            // fp16 col base (4 cols/lane)

    // ---- phase 1: gather + sum (each wave: 4 dst rows) ----
    for (int it = 0; it < 4; ++it) {
        int r = wv * 4 + it, v = brow + r;
        if (v >= n) break;                          // wave-uniform
        float dv = dinv[v];
        uint2 V0 = *(const uint2*)(Ain + (size_t)v * 256 + loff);
        float4 acc = make_float4(0.f, 0.f, 0.f, 0.f);
        HADD(V0);
        int e = row_ptr[v], end = row_ptr[v + 1];
        for (; e + 8 <= end; e += 8) {
            int s8[8]; uint2 V[8];
#pragma unroll
            for (int j = 0; j < 8; j++) s8[j] = adj[e + j];
#pragma unroll
            for (int j = 0; j < 8; j++) V[j] = *(const uint2*)(Ain + (size_t)s8[j] * 256 + loff);
#pragma unroll
            for (int j = 0; j < 8; j++) HADD(V[j]);
        }
        for (; e + 4 <= end; e += 4) {
            int s4[4]; uint2 V[4];
#pragma unroll
            for (int j = 0; j < 4; j++) s4[j] = adj[e + j];
#pragma unroll
            for (int j = 0; j < 4; j++) V[j] = *(const uint2*)(Ain + (size_t)s4[j] * 256 + loff);
#pragma unroll
            for (int j = 0; j < 4; j++) HADD(V[j]);
        }
        for (; e < end; e++) {
            uint2 V = *(const uint2*)(Ain + (size_t)adj[e] * 256 + loff);
            HADD(V);
        }
        uint2 hw, lw;
        split2(dv * acc.x, dv * acc.y, dv * acc.z, dv * acc.w, hw, lw);
        *(uint2*)&LB[(slab * 17 + r) * 8 + i0] = hw;
        *(uint2*)&LB[4352 + (slab * 17 + r) * 8 + i0] = lw;
    }
    __syncthreads();

    // ---- phase 2: 3-term MFMA, wave wv -> cols [wv*64, wv*64+64) ----
    int bcol = wv * 64;
    f32x4 acc2[4] = {};
#pragma unroll
    for (int s = 0; s < 8; ++s) {
        int sl = s * 4 + lg;
        bf16x8 ah = *(bf16x8*)&LB[(sl * 17 + lr) * 8];
        bf16x8 al = *(bf16x8*)&LB[4352 + (sl * 17 + lr) * 8];
        const short* pbh = PBh + ((size_t)sl * 256 + bcol + lr) * 8;
        const short* pbl = PBl + ((size_t)sl * 256 + bcol + lr) * 8;
        bf16x8 bh[4], bl[4];
#pragma unroll
        for (int ni = 0; ni < 4; ni++) {
            bh[ni] = *(const bf16x8*)(pbh + ni * 128);
            bl[ni] = *(const bf16x8*)(pbl + ni * 128);
        }
#pragma unroll
        for (int ni = 0; ni < 4; ni++) {
            acc2[ni] = __builtin_amdgcn_mfma_f32_16x16x32_bf16(ah, bh[ni], acc2[ni], 0, 0, 0);
            acc2[ni] = __builtin_amdgcn_mfma_f32_16x16x32_bf16(ah, bl[ni], acc2[ni], 0, 0, 0);
            acc2[ni] = __builtin_amdgcn_mfma_f32_16x16x32_bf16(al, bh[ni], acc2[ni], 0, 0, 0);
        }
    }
    __syncthreads();   // all LDS A-frag reads done; safe to reuse buffer

    // ---- epilogue: relu(acc+bias) [*dinv] -> fp16 tile [16][256] in LDS ----
    float dvo[4];
    if (SCALE_OUT) {
#pragma unroll
        for (int j = 0; j < 4; j++) {
            int row = brow + lg * 4 + j;
            dvo[j] = (row < n) ? dinv[row] : 0.f;
        }
    }
#pragma unroll
    for (int ni = 0; ni < 4; ni++) {
        int col = bcol + ni * 16 + lr;
        float bv = bias[col];
#pragma unroll
        for (int j = 0; j < 4; j++) {
            int r = lg * 4 + j;
            float o = fmaxf(acc2[ni][j] + bv, 0.f);
            if (SCALE_OUT) o *= dvo[j];
            *(__half*)&LB[r * 256 + col] = __float2half_rn(o);
        }
    }
    __syncthreads();

    // ---- cooperative write-out: 512 x 16B chunks (512B/row) ----
#pragma unroll
    for (int q = 0; q < 2; q++) {
        int idx = t + q * 256;          // [0,512)
        int row = idx >> 5, c = idx & 31;
        int vv = brow + row;
        if (vv < n)
            *(uint4*)(Aout + (size_t)vv * 256 + c * 8) = *(const uint4*)&LB[row * 256 + c * 8];
    }
}

// ---------------- pooling (mean + max over rows) from hpack fp16 --------------

__global__ __launch_bounds__(256) void pool_packed(const short* __restrict__ P, int n,
                                                   float* __restrict__ pool_sum, int* __restrict__ pool_max) {
    int t = threadIdx.x;   // column
    int chunk = (n + gridDim.x - 1) / gridDim.x;
    int r0 = blockIdx.x * chunk, r1 = min(n, r0 + chunk);
    float s = 0.f, mx = 0.f;
    for (int r = r0; r < r1; r++) {
        float v = __half2float(*(const __half*)&P[(size_t)r * 256 + t]);
        s += v;
        mx = fmaxf(mx, v);
    }
    atomicAdd(&pool_sum[t], s);
    atomicMax(&pool_max[t], __float_as_int(mx));
}

// ---------------- final MLP head (single block) ----------------

__global__ __launch_bounds__(256) void mlp_head(const float* __restrict__ pool_sum, const int* __restrict__ pool_max,
                                                const float* __restrict__ Wp1, const float* __restrict__ bp1,
                                                const float* __restrict__ Wp2, const float* __restrict__ bp2,
                                                float* __restrict__ out, float invn) {
    __shared__ float g[2 * HID];
    __shared__ float hid[HID];
    int t = threadIdx.x;
    g[t] = pool_sum[t] * invn;
    g[HID + t] = __int_as_float(pool_max[t]);
    __syncthreads();
    float acc = bp1[t];
#pragma unroll 8
    for (int j = 0; j < 2 * HID; j++) acc = fmaf(g[j], Wp1[j * HID + t], acc);
    hid[t] = fmaxf(acc, 0.f);
    __syncthreads();
    if (t < DEMB) {
        float a2 = bp2[t];
#pragma unroll 8
        for (int j = 0; j < HID; j++) a2 = fmaf(hid[j], Wp2[j * DEMB + t], a2);
        out[t] = a2;
    }
}

// ---------------- launcher ----------------

extern "C" void kernel_launch(void* const* d_in, const int* in_sizes, int n_in,
                              void* d_out, int out_size, void* d_ws, size_t ws_size,
                              hipStream_t stream) {
    const float* x   = (const float*)d_in[0];
    const int*   ei  = (const int*)d_in[1];
    const float* W1  = (const float*)d_in[2];
    const float* b1  = (const float*)d_in[3];
    const float* W2  = (const float*)d_in[4];
    const float* b2  = (const float*)d_in[5];
    const float* Wc  = (const float*)d_in[6];
    const float* bc  = (const float*)d_in[7];
    const float* Wp1 = (const float*)d_in[8];
    const float* bp1 = (const float*)d_in[9];
    const float* Wp2 = (const float*)d_in[10];
    const float* bp2 = (const float*)d_in[11];
    float* out = (float*)d_out;

    int N = in_sizes[0] / FIN;
    int E = in_sizes[1] / 2;
    int nb32 = (N + 31) / 32;
    int nb16 = (N + 15) / 16;
    int R = nb32 * 32;                   // padded rows for hpack buffers

    char* base = (char*)d_ws;
    short* actA = (short*)base;                          // [R,256] fp16 hpack
    short* actB = (short*)(base + (size_t)R * 512);      // [R,256] fp16 hpack
    int*   counts  = (int*)(base + 2 * (size_t)R * 512); // [N]
    int*   row_ptr = counts + N;                         // [N+1]
    int*   cursor  = row_ptr + (N + 1);                  // [N]
    int*   adj     = cursor + N;                         // [E]
    float* dinvp   = (float*)(adj + E);                  // [N]
    float* pool_sum = dinvp + N;                         // [HID]
    int*   pool_max = (int*)(pool_sum + HID);            // [HID]
    int*   chunkSums = pool_max + HID;                   // [<=64]
    short* PH = (short*)((((uintptr_t)(chunkSums + 64)) + 15) & ~(uintptr_t)15);
    short* PL = PH + 278528;
    const int oW1 = 0, oW2 = 16384, oC0 = 81920, oC1 = 147456, oC2 = 212992;

    int nch = (N + 1023) / 1024;
    int nb256 = (N + 255) / 256;
    int eb256 = (E + 255) / 256;

    zero_kernel<<<nb256, 256, 0, stream>>>(counts, N, pool_sum, pool_max);
    hist_kernel<<<eb256, 256, 0, stream>>>(ei, E, counts);
    scan_partial<<<nch, 256, 0, stream>>>(counts, N, chunkSums, dinvp);
    scan_sums<<<1, 64, 0, stream>>>(chunkSums, nch);
    scan_final<<<nch, 256, 0, stream>>>(counts, N, chunkSums, row_ptr, cursor);
    fill_kernel<<<eb256, 256, 0, stream>>>(ei, E, cursor, adj);

    pack_all<<<64 + 4 * 256, 256, 0, stream>>>(W1, W2, Wc, PH, PL);

    // fused encoder: actA = hpack(dinv * (relu(x@W1+b1)@W2 + b2))
    encoder_fused<<<nb32, 256, 0, stream>>>(x, PH + oW1, PL + oW1, PH + oW2, PL + oW2,
                                            b1, b2, dinvp, actA, N);

    // fused GCN layers: out = relu((S@h)@Wc + bc); pre-scaled except last
    layer_fused<true><<<nb16, 256, 0, stream>>>(actA, row_ptr, adj, dinvp, PH + oC0, PL + oC0, bc + 0 * HID, actB, N);
    layer_fused<true><<<nb16, 256, 0, stream>>>(actB, row_ptr, adj, dinvp, PH + oC1, PL + oC1, bc + 1 * HID, actA, N);
    layer_fused<false><<<nb16, 256, 0, stream>>>(actA, row_ptr, adj, dinvp, PH + oC2, PL + oC2, bc + 2 * HID, actB, N);

    // pooling + head
    pool_packed<<<256, 256, 0, stream>>>(actB, N, pool_sum, pool_max);
    mlp_head<<<1, 256, 0, stream>>>(pool_sum, pool_max, Wp1, bp1, Wp2, bp2, out, 1.0f / (float)N);
}

// Round 15
// 481.240 us; speedup vs baseline: 1.0706x; 1.0016x over previous
//
#include <hip/hip_runtime.h>
#include <hip/hip_fp16.h>

#define FIN 64
#define HID 256
#define DEMB 128
#define NLAYERS 3
#define TPAD 264

typedef __attribute__((ext_vector_type(8))) short bf16x8;
typedef __attribute__((ext_vector_type(4))) float f32x4;

__device__ inline short f2bf(float x) {               // RNE fp32 -> bf16 bits
    unsigned u = __float_as_uint(x);
    u += 0x7fff + ((u >> 16) & 1);
    return (short)(u >> 16);
}
__device__ inline float bf2f(short h) {
    return __uint_as_float(((unsigned)(unsigned short)h) << 16);
}

// Activation layout "hpack": per row r, 256 fp16 (512B contiguous), linear cols.
// Values PRE-SCALED by dinv[row] except after the last layer.

// add 4 fp16 cols (uint2) into fp32 acc
#define HADD(V) do { \
    __half2 p0 = *(__half2*)&(V).x, p1 = *(__half2*)&(V).y; \
    float2 f0 = __half22float2(p0), f1 = __half22float2(p1); \
    acc.x += f0.x; acc.y += f0.y; acc.z += f1.x; acc.w += f1.y; } while (0)

__device__ inline void split2(float a0, float a1, float a2, float a3, uint2& hw, uint2& lw) {
    short h0 = f2bf(a0), h1 = f2bf(a1), h2 = f2bf(a2), h3 = f2bf(a3);
    short l0 = f2bf(a0 - bf2f(h0)), l1 = f2bf(a1 - bf2f(h1));
    short l2 = f2bf(a2 - bf2f(h2)), l3 = f2bf(a3 - bf2f(h3));
    hw.x = (unsigned short)h0 | ((unsigned)(unsigned short)h1 << 16);
    hw.y = (unsigned short)h2 | ((unsigned)(unsigned short)h3 << 16);
    lw.x = (unsigned short)l0 | ((unsigned)(unsigned short)l1 << 16);
    lw.y = (unsigned short)l2 | ((unsigned)(unsigned short)l3 << 16);
}

// 8 fp16 (uint4) -> split-bf16 pair (ah, al), exact (fp16 subset of fp32)
__device__ inline void h8_to_bf16pair(uint4 V, bf16x8& ah, bf16x8& al) {
    const unsigned* w = (const unsigned*)&V;
    short hh[8], ll[8];
#pragma unroll
    for (int q = 0; q < 4; q++) {
        __half2 p = *(__half2*)&w[q];
        float2 f = __half22float2(p);
        short h0 = f2bf(f.x), h1 = f2bf(f.y);
        hh[2 * q] = h0; hh[2 * q + 1] = h1;
        ll[2 * q] = f2bf(f.x - bf2f(h0));
        ll[2 * q + 1] = f2bf(f.y - bf2f(h1));
    }
#pragma unroll
    for (int q = 0; q < 8; q++) { ah[q] = hh[q]; al[q] = ll[q]; }
}

// ---------------- zero + weight-pack combined (independent work) --------------
// blocks [0, nzb): zero counts/pools.  blocks [nzb, nzb+1088): pack weights.
// pack: element (k,n) -> P[ ((k>>3)*256 + n)*8 + (k&7) ]

__global__ __launch_bounds__(256) void zero_pack(int* counts, int n, float* pool_sum, int* pool_max, int nzb,
                                                 const float* __restrict__ W1, const float* __restrict__ W2,
                                                 const float* __restrict__ Wc,
                                                 short* __restrict__ PH, short* __restrict__ PL) {
    if ((int)blockIdx.x < nzb) {
        int i = blockIdx.x * 256 + threadIdx.x;
        if (i < n) counts[i] = 0;
        if (i < HID) { pool_sum[i] = 0.0f; pool_max[i] = 0; }
        return;
    }
    int b = blockIdx.x - nzb, nn = threadIdx.x;
    const float* src; int k; size_t dst;
    if (b < 64) { src = W1; k = b; dst = 0; }
    else {
        int m = (b - 64) >> 8; k = (b - 64) & 255;
        src = (m == 0) ? W2 : (Wc + (size_t)(m - 1) * 65536);
        dst = 16384 + (size_t)m * 65536;
    }
    float w = src[(size_t)k * 256 + nn];
    short h = f2bf(w);
    short l = f2bf(w - bf2f(h));
    int o = ((k >> 3) * 256 + nn) * 8 + (k & 7);
    PH[dst + o] = h; PL[dst + o] = l;
}

__global__ __launch_bounds__(256) void hist_kernel(const int* __restrict__ ei, int E, int* __restrict__ counts) {
    int e = blockIdx.x * 256 + threadIdx.x;
    if (e < E) atomicAdd(&counts[ei[E + e]], 1);
}

__global__ __launch_bounds__(256) void scan_partial(const int* __restrict__ counts, int n,
                                                    int* __restrict__ chunkSums, float* __restrict__ dinv) {
    __shared__ int s[256];
    int t = threadIdx.x, base = blockIdx.x * 1024;
    int sum = 0;
#pragma unroll
    for (int j = 0; j < 4; j++) {
        int i = base + t * 4 + j;
        if (i < n) {
            int c = counts[i];
            sum += c;
            dinv[i] = rsqrtf((float)(c + 1));
        }
    }
    s[t] = sum; __syncthreads();
    for (int off = 128; off > 0; off >>= 1) { if (t < off) s[t] += s[t + off]; __syncthreads(); }
    if (t == 0) chunkSums[blockIdx.x] = s[0];
}

// scan_final now derives its own chunk offset (serial prefix over <=64 sums)
__global__ __launch_bounds__(256) void scan_final(const int* __restrict__ counts, int n,
                                                  const int* __restrict__ chunkSums, int* __restrict__ row_ptr,
                                                  int* __restrict__ cursor) {
    __shared__ int s[256];
    __shared__ int base_s;
    int t = threadIdx.x, base = blockIdx.x * 1024;
    if (t == 0) {
        int a = 0;
        for (int i = 0; i < (int)blockIdx.x; i++) a += chunkSums[i];
        base_s = a;
    }
    int v[4]; int sum = 0;
#pragma unroll
    for (int j = 0; j < 4; j++) { int i = base + t * 4 + j; v[j] = (i < n) ? counts[i] : 0; sum += v[j]; }
    s[t] = sum; __syncthreads();
    for (int off = 1; off < 256; off <<= 1) {
        int x = (t >= off) ? s[t - off] : 0;
        __syncthreads();
        s[t] += x;
        __syncthreads();
    }
    int run = base_s + (s[t] - sum);
#pragma unroll
    for (int j = 0; j < 4; j++) {
        int i = base + t * 4 + j;
        if (i < n) {
            row_ptr[i] = run; cursor[i] = run; run += v[j];
            if (i == n - 1) row_ptr[n] = run;
        }
    }
}

__global__ __launch_bounds__(256) void fill_kernel(const int* __restrict__ ei, int E,
                                                   int* __restrict__ cursor, int* __restrict__ adj) {
    int e = blockIdx.x * 256 + threadIdx.x;
    if (e < E) {
        int s = ei[e], d = ei[E + e];
        int p = atomicAdd(&cursor[d], 1);
        adj[p] = s;
    }
}

// ---------------- fused encoder: out = hpack(dinv * (relu(x@W1+b1)@W2 + b2)) --
// BM=32 rows/block, 4 waves. LDS LB[8448] shorts (16896 B).

__global__ __launch_bounds__(256) void encoder_fused(const float* __restrict__ x,
                                                     const short* __restrict__ PB1h, const short* __restrict__ PB1l,
                                                     const short* __restrict__ PB2h, const short* __restrict__ PB2l,
                                                     const float* __restrict__ b1, const float* __restrict__ b2,
                                                     const float* __restrict__ dinv,
                                                     short* __restrict__ Aout, int n) {
    __shared__ short LB[8448];
    int t = threadIdx.x, lane = t & 63, wv = t >> 6;
    int lr = lane & 15, lg = lane >> 4;
    int brow = blockIdx.x * 32;
    int bcol = wv * 64;

    // ---- stage 1 load: x tile 32x64 -> split-bf16 A frags ----
#pragma unroll
    for (int l = 0; l < 2; l++) {
        int lin = t + l * 256;
        int r = lin >> 4, kq = (lin & 15) * 4;
        int row = brow + r;
        float4 v = (row < n) ? *(const float4*)(x + (size_t)row * FIN + kq)
                             : make_float4(0.f, 0.f, 0.f, 0.f);
        uint2 hw, lw; split2(v.x, v.y, v.z, v.w, hw, lw);
        int g = kq >> 3, i0 = kq & 7;
        *(uint2*)&LB[(g * 33 + r) * 8 + i0] = hw;
        *(uint2*)&LB[2112 + (g * 33 + r) * 8 + i0] = lw;
    }
    __syncthreads();

    // ---- stage 1 MFMA: t = x@W1, K=64 ----
    f32x4 acc1[2][4] = {};
#pragma unroll
    for (int s = 0; s < 2; s++) {
        int sl = s * 4 + lg;
        bf16x8 ah[2], al[2], bh[4], bl[4];
#pragma unroll
        for (int mi = 0; mi < 2; mi++) {
            ah[mi] = *(bf16x8*)&LB[(sl * 33 + mi * 16 + lr) * 8];
            al[mi] = *(bf16x8*)&LB[2112 + (sl * 33 + mi * 16 + lr) * 8];
        }
        const short* pbh = PB1h + ((size_t)sl * 256 + bcol + lr) * 8;
        const short* pbl = PB1l + ((size_t)sl * 256 + bcol + lr) * 8;
#pragma unroll
        for (int ni = 0; ni < 4; ni++) {
            bh[ni] = *(const bf16x8*)(pbh + ni * 128);
            bl[ni] = *(const bf16x8*)(pbl + ni * 128);
        }
#pragma unroll
        for (int mi = 0; mi < 2; mi++)
#pragma unroll
            for (int ni = 0; ni < 4; ni++) {
                acc1[mi][ni] = __builtin_amdgcn_mfma_f32_16x16x32_bf16(ah[mi], bh[ni], acc1[mi][ni], 0, 0, 0);
                acc1[mi][ni] = __builtin_amdgcn_mfma_f32_16x16x32_bf16(ah[mi], bl[ni], acc1[mi][ni], 0, 0, 0);
                acc1[mi][ni] = __builtin_amdgcn_mfma_f32_16x16x32_bf16(al[mi], bh[ni], acc1[mi][ni], 0, 0, 0);
            }
    }
    __syncthreads();   // stage-1 frag reads done; LB reusable

    // ---- t = relu(acc1 + b1) -> fp16 [32][TPAD] in LDS ----
#pragma unroll
    for (int ni = 0; ni < 4; ni++) {
        int col = bcol + ni * 16 + lr;
        float bv = b1[col];
#pragma unroll
        for (int mi = 0; mi < 2; mi++)
#pragma unroll
            for (int j = 0; j < 4; j++) {
                int r = mi * 16 + lg * 4 + j;
                float o = fmaxf(acc1[mi][ni][j] + bv, 0.f);
                *(__half*)&LB[r * TPAD + col] = __float2half_rn(o);
            }
    }
    __syncthreads();

    // ---- stage 2 MFMA: out = t@W2, K=256 (t split fp16->bf16 pair at read) ----
    f32x4 acc2[2][4] = {};
#pragma unroll
    for (int s = 0; s < 8; s++) {
        int sl = s * 4 + lg;
        bf16x8 ah[2], al[2], bh[4], bl[4];
#pragma unroll
        for (int mi = 0; mi < 2; mi++) {
            uint4 V = *(uint4*)&LB[(mi * 16 + lr) * TPAD + sl * 8];
            h8_to_bf16pair(V, ah[mi], al[mi]);
        }
        const short* pbh = PB2h + ((size_t)sl * 256 + bcol + lr) * 8;
        const short* pbl = PB2l + ((size_t)sl * 256 + bcol + lr) * 8;
#pragma unroll
        for (int ni = 0; ni < 4; ni++) {
            bh[ni] = *(const bf16x8*)(pbh + ni * 128);
            bl[ni] = *(const bf16x8*)(pbl + ni * 128);
        }
#pragma unroll
        for (int mi = 0; mi < 2; mi++)
#pragma unroll
            for (int ni = 0; ni < 4; ni++) {
                acc2[mi][ni] = __builtin_amdgcn_mfma_f32_16x16x32_bf16(ah[mi], bh[ni], acc2[mi][ni], 0, 0, 0);
                acc2[mi][ni] = __builtin_amdgcn_mfma_f32_16x16x32_bf16(ah[mi], bl[ni], acc2[mi][ni], 0, 0, 0);
                acc2[mi][ni] = __builtin_amdgcn_mfma_f32_16x16x32_bf16(al[mi], bh[ni], acc2[mi][ni], 0, 0, 0);
            }
    }
    __syncthreads();   // t reads done; LB reusable

    // ---- epilogue: dinv * (acc2 + b2) -> fp16 tile [32][TPAD] in LDS ----
    float dvo[2][4];
#pragma unroll
    for (int mi = 0; mi < 2; mi++)
#pragma unroll
        for (int j = 0; j < 4; j++) {
            int row = brow + mi * 16 + lg * 4 + j;
            dvo[mi][j] = (row < n) ? dinv[row] : 0.f;
        }
#pragma unroll
    for (int ni = 0; ni < 4; ni++) {
        int col = bcol + ni * 16 + lr;
        float bv = b2[col];
#pragma unroll
        for (int mi = 0; mi < 2; mi++)
#pragma unroll
            for (int j = 0; j < 4; j++) {
                int r = mi * 16 + lg * 4 + j;
                float o = (acc2[mi][ni][j] + bv) * dvo[mi][j];
                *(__half*)&LB[r * TPAD + col] = __float2half_rn(o);
            }
    }
    __syncthreads();

    // ---- cooperative write-out: 1024 x 16B chunks (512B/row) ----
#pragma unroll
    for (int q = 0; q < 4; q++) {
        int idx = t + q * 256;          // [0,1024)
        int row = idx >> 5, c = idx & 31;
        int vv = brow + row;
        if (vv < n)
            *(uint4*)(Aout + (size_t)vv * 256 + c * 8) = *(const uint4*)&LB[row * TPAD + c * 8];
    }
}

// ---------------- fused GCN layer: out = relu((S@h)@Wc + b) -------------------
// Input hpack fp16 PRE-SCALED by dinv => gather is a pure fp16 row sum.
// BM=32 rows/block, 4 waves (8 rows/wave); 8-deep gather (R11 inner loop).
// A-frags stored UNSPLIT fp16 [32][TPAD] in LDS; split to bf16-pair at
// phase-2 read (h8_to_bf16pair). LDS = 8448 shorts = 16896 B.

template<bool SCALE_OUT>
__global__ __launch_bounds__(256) void layer_fused(const short* __restrict__ Ain,
                                                   const int* __restrict__ row_ptr, const int* __restrict__ adj,
                                                   const float* __restrict__ dinv,
                                                   const short* __restrict__ PBh, const short* __restrict__ PBl,
                                                   const float* __restrict__ bias,
                                                   short* __restrict__ Aout, int n) {
    __shared__ short LB[8448];
    int t = threadIdx.x, lane = t & 63, wv = t >> 6;
    int lr = lane & 15, lg = lane >> 4;
    int brow = blockIdx.x * 32;
    int loff = lane * 4;                            // fp16 col base (4 cols/lane)

    // ---- phase 1: gather + sum (each wave: 8 dst rows) ----
    for (int it = 0; it < 8; ++it) {
        int r = wv * 8 + it, v = brow + r;
        if (v >= n) break;                          // wave-uniform
        float dv = dinv[v];
        uint2 V0 = *(const uint2*)(Ain + (size_t)v * 256 + loff);
        float4 acc = make_float4(0.f, 0.f, 0.f, 0.f);
        HADD(V0);
        int e = row_ptr[v], end = row_ptr[v + 1];
        for (; e + 8 <= end; e += 8) {
            int s8[8]; uint2 V[8];
#pragma unroll
            for (int j = 0; j < 8; j++) s8[j] = adj[e + j];
#pragma unroll
            for (int j = 0; j < 8; j++) V[j] = *(const uint2*)(Ain + (size_t)s8[j] * 256 + loff);
#pragma unroll
            for (int j = 0; j < 8; j++) HADD(V[j]);
        }
        for (; e + 4 <= end; e += 4) {
            int s4[4]; uint2 V[4];
#pragma unroll
            for (int j = 0; j < 4; j++) s4[j] = adj[e + j];
#pragma unroll
            for (int j = 0; j < 4; j++) V[j] = *(const uint2*)(Ain + (size_t)s4[j] * 256 + loff);
#pragma unroll
            for (int j = 0; j < 4; j++) HADD(V[j]);
        }
        for (; e < end; e++) {
            uint2 V = *(const uint2*)(Ain + (size_t)adj[e] * 256 + loff);
            HADD(V);
        }
        // store aggregated row (scaled) as fp16 into A-frag tile
        float a0 = dv * acc.x, a1 = dv * acc.y, a2 = dv * acc.z, a3 = dv * acc.w;
        __half2 q0 = __floats2half2_rn(a0, a1);
        __half2 q1 = __floats2half2_rn(a2, a3);
        uint2 pw;
        pw.x = *(unsigned*)&q0; pw.y = *(unsigned*)&q1;
        *(uint2*)&LB[r * TPAD + loff] = pw;
    }
    __syncthreads();

    // ---- phase 2: 3-term MFMA, wave wv -> cols [wv*64, wv*64+64) ----
    int bcol = wv * 64;
    f32x4 acc2[2][4] = {};
#pragma unroll
    for (int s = 0; s < 8; ++s) {
        int sl = s * 4 + lg;
        bf16x8 ah[2], al[2], bh[4], bl[4];
#pragma unroll
        for (int mi = 0; mi < 2; mi++) {
            uint4 V = *(uint4*)&LB[(mi * 16 + lr) * TPAD + sl * 8];
            h8_to_bf16pair(V, ah[mi], al[mi]);
        }
        const short* pbh = PBh + ((size_t)sl * 256 + bcol + lr) * 8;
        const short* pbl = PBl + ((size_t)sl * 256 + bcol + lr) * 8;
#pragma unroll
        for (int ni = 0; ni < 4; ni++) {
            bh[ni] = *(const bf16x8*)(pbh + ni * 128);
            bl[ni] = *(const bf16x8*)(pbl + ni * 128);
        }
#pragma unroll
        for (int mi = 0; mi < 2; mi++)
#pragma unroll
            for (int ni = 0; ni < 4; ni++) {
                acc2[mi][ni] = __builtin_amdgcn_mfma_f32_16x16x32_bf16(ah[mi], bh[ni], acc2[mi][ni], 0, 0, 0);
                acc2[mi][ni] = __builtin_amdgcn_mfma_f32_16x16x32_bf16(ah[mi], bl[ni], acc2[mi][ni], 0, 0, 0);
                acc2[mi][ni] = __builtin_amdgcn_mfma_f32_16x16x32_bf16(al[mi], bh[ni], acc2[mi][ni], 0, 0, 0);
            }
    }
    __syncthreads();   // all LDS A-frag reads done; safe to reuse buffer

    // ---- epilogue: relu(acc+bias) [*dinv] -> fp16 tile [32][TPAD] in LDS ----
    float dvo[2][4];
    if (SCALE_OUT) {
#pragma unroll
        for (int mi = 0; mi < 2; mi++)
#pragma unroll
            for (int j = 0; j < 4; j++) {
                int row = brow + mi * 16 + lg * 4 + j;
                dvo[mi][j] = (row < n) ? dinv[row] : 0.f;
            }
    }
#pragma unroll
    for (int ni = 0; ni < 4; ni++) {
        int col = bcol + ni * 16 + lr;
        float bv = bias[col];
#pragma unroll
        for (int mi = 0; mi < 2; mi++)
#pragma unroll
            for (int j = 0; j < 4; j++) {
                int r = mi * 16 + lg * 4 + j;
                float o = fmaxf(acc2[mi][ni][j] + bv, 0.f);
                if (SCALE_OUT) o *= dvo[mi][j];
                *(__half*)&LB[r * TPAD + col] = __float2half_rn(o);
            }
    }
    __syncthreads();

    // ---- cooperative write-out: 1024 x 16B chunks (512B/row) ----
#pragma unroll
    for (int q = 0; q < 4; q++) {
        int idx = t + q * 256;          // [0,1024)
        int row = idx >> 5, c = idx & 31;
        int vv = brow + row;
        if (vv < n)
            *(uint4*)(Aout + (size_t)vv * 256 + c * 8) = *(const uint4*)&LB[row * TPAD + c * 8];
    }
}

// ---------------- pooling (mean + max over rows) from hpack fp16 --------------

__global__ __launch_bounds__(256) void pool_packed(const short* __restrict__ P, int n,
                                                   float* __restrict__ pool_sum, int* __restrict__ pool_max) {
    int t = threadIdx.x;   // column
    int chunk = (n + gridDim.x - 1) / gridDim.x;
    int r0 = blockIdx.x * chunk, r1 = min(n, r0 + chunk);
    float s = 0.f, mx = 0.f;
    for (int r = r0; r < r1; r++) {
        float v = __half2float(*(const __half*)&P[(size_t)r * 256 + t]);
        s += v;
        mx = fmaxf(mx, v);
    }
    atomicAdd(&pool_sum[t], s);
    atomicMax(&pool_max[t], __float_as_int(mx));
}

// ---------------- MLP head, stage 1: hid = relu(g @ Wp1 + bp1), 8 blocks ------

__global__ __launch_bounds__(256) void head1(const float* __restrict__ pool_sum, const int* __restrict__ pool_max,
                                             const float* __restrict__ Wp1, const float* __restrict__ bp1,
                                             float* __restrict__ hid, float invn) {
    __shared__ float red[8][33];
    int t = threadIdx.x, cl = t & 31, w = t >> 5;
    int col = blockIdx.x * 32 + cl;
    float p = 0.f;
    for (int j = w * 64; j < w * 64 + 64; j++) {
        float g = (j < HID) ? pool_sum[j] * invn : __int_as_float(pool_max[j - HID]);
        p = fmaf(g, Wp1[(size_t)j * HID + col], p);
    }
    red[w][cl] = p;
    __syncthreads();
    if (w == 0) {
        float a = 0.f;
#pragma unroll
        for (int k = 0; k < 8; k++) a += red[k][cl];
        hid[col] = fmaxf(a + bp1[col], 0.f);
    }
}

// ---------------- MLP head, stage 2: out = hid @ Wp2 + bp2, 1 block -----------

__global__ __launch_bounds__(128) void head2(const float* __restrict__ hid,
                                             const float* __restrict__ Wp2, const float* __restrict__ bp2,
                                             float* __restrict__ out) {
    int t = threadIdx.x;   // 128
    float a = bp2[t];
#pragma unroll 8
    for (int j = 0; j < HID; j++) a = fmaf(hid[j], Wp2[(size_t)j * DEMB + t], a);
    out[t] = a;
}

// ---------------- launcher ----------------

extern "C" void kernel_launch(void* const* d_in, const int* in_sizes, int n_in,
                              void* d_out, int out_size, void* d_ws, size_t ws_size,
                              hipStream_t stream) {
    const float* x   = (const float*)d_in[0];
    const int*   ei  = (const int*)d_in[1];
    const float* W1  = (const float*)d_in[2];
    const float* b1  = (const float*)d_in[3];
    const float* W2  = (const float*)d_in[4];
    const float* b2  = (const float*)d_in[5];
    const float* Wc  = (const float*)d_in[6];
    const float* bc  = (const float*)d_in[7];
    const float* Wp1 = (const float*)d_in[8];
    const float* bp1 = (const float*)d_in[9];
    const float* Wp2 = (const float*)d_in[10];
    const float* bp2 = (const float*)d_in[11];
    float* out = (float*)d_out;

    int N = in_sizes[0] / FIN;
    int E = in_sizes[1] / 2;
    int nb32 = (N + 31) / 32;
    int R = nb32 * 32;                   // padded rows for hpack buffers

    char* base = (char*)d_ws;
    short* actA = (short*)base;                          // [R,256] fp16 hpack
    short* actB = (short*)(base + (size_t)R * 512);      // [R,256] fp16 hpack
    int*   counts  = (int*)(base + 2 * (size_t)R * 512); // [N]
    int*   row_ptr = counts + N;                         // [N+1]
    int*   cursor  = row_ptr + (N + 1);                  // [N]
    int*   adj     = cursor + N;                         // [E]
    float* dinvp   = (float*)(adj + E);                  // [N]
    float* pool_sum = dinvp + N;                         // [HID]
    int*   pool_max = (int*)(pool_sum + HID);            // [HID]
    int*   chunkSums = pool_max + HID;                   // [<=64]
    float* hidbuf  = (float*)(chunkSums + 64);           // [HID]
    short* PH = (short*)((((uintptr_t)(hidbuf + HID)) + 15) & ~(uintptr_t)15);
    short* PL = PH + 278528;
    const int oW1 = 0, oW2 = 16384, oC0 = 81920, oC1 = 147456, oC2 = 212992;

    int nch = (N + 1023) / 1024;
    int nb256 = (N + 255) / 256;
    int eb256 = (E + 255) / 256;

    zero_pack<<<nb256 + 64 + 4 * 256, 256, 0, stream>>>(counts, N, pool_sum, pool_max, nb256,
                                                        W1, W2, Wc, PH, PL);
    hist_kernel<<<eb256, 256, 0, stream>>>(ei, E, counts);
    scan_partial<<<nch, 256, 0, stream>>>(counts, N, chunkSums, dinvp);
    scan_final<<<nch, 256, 0, stream>>>(counts, N, chunkSums, row_ptr, cursor);
    fill_kernel<<<eb256, 256, 0, stream>>>(ei, E, cursor, adj);

    // fused encoder: actA = hpack(dinv * (relu(x@W1+b1)@W2 + b2))
    encoder_fused<<<nb32, 256, 0, stream>>>(x, PH + oW1, PL + oW1, PH + oW2, PL + oW2,
                                            b1, b2, dinvp, actA, N);

    // fused GCN layers: out = relu((S@h)@Wc + bc); pre-scaled except last
    layer_fused<true><<<nb32, 256, 0, stream>>>(actA, row_ptr, adj, dinvp, PH + oC0, PL + oC0, bc + 0 * HID, actB, N);
    layer_fused<true><<<nb32, 256, 0, stream>>>(actB, row_ptr, adj, dinvp, PH + oC1, PL + oC1, bc + 1 * HID, actA, N);
    layer_fused<false><<<nb32, 256, 0, stream>>>(actA, row_ptr, adj, dinvp, PH + oC2, PL + oC2, bc + 2 * HID, actB, N);

    // pooling + head
    pool_packed<<<256, 256, 0, stream>>>(actB, N, pool_sum, pool_max);
    head1<<<8, 256, 0, stream>>>(pool_sum, pool_max, Wp1, bp1, hidbuf, 1.0f / (float)N);
    head2<<<1, 128, 0, stream>>>(hidbuf, Wp2, bp2, out);
}

// Round 16
// 477.705 us; speedup vs baseline: 1.0786x; 1.0074x over previous
//
#include <hip/hip_runtime.h>
#include <hip/hip_fp16.h>

#define FIN 64
#define HID 256
#define DEMB 128
#define NLAYERS 3
#define TPAD 264

typedef __attribute__((ext_vector_type(8))) short bf16x8;
typedef __attribute__((ext_vector_type(4))) float f32x4;

__device__ inline short f2bf(float x) {               // RNE fp32 -> bf16 bits
    unsigned u = __float_as_uint(x);
    u += 0x7fff + ((u >> 16) & 1);
    return (short)(u >> 16);
}
__device__ inline float bf2f(short h) {
    return __uint_as_float(((unsigned)(unsigned short)h) << 16);
}

// Activation layout "hpack": per row r, 256 fp16 (512B contiguous), linear cols.
// Values PRE-SCALED by dinv[row] except after the last layer.

// add 4 fp16 cols (uint2) into fp32 acc
#define HADD(V) do { \
    __half2 p0 = *(__half2*)&(V).x, p1 = *(__half2*)&(V).y; \
    float2 f0 = __half22float2(p0), f1 = __half22float2(p1); \
    acc.x += f0.x; acc.y += f0.y; acc.z += f1.x; acc.w += f1.y; } while (0)

__device__ inline void split2(float a0, float a1, float a2, float a3, uint2& hw, uint2& lw) {
    short h0 = f2bf(a0), h1 = f2bf(a1), h2 = f2bf(a2), h3 = f2bf(a3);
    short l0 = f2bf(a0 - bf2f(h0)), l1 = f2bf(a1 - bf2f(h1));
    short l2 = f2bf(a2 - bf2f(h2)), l3 = f2bf(a3 - bf2f(h3));
    hw.x = (unsigned short)h0 | ((unsigned)(unsigned short)h1 << 16);
    hw.y = (unsigned short)h2 | ((unsigned)(unsigned short)h3 << 16);
    lw.x = (unsigned short)l0 | ((unsigned)(unsigned short)l1 << 16);
    lw.y = (unsigned short)l2 | ((unsigned)(unsigned short)l3 << 16);
}

// 8 fp16 (uint4) -> split-bf16 pair (ah, al), exact (fp16 subset of fp32)
__device__ inline void h8_to_bf16pair(uint4 V, bf16x8& ah, bf16x8& al) {
    const unsigned* w = (const unsigned*)&V;
    short hh[8], ll[8];
#pragma unroll
    for (int q = 0; q < 4; q++) {
        __half2 p = *(__half2*)&w[q];
        float2 f = __half22float2(p);
        short h0 = f2bf(f.x), h1 = f2bf(f.y);
        hh[2 * q] = h0; hh[2 * q + 1] = h1;
        ll[2 * q] = f2bf(f.x - bf2f(h0));
        ll[2 * q + 1] = f2bf(f.y - bf2f(h1));
    }
#pragma unroll
    for (int q = 0; q < 8; q++) { ah[q] = hh[q]; al[q] = ll[q]; }
}

// ---------------- zero + weight-pack combined (independent work) --------------

__global__ __launch_bounds__(256) void zero_pack(int* counts, int n, float* pool_sum, int* pool_max, int nzb,
                                                 const float* __restrict__ W1, const float* __restrict__ W2,
                                                 const float* __restrict__ Wc,
                                                 short* __restrict__ PH, short* __restrict__ PL) {
    if ((int)blockIdx.x < nzb) {
        int i = blockIdx.x * 256 + threadIdx.x;
        if (i < n) counts[i] = 0;
        if (i < HID) { pool_sum[i] = 0.0f; pool_max[i] = 0; }
        return;
    }
    int b = blockIdx.x - nzb, nn = threadIdx.x;
    const float* src; int k; size_t dst;
    if (b < 64) { src = W1; k = b; dst = 0; }
    else {
        int m = (b - 64) >> 8; k = (b - 64) & 255;
        src = (m == 0) ? W2 : (Wc + (size_t)(m - 1) * 65536);
        dst = 16384 + (size_t)m * 65536;
    }
    float w = src[(size_t)k * 256 + nn];
    short h = f2bf(w);
    short l = f2bf(w - bf2f(h));
    int o = ((k >> 3) * 256 + nn) * 8 + (k & 7);
    PH[dst + o] = h; PL[dst + o] = l;
}

__global__ __launch_bounds__(256) void hist_kernel(const int* __restrict__ ei, int E, int* __restrict__ counts) {
    int e = blockIdx.x * 256 + threadIdx.x;
    if (e < E) atomicAdd(&counts[ei[E + e]], 1);
}

__global__ __launch_bounds__(256) void scan_partial(const int* __restrict__ counts, int n,
                                                    int* __restrict__ chunkSums, float* __restrict__ dinv) {
    __shared__ int s[256];
    int t = threadIdx.x, base = blockIdx.x * 1024;
    int sum = 0;
#pragma unroll
    for (int j = 0; j < 4; j++) {
        int i = base + t * 4 + j;
        if (i < n) {
            int c = counts[i];
            sum += c;
            dinv[i] = rsqrtf((float)(c + 1));
        }
    }
    s[t] = sum; __syncthreads();
    for (int off = 128; off > 0; off >>= 1) { if (t < off) s[t] += s[t + off]; __syncthreads(); }
    if (t == 0) chunkSums[blockIdx.x] = s[0];
}

// scan_final derives its own chunk offset (serial prefix over <=64 sums)
__global__ __launch_bounds__(256) void scan_final(const int* __restrict__ counts, int n,
                                                  const int* __restrict__ chunkSums, int* __restrict__ row_ptr,
                                                  int* __restrict__ cursor) {
    __shared__ int s[256];
    __shared__ int base_s;
    int t = threadIdx.x, base = blockIdx.x * 1024;
    if (t == 0) {
        int a = 0;
        for (int i = 0; i < (int)blockIdx.x; i++) a += chunkSums[i];
        base_s = a;
    }
    int v[4]; int sum = 0;
#pragma unroll
    for (int j = 0; j < 4; j++) { int i = base + t * 4 + j; v[j] = (i < n) ? counts[i] : 0; sum += v[j]; }
    s[t] = sum; __syncthreads();
    for (int off = 1; off < 256; off <<= 1) {
        int x = (t >= off) ? s[t - off] : 0;
        __syncthreads();
        s[t] += x;
        __syncthreads();
    }
    int run = base_s + (s[t] - sum);
#pragma unroll
    for (int j = 0; j < 4; j++) {
        int i = base + t * 4 + j;
        if (i < n) {
            row_ptr[i] = run; cursor[i] = run; run += v[j];
            if (i == n - 1) row_ptr[n] = run;
        }
    }
}

__global__ __launch_bounds__(256) void fill_kernel(const int* __restrict__ ei, int E,
                                                   int* __restrict__ cursor, int* __restrict__ adj) {
    int e = blockIdx.x * 256 + threadIdx.x;
    if (e < E) {
        int s = ei[e], d = ei[E + e];
        int p = atomicAdd(&cursor[d], 1);
        adj[p] = s;
    }
}

// ---------------- fused encoder: out = hpack(dinv * (relu(x@W1+b1)@W2 + b2)) --
// BM=32 rows/block, 4 waves. LDS LB[8448] shorts (16896 B).

__global__ __launch_bounds__(256) void encoder_fused(const float* __restrict__ x,
                                                     const short* __restrict__ PB1h, const short* __restrict__ PB1l,
                                                     const short* __restrict__ PB2h, const short* __restrict__ PB2l,
                                                     const float* __restrict__ b1, const float* __restrict__ b2,
                                                     const float* __restrict__ dinv,
                                                     short* __restrict__ Aout, int n) {
    __shared__ short LB[8448];
    int t = threadIdx.x, lane = t & 63, wv = t >> 6;
    int lr = lane & 15, lg = lane >> 4;
    int brow = blockIdx.x * 32;
    int bcol = wv * 64;

    // ---- stage 1 load: x tile 32x64 -> split-bf16 A frags ----
#pragma unroll
    for (int l = 0; l < 2; l++) {
        int lin = t + l * 256;
        int r = lin >> 4, kq = (lin & 15) * 4;
        int row = brow + r;
        float4 v = (row < n) ? *(const float4*)(x + (size_t)row * FIN + kq)
                             : make_float4(0.f, 0.f, 0.f, 0.f);
        uint2 hw, lw; split2(v.x, v.y, v.z, v.w, hw, lw);
        int g = kq >> 3, i0 = kq & 7;
        *(uint2*)&LB[(g * 33 + r) * 8 + i0] = hw;
        *(uint2*)&LB[2112 + (g * 33 + r) * 8 + i0] = lw;
    }
    __syncthreads();

    // ---- stage 1 MFMA: t = x@W1, K=64 ----
    f32x4 acc1[2][4] = {};
#pragma unroll
    for (int s = 0; s < 2; s++) {
        int sl = s * 4 + lg;
        bf16x8 ah[2], al[2], bh[4], bl[4];
#pragma unroll
        for (int mi = 0; mi < 2; mi++) {
            ah[mi] = *(bf16x8*)&LB[(sl * 33 + mi * 16 + lr) * 8];
            al[mi] = *(bf16x8*)&LB[2112 + (sl * 33 + mi * 16 + lr) * 8];
        }
        const short* pbh = PB1h + ((size_t)sl * 256 + bcol + lr) * 8;
        const short* pbl = PB1l + ((size_t)sl * 256 + bcol + lr) * 8;
#pragma unroll
        for (int ni = 0; ni < 4; ni++) {
            bh[ni] = *(const bf16x8*)(pbh + ni * 128);
            bl[ni] = *(const bf16x8*)(pbl + ni * 128);
        }
#pragma unroll
        for (int mi = 0; mi < 2; mi++)
#pragma unroll
            for (int ni = 0; ni < 4; ni++) {
                acc1[mi][ni] = __builtin_amdgcn_mfma_f32_16x16x32_bf16(ah[mi], bh[ni], acc1[mi][ni], 0, 0, 0);
                acc1[mi][ni] = __builtin_amdgcn_mfma_f32_16x16x32_bf16(ah[mi], bl[ni], acc1[mi][ni], 0, 0, 0);
                acc1[mi][ni] = __builtin_amdgcn_mfma_f32_16x16x32_bf16(al[mi], bh[ni], acc1[mi][ni], 0, 0, 0);
            }
    }
    __syncthreads();   // stage-1 frag reads done; LB reusable

    // ---- t = relu(acc1 + b1) -> fp16 [32][TPAD] in LDS ----
#pragma unroll
    for (int ni = 0; ni < 4; ni++) {
        int col = bcol + ni * 16 + lr;
        float bv = b1[col];
#pragma unroll
        for (int mi = 0; mi < 2; mi++)
#pragma unroll
            for (int j = 0; j < 4; j++) {
                int r = mi * 16 + lg * 4 + j;
                float o = fmaxf(acc1[mi][ni][j] + bv, 0.f);
                *(__half*)&LB[r * TPAD + col] = __float2half_rn(o);
            }
    }
    __syncthreads();

    // ---- stage 2 MFMA: out = t@W2, K=256 (t split fp16->bf16 pair at read) ----
    f32x4 acc2[2][4] = {};
#pragma unroll
    for (int s = 0; s < 8; s++) {
        int sl = s * 4 + lg;
        bf16x8 ah[2], al[2], bh[4], bl[4];
#pragma unroll
        for (int mi = 0; mi < 2; mi++) {
            uint4 V = *(uint4*)&LB[(mi * 16 + lr) * TPAD + sl * 8];
            h8_to_bf16pair(V, ah[mi], al[mi]);
        }
        const short* pbh = PB2h + ((size_t)sl * 256 + bcol + lr) * 8;
        const short* pbl = PB2l + ((size_t)sl * 256 + bcol + lr) * 8;
#pragma unroll
        for (int ni = 0; ni < 4; ni++) {
            bh[ni] = *(const bf16x8*)(pbh + ni * 128);
            bl[ni] = *(const bf16x8*)(pbl + ni * 128);
        }
#pragma unroll
        for (int mi = 0; mi < 2; mi++)
#pragma unroll
            for (int ni = 0; ni < 4; ni++) {
                acc2[mi][ni] = __builtin_amdgcn_mfma_f32_16x16x32_bf16(ah[mi], bh[ni], acc2[mi][ni], 0, 0, 0);
                acc2[mi][ni] = __builtin_amdgcn_mfma_f32_16x16x32_bf16(ah[mi], bl[ni], acc2[mi][ni], 0, 0, 0);
                acc2[mi][ni] = __builtin_amdgcn_mfma_f32_16x16x32_bf16(al[mi], bh[ni], acc2[mi][ni], 0, 0, 0);
            }
    }
    __syncthreads();   // t reads done; LB reusable

    // ---- epilogue: dinv * (acc2 + b2) -> fp16 tile [32][TPAD] in LDS ----
    float dvo[2][4];
#pragma unroll
    for (int mi = 0; mi < 2; mi++)
#pragma unroll
        for (int j = 0; j < 4; j++) {
            int row = brow + mi * 16 + lg * 4 + j;
            dvo[mi][j] = (row < n) ? dinv[row] : 0.f;
        }
#pragma unroll
    for (int ni = 0; ni < 4; ni++) {
        int col = bcol + ni * 16 + lr;
        float bv = b2[col];
#pragma unroll
        for (int mi = 0; mi < 2; mi++)
#pragma unroll
            for (int j = 0; j < 4; j++) {
                int r = mi * 16 + lg * 4 + j;
                float o = (acc2[mi][ni][j] + bv) * dvo[mi][j];
                *(__half*)&LB[r * TPAD + col] = __float2half_rn(o);
            }
    }
    __syncthreads();

    // ---- cooperative write-out: 1024 x 16B chunks (512B/row) ----
#pragma unroll
    for (int q = 0; q < 4; q++) {
        int idx = t + q * 256;          // [0,1024)
        int row = idx >> 5, c = idx & 31;
        int vv = brow + row;
        if (vv < n)
            *(uint4*)(Aout + (size_t)vv * 256 + c * 8) = *(const uint4*)&LB[row * TPAD + c * 8];
    }
}

// ---------------- fused GCN layer (R14-proven config) -------------------------
// Input hpack fp16 PRE-SCALED by dinv => gather is a pure fp16 row sum.
// BM=16 rows/block, 4 waves; 8-deep gather (uint2/lane, VGPR~36).
// LDS aliased: bf16 A-frags (8704 sh) / fp16 out tile (4096 sh).

template<bool SCALE_OUT>
__global__ __launch_bounds__(256) void layer_fused(const short* __restrict__ Ain,
                                                   const int* __restrict__ row_ptr, const int* __restrict__ adj,
                                                   const float* __restrict__ dinv,
                                                   const short* __restrict__ PBh, const short* __restrict__ PBl,
                                                   const float* __restrict__ bias,
                                                   short* __restrict__ Aout, int n) {
    __shared__ short LB[8704];
    int t = threadIdx.x, lane = t & 63, wv = t >> 6;
    int lr = lane & 15, lg = lane >> 4;
    int brow = blockIdx.x * 16;
    int slab = lane >> 1, i0 = (lane & 1) * 4;
    int loff = lane * 4;                            // fp16 col base (4 cols/lane)

    // ---- phase 1: gather + sum (each wave: 4 dst rows) ----
    for (int it = 0; it < 4; ++it) {
        int r = wv * 4 + it, v = brow + r;
        if (v >= n) break;                          // wave-uniform
        float dv = dinv[v];
        uint2 V0 = *(const uint2*)(Ain + (size_t)v * 256 + loff);
        float4 acc = make_float4(0.f, 0.f, 0.f, 0.f);
        HADD(V0);
        int e = row_ptr[v], end = row_ptr[v + 1];
        for (; e + 8 <= end; e += 8) {
            int s8[8]; uint2 V[8];
#pragma unroll
            for (int j = 0; j < 8; j++) s8[j] = adj[e + j];
#pragma unroll
            for (int j = 0; j < 8; j++) V[j] = *(const uint2*)(Ain + (size_t)s8[j] * 256 + loff);
#pragma unroll
            for (int j = 0; j < 8; j++) HADD(V[j]);
        }
        for (; e + 4 <= end; e += 4) {
            int s4[4]; uint2 V[4];
#pragma unroll
            for (int j = 0; j < 4; j++) s4[j] = adj[e + j];
#pragma unroll
            for (int j = 0; j < 4; j++) V[j] = *(const uint2*)(Ain + (size_t)s4[j] * 256 + loff);
#pragma unroll
            for (int j = 0; j < 4; j++) HADD(V[j]);
        }
        for (; e < end; e++) {
            uint2 V = *(const uint2*)(Ain + (size_t)adj[e] * 256 + loff);
            HADD(V);
        }
        uint2 hw, lw;
        split2(dv * acc.x, dv * acc.y, dv * acc.z, dv * acc.w, hw, lw);
        *(uint2*)&LB[(slab * 17 + r) * 8 + i0] = hw;
        *(uint2*)&LB[4352 + (slab * 17 + r) * 8 + i0] = lw;
    }
    __syncthreads();

    // ---- phase 2: 3-term MFMA, wave wv -> cols [wv*64, wv*64+64) ----
    int bcol = wv * 64;
    f32x4 acc2[4] = {};
#pragma unroll
    for (int s = 0; s < 8; ++s) {
        int sl = s * 4 + lg;
        bf16x8 ah = *(bf16x8*)&LB[(sl * 17 + lr) * 8];
        bf16x8 al = *(bf16x8*)&LB[4352 + (sl * 17 + lr) * 8];
        const short* pbh = PBh + ((size_t)sl * 256 + bcol + lr) * 8;
        const short* pbl = PBl + ((size_t)sl * 256 + bcol + lr) * 8;
        bf16x8 bh[4], bl[4];
#pragma unroll
        for (int ni = 0; ni < 4; ni++) {
            bh[ni] = *(const bf16x8*)(pbh + ni * 128);
            bl[ni] = *(const bf16x8*)(pbl + ni * 128);
        }
#pragma unroll
        for (int ni = 0; ni < 4; ni++) {
            acc2[ni] = __builtin_amdgcn_mfma_f32_16x16x32_bf16(ah, bh[ni], acc2[ni], 0, 0, 0);
            acc2[ni] = __builtin_amdgcn_mfma_f32_16x16x32_bf16(ah, bl[ni], acc2[ni], 0, 0, 0);
            acc2[ni] = __builtin_amdgcn_mfma_f32_16x16x32_bf16(al, bh[ni], acc2[ni], 0, 0, 0);
        }
    }
    __syncthreads();   // all LDS A-frag reads done; safe to reuse buffer

    // ---- epilogue: relu(acc+bias) [*dinv] -> fp16 tile [16][256] in LDS ----
    float dvo[4];
    if (SCALE_OUT) {
#pragma unroll
        for (int j = 0; j < 4; j++) {
            int row = brow + lg * 4 + j;
            dvo[j] = (row < n) ? dinv[row] : 0.f;
        }
    }
#pragma unroll
    for (int ni = 0; ni < 4; ni++) {
        int col = bcol + ni * 16 + lr;
        float bv = bias[col];
#pragma unroll
        for (int j = 0; j < 4; j++) {
            int r = lg * 4 + j;
            float o = fmaxf(acc2[ni][j] + bv, 0.f);
            if (SCALE_OUT) o *= dvo[j];
            *(__half*)&LB[r * 256 + col] = __float2half_rn(o);
        }
    }
    __syncthreads();

    // ---- cooperative write-out: 512 x 16B chunks (512B/row) ----
#pragma unroll
    for (int q = 0; q < 2; q++) {
        int idx = t + q * 256;          // [0,512)
        int row = idx >> 5, c = idx & 31;
        int vv = brow + row;
        if (vv < n)
            *(uint4*)(Aout + (size_t)vv * 256 + c * 8) = *(const uint4*)&LB[row * 256 + c * 8];
    }
}

// ---------------- pooling (mean + max over rows) from hpack fp16 --------------

__global__ __launch_bounds__(256) void pool_packed(const short* __restrict__ P, int n,
                                                   float* __restrict__ pool_sum, int* __restrict__ pool_max) {
    int t = threadIdx.x;   // column
    int chunk = (n + gridDim.x - 1) / gridDim.x;
    int r0 = blockIdx.x * chunk, r1 = min(n, r0 + chunk);
    float s = 0.f, mx = 0.f;
    for (int r = r0; r < r1; r++) {
        float v = __half2float(*(const __half*)&P[(size_t)r * 256 + t]);
        s += v;
        mx = fmaxf(mx, v);
    }
    atomicAdd(&pool_sum[t], s);
    atomicMax(&pool_max[t], __float_as_int(mx));
}

// ---------------- MLP head, stage 1: hid = relu(g @ Wp1 + bp1), 8 blocks ------

__global__ __launch_bounds__(256) void head1(const float* __restrict__ pool_sum, const int* __restrict__ pool_max,
                                             const float* __restrict__ Wp1, const float* __restrict__ bp1,
                                             float* __restrict__ hid, float invn) {
    __shared__ float red[8][33];
    int t = threadIdx.x, cl = t & 31, w = t >> 5;
    int col = blockIdx.x * 32 + cl;
    float p = 0.f;
    for (int j = w * 64; j < w * 64 + 64; j++) {
        float g = (j < HID) ? pool_sum[j] * invn : __int_as_float(pool_max[j - HID]);
        p = fmaf(g, Wp1[(size_t)j * HID + col], p);
    }
    red[w][cl] = p;
    __syncthreads();
    if (w == 0) {
        float a = 0.f;
#pragma unroll
        for (int k = 0; k < 8; k++) a += red[k][cl];
        hid[col] = fmaxf(a + bp1[col], 0.f);
    }
}

// ---------------- MLP head, stage 2: out = hid @ Wp2 + bp2, 1 block -----------

__global__ __launch_bounds__(128) void head2(const float* __restrict__ hid,
                                             const float* __restrict__ Wp2, const float* __restrict__ bp2,
                                             float* __restrict__ out) {
    int t = threadIdx.x;   // 128
    float a = bp2[t];
#pragma unroll 8
    for (int j = 0; j < HID; j++) a = fmaf(hid[j], Wp2[(size_t)j * DEMB + t], a);
    out[t] = a;
}

// ---------------- launcher ----------------

extern "C" void kernel_launch(void* const* d_in, const int* in_sizes, int n_in,
                              void* d_out, int out_size, void* d_ws, size_t ws_size,
                              hipStream_t stream) {
    const float* x   = (const float*)d_in[0];
    const int*   ei  = (const int*)d_in[1];
    const float* W1  = (const float*)d_in[2];
    const float* b1  = (const float*)d_in[3];
    const float* W2  = (const float*)d_in[4];
    const float* b2  = (const float*)d_in[5];
    const float* Wc  = (const float*)d_in[6];
    const float* bc  = (const float*)d_in[7];
    const float* Wp1 = (const float*)d_in[8];
    const float* bp1 = (const float*)d_in[9];
    const float* Wp2 = (const float*)d_in[10];
    const float* bp2 = (const float*)d_in[11];
    float* out = (float*)d_out;

    int N = in_sizes[0] / FIN;
    int E = in_sizes[1] / 2;
    int nb32 = (N + 31) / 32;
    int nb16 = (N + 15) / 16;
    int R = nb32 * 32;                   // padded rows for hpack buffers

    char* base = (char*)d_ws;
    short* actA = (short*)base;                          // [R,256] fp16 hpack
    short* actB = (short*)(base + (size_t)R * 512);      // [R,256] fp16 hpack
    int*   counts  = (int*)(base + 2 * (size_t)R * 512); // [N]
    int*   row_ptr = counts + N;                         // [N+1]
    int*   cursor  = row_ptr + (N + 1);                  // [N]
    int*   adj     = cursor + N;                         // [E]
    float* dinvp   = (float*)(adj + E);                  // [N]
    float* pool_sum = dinvp + N;                         // [HID]
    int*   pool_max = (int*)(pool_sum + HID);            // [HID]
    int*   chunkSums = pool_max + HID;                   // [<=64]
    float* hidbuf  = (float*)(chunkSums + 64);           // [HID]
    short* PH = (short*)((((uintptr_t)(hidbuf + HID)) + 15) & ~(uintptr_t)15);
    short* PL = PH + 278528;
    const int oW1 = 0, oW2 = 16384, oC0 = 81920, oC1 = 147456, oC2 = 212992;

    int nch = (N + 1023) / 1024;
    int nb256 = (N + 255) / 256;
    int eb256 = (E + 255) / 256;

    zero_pack<<<nb256 + 64 + 4 * 256, 256, 0, stream>>>(counts, N, pool_sum, pool_max, nb256,
                                                        W1, W2, Wc, PH, PL);
    hist_kernel<<<eb256, 256, 0, stream>>>(ei, E, counts);
    scan_partial<<<nch, 256, 0, stream>>>(counts, N, chunkSums, dinvp);
    scan_final<<<nch, 256, 0, stream>>>(counts, N, chunkSums, row_ptr, cursor);
    fill_kernel<<<eb256, 256, 0, stream>>>(ei, E, cursor, adj);

    // fused encoder: actA = hpack(dinv * (relu(x@W1+b1)@W2 + b2))
    encoder_fused<<<nb32, 256, 0, stream>>>(x, PH + oW1, PL + oW1, PH + oW2, PL + oW2,
                                            b1, b2, dinvp, actA, N);

    // fused GCN layers: out = relu((S@h)@Wc + bc); pre-scaled except last
    layer_fused<true><<<nb16, 256, 0, stream>>>(actA, row_ptr, adj, dinvp, PH + oC0, PL + oC0, bc + 0 * HID, actB, N);
    layer_fused<true><<<nb16, 256, 0, stream>>>(actB, row_ptr, adj, dinvp, PH + oC1, PL + oC1, bc + 1 * HID, actA, N);
    layer_fused<false><<<nb16, 256, 0, stream>>>(actA, row_ptr, adj, dinvp, PH + oC2, PL + oC2, bc + 2 * HID, actB, N);

    // pooling + head
    pool_packed<<<256, 256, 0, stream>>>(actB, N, pool_sum, pool_max);
    head1<<<8, 256, 0, stream>>>(pool_sum, pool_max, Wp1, bp1, hidbuf, 1.0f / (float)N);
    head2<<<1, 128, 0, stream>>>(hidbuf, Wp2, bp2, out);
}

// Round 17
// 474.743 us; speedup vs baseline: 1.0853x; 1.0062x over previous
//
#include <hip/hip_runtime.h>
#include <hip/hip_fp16.h>

#define FIN 64
#define HID 256
#define DEMB 128
#define NLAYERS 3
#define TPAD 264

typedef __attribute__((ext_vector_type(8))) short bf16x8;
typedef __attribute__((ext_vector_type(4))) float f32x4;

__device__ inline short f2bf(float x) {               // RNE fp32 -> bf16 bits
    unsigned u = __float_as_uint(x);
    u += 0x7fff + ((u >> 16) & 1);
    return (short)(u >> 16);
}
__device__ inline float bf2f(short h) {
    return __uint_as_float(((unsigned)(unsigned short)h) << 16);
}

// Activation layout "hpack": per row r, 256 fp16 (512B contiguous), linear cols.
// Values PRE-SCALED by dinv[row] except after the last layer.

// add 4 fp16 cols (uint2) into fp32 acc
#define HADD(V) do { \
    __half2 p0 = *(__half2*)&(V).x, p1 = *(__half2*)&(V).y; \
    float2 f0 = __half22float2(p0), f1 = __half22float2(p1); \
    acc.x += f0.x; acc.y += f0.y; acc.z += f1.x; acc.w += f1.y; } while (0)

__device__ inline void split2(float a0, float a1, float a2, float a3, uint2& hw, uint2& lw) {
    short h0 = f2bf(a0), h1 = f2bf(a1), h2 = f2bf(a2), h3 = f2bf(a3);
    short l0 = f2bf(a0 - bf2f(h0)), l1 = f2bf(a1 - bf2f(h1));
    short l2 = f2bf(a2 - bf2f(h2)), l3 = f2bf(a3 - bf2f(h3));
    hw.x = (unsigned short)h0 | ((unsigned)(unsigned short)h1 << 16);
    hw.y = (unsigned short)h2 | ((unsigned)(unsigned short)h3 << 16);
    lw.x = (unsigned short)l0 | ((unsigned)(unsigned short)l1 << 16);
    lw.y = (unsigned short)l2 | ((unsigned)(unsigned short)l3 << 16);
}

// 8 fp16 (uint4) -> split-bf16 pair (ah, al), exact (fp16 subset of fp32)
__device__ inline void h8_to_bf16pair(uint4 V, bf16x8& ah, bf16x8& al) {
    const unsigned* w = (const unsigned*)&V;
    short hh[8], ll[8];
#pragma unroll
    for (int q = 0; q < 4; q++) {
        __half2 p = *(__half2*)&w[q];
        float2 f = __half22float2(p);
        short h0 = f2bf(f.x), h1 = f2bf(f.y);
        hh[2 * q] = h0; hh[2 * q + 1] = h1;
        ll[2 * q] = f2bf(f.x - bf2f(h0));
        ll[2 * q + 1] = f2bf(f.y - bf2f(h1));
    }
#pragma unroll
    for (int q = 0; q < 8; q++) { ah[q] = hh[q]; al[q] = ll[q]; }
}

// ---------------- zero + weight-pack combined ----------------

__global__ __launch_bounds__(256) void zero_pack(int* counts, int n, float* pool_sum, int* pool_max, int nzb,
                                                 const float* __restrict__ W1, const float* __restrict__ W2,
                                                 const float* __restrict__ Wc,
                                                 short* __restrict__ PH, short* __restrict__ PL) {
    if ((int)blockIdx.x < nzb) {
        int i = blockIdx.x * 256 + threadIdx.x;
        if (i < n) counts[i] = 0;
        if (i < HID) { pool_sum[i] = 0.0f; pool_max[i] = 0; }
        return;
    }
    int b = blockIdx.x - nzb, nn = threadIdx.x;
    const float* src; int k; size_t dst;
    if (b < 64) { src = W1; k = b; dst = 0; }
    else {
        int m = (b - 64) >> 8; k = (b - 64) & 255;
        src = (m == 0) ? W2 : (Wc + (size_t)(m - 1) * 65536);
        dst = 16384 + (size_t)m * 65536;
    }
    float w = src[(size_t)k * 256 + nn];
    short h = f2bf(w);
    short l = f2bf(w - bf2f(h));
    int o = ((k >> 3) * 256 + nn) * 8 + (k & 7);
    PH[dst + o] = h; PL[dst + o] = l;
}

__global__ __launch_bounds__(256) void hist_kernel(const int* __restrict__ ei, int E, int* __restrict__ counts) {
    int e = blockIdx.x * 256 + threadIdx.x;
    if (e < E) atomicAdd(&counts[ei[E + e]], 1);
}

__global__ __launch_bounds__(256) void scan_partial(const int* __restrict__ counts, int n,
                                                    int* __restrict__ chunkSums, float* __restrict__ dinv) {
    __shared__ int s[256];
    int t = threadIdx.x, base = blockIdx.x * 1024;
    int sum = 0;
#pragma unroll
    for (int j = 0; j < 4; j++) {
        int i = base + t * 4 + j;
        if (i < n) {
            int c = counts[i];
            sum += c;
            dinv[i] = rsqrtf((float)(c + 1));
        }
    }
    s[t] = sum; __syncthreads();
    for (int off = 128; off > 0; off >>= 1) { if (t < off) s[t] += s[t + off]; __syncthreads(); }
    if (t == 0) chunkSums[blockIdx.x] = s[0];
}

__global__ __launch_bounds__(256) void scan_final(const int* __restrict__ counts, int n,
                                                  const int* __restrict__ chunkSums, int* __restrict__ row_ptr,
                                                  int* __restrict__ cursor) {
    __shared__ int s[256];
    __shared__ int base_s;
    int t = threadIdx.x, base = blockIdx.x * 1024;
    if (t == 0) {
        int a = 0;
        for (int i = 0; i < (int)blockIdx.x; i++) a += chunkSums[i];
        base_s = a;
    }
    int v[4]; int sum = 0;
#pragma unroll
    for (int j = 0; j < 4; j++) { int i = base + t * 4 + j; v[j] = (i < n) ? counts[i] : 0; sum += v[j]; }
    s[t] = sum; __syncthreads();
    for (int off = 1; off < 256; off <<= 1) {
        int x = (t >= off) ? s[t - off] : 0;
        __syncthreads();
        s[t] += x;
        __syncthreads();
    }
    int run = base_s + (s[t] - sum);
#pragma unroll
    for (int j = 0; j < 4; j++) {
        int i = base + t * 4 + j;
        if (i < n) {
            row_ptr[i] = run; cursor[i] = run; run += v[j];
            if (i == n - 1) row_ptr[n] = run;
        }
    }
}

__global__ __launch_bounds__(256) void fill_kernel(const int* __restrict__ ei, int E,
                                                   int* __restrict__ cursor, int* __restrict__ adj) {
    int e = blockIdx.x * 256 + threadIdx.x;
    if (e < E) {
        int s = ei[e], d = ei[E + e];
        int p = atomicAdd(&cursor[d], 1);
        adj[p] = s;
    }
}

// ---------------- fused encoder: out = hpack(dinv * (relu(x@W1+b1)@W2 + b2)) --
// BM=32 rows/block, 4 waves. LDS LB[8448] shorts (16896 B).

__global__ __launch_bounds__(256) void encoder_fused(const float* __restrict__ x,
                                                     const short* __restrict__ PB1h, const short* __restrict__ PB1l,
                                                     const short* __restrict__ PB2h, const short* __restrict__ PB2l,
                                                     const float* __restrict__ b1, const float* __restrict__ b2,
                                                     const float* __restrict__ dinv,
                                                     short* __restrict__ Aout, int n) {
    __shared__ short LB[8448];
    int t = threadIdx.x, lane = t & 63, wv = t >> 6;
    int lr = lane & 15, lg = lane >> 4;
    int brow = blockIdx.x * 32;
    int bcol = wv * 64;

#pragma unroll
    for (int l = 0; l < 2; l++) {
        int lin = t + l * 256;
        int r = lin >> 4, kq = (lin & 15) * 4;
        int row = brow + r;
        float4 v = (row < n) ? *(const float4*)(x + (size_t)row * FIN + kq)
                             : make_float4(0.f, 0.f, 0.f, 0.f);
        uint2 hw, lw; split2(v.x, v.y, v.z, v.w, hw, lw);
        int g = kq >> 3, i0 = kq & 7;
        *(uint2*)&LB[(g * 33 + r) * 8 + i0] = hw;
        *(uint2*)&LB[2112 + (g * 33 + r) * 8 + i0] = lw;
    }
    __syncthreads();

    f32x4 acc1[2][4] = {};
#pragma unroll
    for (int s = 0; s < 2; s++) {
        int sl = s * 4 + lg;
        bf16x8 ah[2], al[2], bh[4], bl[4];
#pragma unroll
        for (int mi = 0; mi < 2; mi++) {
            ah[mi] = *(bf16x8*)&LB[(sl * 33 + mi * 16 + lr) * 8];
            al[mi] = *(bf16x8*)&LB[2112 + (sl * 33 + mi * 16 + lr) * 8];
        }
        const short* pbh = PB1h + ((size_t)sl * 256 + bcol + lr) * 8;
        const short* pbl = PB1l + ((size_t)sl * 256 + bcol + lr) * 8;
#pragma unroll
        for (int ni = 0; ni < 4; ni++) {
            bh[ni] = *(const bf16x8*)(pbh + ni * 128);
            bl[ni] = *(const bf16x8*)(pbl + ni * 128);
        }
#pragma unroll
        for (int mi = 0; mi < 2; mi++)
#pragma unroll
            for (int ni = 0; ni < 4; ni++) {
                acc1[mi][ni] = __builtin_amdgcn_mfma_f32_16x16x32_bf16(ah[mi], bh[ni], acc1[mi][ni], 0, 0, 0);
                acc1[mi][ni] = __builtin_amdgcn_mfma_f32_16x16x32_bf16(ah[mi], bl[ni], acc1[mi][ni], 0, 0, 0);
                acc1[mi][ni] = __builtin_amdgcn_mfma_f32_16x16x32_bf16(al[mi], bh[ni], acc1[mi][ni], 0, 0, 0);
            }
    }
    __syncthreads();

#pragma unroll
    for (int ni = 0; ni < 4; ni++) {
        int col = bcol + ni * 16 + lr;
        float bv = b1[col];
#pragma unroll
        for (int mi = 0; mi < 2; mi++)
#pragma unroll
            for (int j = 0; j < 4; j++) {
                int r = mi * 16 + lg * 4 + j;
                float o = fmaxf(acc1[mi][ni][j] + bv, 0.f);
                *(__half*)&LB[r * TPAD + col] = __float2half_rn(o);
            }
    }
    __syncthreads();

    f32x4 acc2[2][4] = {};
#pragma unroll
    for (int s = 0; s < 8; s++) {
        int sl = s * 4 + lg;
        bf16x8 ah[2], al[2], bh[4], bl[4];
#pragma unroll
        for (int mi = 0; mi < 2; mi++) {
            uint4 V = *(uint4*)&LB[(mi * 16 + lr) * TPAD + sl * 8];
            h8_to_bf16pair(V, ah[mi], al[mi]);
        }
        const short* pbh = PB2h + ((size_t)sl * 256 + bcol + lr) * 8;
        const short* pbl = PB2l + ((size_t)sl * 256 + bcol + lr) * 8;
#pragma unroll
        for (int ni = 0; ni < 4; ni++) {
            bh[ni] = *(const bf16x8*)(pbh + ni * 128);
            bl[ni] = *(const bf16x8*)(pbl + ni * 128);
        }
#pragma unroll
        for (int mi = 0; mi < 2; mi++)
#pragma unroll
            for (int ni = 0; ni < 4; ni++) {
                acc2[mi][ni] = __builtin_amdgcn_mfma_f32_16x16x32_bf16(ah[mi], bh[ni], acc2[mi][ni], 0, 0, 0);
                acc2[mi][ni] = __builtin_amdgcn_mfma_f32_16x16x32_bf16(ah[mi], bl[ni], acc2[mi][ni], 0, 0, 0);
                acc2[mi][ni] = __builtin_amdgcn_mfma_f32_16x16x32_bf16(al[mi], bh[ni], acc2[mi][ni], 0, 0, 0);
            }
    }
    __syncthreads();

    float dvo[2][4];
#pragma unroll
    for (int mi = 0; mi < 2; mi++)
#pragma unroll
        for (int j = 0; j < 4; j++) {
            int row = brow + mi * 16 + lg * 4 + j;
            dvo[mi][j] = (row < n) ? dinv[row] : 0.f;
        }
#pragma unroll
    for (int ni = 0; ni < 4; ni++) {
        int col = bcol + ni * 16 + lr;
        float bv = b2[col];
#pragma unroll
        for (int mi = 0; mi < 2; mi++)
#pragma unroll
            for (int j = 0; j < 4; j++) {
                int r = mi * 16 + lg * 4 + j;
                float o = (acc2[mi][ni][j] + bv) * dvo[mi][j];
                *(__half*)&LB[r * TPAD + col] = __float2half_rn(o);
            }
    }
    __syncthreads();

#pragma unroll
    for (int q = 0; q < 4; q++) {
        int idx = t + q * 256;          // [0,1024)
        int row = idx >> 5, c = idx & 31;
        int vv = brow + row;
        if (vv < n)
            *(uint4*)(Aout + (size_t)vv * 256 + c * 8) = *(const uint4*)&LB[row * TPAD + c * 8];
    }
}

// ---------------- standalone gather: agg[v] = dinv[v] * (self + sum nbrs) ------
// One wave per dst node, no LDS, no barriers (R6 structure, fp16 data).
// Input prescaled by dinv; output fp16 512B-contiguous rows.

__global__ __launch_bounds__(256) void agg_fp16(const short* __restrict__ Ain,
                                                const int* __restrict__ row_ptr, const int* __restrict__ adj,
                                                const float* __restrict__ dinv,
                                                short* __restrict__ Agg, int n) {
    int t = threadIdx.x;
    int v = blockIdx.x * 4 + (t >> 6);
    if (v >= n) return;
    int lane = t & 63;
    int loff = lane * 4;                            // fp16 col base (4 cols/lane)
    float dv = dinv[v];
    uint2 V0 = *(const uint2*)(Ain + (size_t)v * 256 + loff);
    float4 acc = make_float4(0.f, 0.f, 0.f, 0.f);
    HADD(V0);
    int e = row_ptr[v], end = row_ptr[v + 1];
    for (; e + 8 <= end; e += 8) {
        int s8[8]; uint2 V[8];
#pragma unroll
        for (int j = 0; j < 8; j++) s8[j] = adj[e + j];
#pragma unroll
        for (int j = 0; j < 8; j++) V[j] = *(const uint2*)(Ain + (size_t)s8[j] * 256 + loff);
#pragma unroll
        for (int j = 0; j < 8; j++) HADD(V[j]);
    }
    for (; e + 4 <= end; e += 4) {
        int s4[4]; uint2 V[4];
#pragma unroll
        for (int j = 0; j < 4; j++) s4[j] = adj[e + j];
#pragma unroll
        for (int j = 0; j < 4; j++) V[j] = *(const uint2*)(Ain + (size_t)s4[j] * 256 + loff);
#pragma unroll
        for (int j = 0; j < 4; j++) HADD(V[j]);
    }
    for (; e < end; e++) {
        uint2 V = *(const uint2*)(Ain + (size_t)adj[e] * 256 + loff);
        HADD(V);
    }
    __half2 q0 = __floats2half2_rn(dv * acc.x, dv * acc.y);
    __half2 q1 = __floats2half2_rn(dv * acc.z, dv * acc.w);
    uint2 pw;
    pw.x = *(unsigned*)&q0; pw.y = *(unsigned*)&q1;
    *(uint2*)(Agg + (size_t)v * 256 + loff) = pw;
}

// ---------------- transform: act = relu(agg @ Wc + bc) [*dinv] ----------------
// BM=32 rows/block, 4 waves. Coop-load agg tile -> LDS fp16, split at frag read,
// 3-term MFMA, epilogue -> fp16 act. LDS LB[8448] shorts.

template<bool SCALE_OUT>
__global__ __launch_bounds__(256) void trans_mfma(const short* __restrict__ Agg,
                                                  const short* __restrict__ PBh, const short* __restrict__ PBl,
                                                  const float* __restrict__ bias, const float* __restrict__ dinv,
                                                  short* __restrict__ Aout, int n) {
    __shared__ short LB[8448];
    int t = threadIdx.x, lane = t & 63, wv = t >> 6;
    int lr = lane & 15, lg = lane >> 4;
    int brow = blockIdx.x * 32;
    int bcol = wv * 64;

    // ---- coop load agg tile (rows are within padded buffer; garbage rows only
    //      affect their own dead output rows) ----
#pragma unroll
    for (int q = 0; q < 4; q++) {
        int idx = t + q * 256;          // [0,1024)
        int row = idx >> 5, c = idx & 31;
        *(uint4*)&LB[row * TPAD + c * 8] = *(const uint4*)(Agg + (size_t)(brow + row) * 256 + c * 8);
    }
    __syncthreads();

    // ---- 3-term MFMA ----
    f32x4 acc2[2][4] = {};
#pragma unroll
    for (int s = 0; s < 8; s++) {
        int sl = s * 4 + lg;
        bf16x8 ah[2], al[2], bh[4], bl[4];
#pragma unroll
        for (int mi = 0; mi < 2; mi++) {
            uint4 V = *(uint4*)&LB[(mi * 16 + lr) * TPAD + sl * 8];
            h8_to_bf16pair(V, ah[mi], al[mi]);
        }
        const short* pbh = PBh + ((size_t)sl * 256 + bcol + lr) * 8;
        const short* pbl = PBl + ((size_t)sl * 256 + bcol + lr) * 8;
#pragma unroll
        for (int ni = 0; ni < 4; ni++) {
            bh[ni] = *(const bf16x8*)(pbh + ni * 128);
            bl[ni] = *(const bf16x8*)(pbl + ni * 128);
        }
#pragma unroll
        for (int mi = 0; mi < 2; mi++)
#pragma unroll
            for (int ni = 0; ni < 4; ni++) {
                acc2[mi][ni] = __builtin_amdgcn_mfma_f32_16x16x32_bf16(ah[mi], bh[ni], acc2[mi][ni], 0, 0, 0);
                acc2[mi][ni] = __builtin_amdgcn_mfma_f32_16x16x32_bf16(ah[mi], bl[ni], acc2[mi][ni], 0, 0, 0);
                acc2[mi][ni] = __builtin_amdgcn_mfma_f32_16x16x32_bf16(al[mi], bh[ni], acc2[mi][ni], 0, 0, 0);
            }
    }
    __syncthreads();   // frag reads done; LB reusable

    // ---- epilogue: relu(acc+bias) [*dinv] -> fp16 tile [32][TPAD] ----
    float dvo[2][4];
    if (SCALE_OUT) {
#pragma unroll
        for (int mi = 0; mi < 2; mi++)
#pragma unroll
            for (int j = 0; j < 4; j++) {
                int row = brow + mi * 16 + lg * 4 + j;
                dvo[mi][j] = (row < n) ? dinv[row] : 0.f;
            }
    }
#pragma unroll
    for (int ni = 0; ni < 4; ni++) {
        int col = bcol + ni * 16 + lr;
        float bv = bias[col];
#pragma unroll
        for (int mi = 0; mi < 2; mi++)
#pragma unroll
            for (int j = 0; j < 4; j++) {
                int r = mi * 16 + lg * 4 + j;
                float o = fmaxf(acc2[mi][ni][j] + bv, 0.f);
                if (SCALE_OUT) o *= dvo[mi][j];
                *(__half*)&LB[r * TPAD + col] = __float2half_rn(o);
            }
    }
    __syncthreads();

    // ---- coop write-out ----
#pragma unroll
    for (int q = 0; q < 4; q++) {
        int idx = t + q * 256;          // [0,1024)
        int row = idx >> 5, c = idx & 31;
        int vv = brow + row;
        if (vv < n)
            *(uint4*)(Aout + (size_t)vv * 256 + c * 8) = *(const uint4*)&LB[row * TPAD + c * 8];
    }
}

// ---------------- pooling (mean + max over rows) from hpack fp16 --------------

__global__ __launch_bounds__(256) void pool_packed(const short* __restrict__ P, int n,
                                                   float* __restrict__ pool_sum, int* __restrict__ pool_max) {
    int t = threadIdx.x;   // column
    int chunk = (n + gridDim.x - 1) / gridDim.x;
    int r0 = blockIdx.x * chunk, r1 = min(n, r0 + chunk);
    float s = 0.f, mx = 0.f;
    for (int r = r0; r < r1; r++) {
        float v = __half2float(*(const __half*)&P[(size_t)r * 256 + t]);
        s += v;
        mx = fmaxf(mx, v);
    }
    atomicAdd(&pool_sum[t], s);
    atomicMax(&pool_max[t], __float_as_int(mx));
}

// ---------------- MLP head ----------------

__global__ __launch_bounds__(256) void head1(const float* __restrict__ pool_sum, const int* __restrict__ pool_max,
                                             const float* __restrict__ Wp1, const float* __restrict__ bp1,
                                             float* __restrict__ hid, float invn) {
    __shared__ float red[8][33];
    int t = threadIdx.x, cl = t & 31, w = t >> 5;
    int col = blockIdx.x * 32 + cl;
    float p = 0.f;
    for (int j = w * 64; j < w * 64 + 64; j++) {
        float g = (j < HID) ? pool_sum[j] * invn : __int_as_float(pool_max[j - HID]);
        p = fmaf(g, Wp1[(size_t)j * HID + col], p);
    }
    red[w][cl] = p;
    __syncthreads();
    if (w == 0) {
        float a = 0.f;
#pragma unroll
        for (int k = 0; k < 8; k++) a += red[k][cl];
        hid[col] = fmaxf(a + bp1[col], 0.f);
    }
}

__global__ __launch_bounds__(128) void head2(const float* __restrict__ hid,
                                             const float* __restrict__ Wp2, const float* __restrict__ bp2,
                                             float* __restrict__ out) {
    int t = threadIdx.x;   // 128
    float a = bp2[t];
#pragma unroll 8
    for (int j = 0; j < HID; j++) a = fmaf(hid[j], Wp2[(size_t)j * DEMB + t], a);
    out[t] = a;
}

// ---------------- launcher ----------------

extern "C" void kernel_launch(void* const* d_in, const int* in_sizes, int n_in,
                              void* d_out, int out_size, void* d_ws, size_t ws_size,
                              hipStream_t stream) {
    const float* x   = (const float*)d_in[0];
    const int*   ei  = (const int*)d_in[1];
    const float* W1  = (const float*)d_in[2];
    const float* b1  = (const float*)d_in[3];
    const float* W2  = (const float*)d_in[4];
    const float* b2  = (const float*)d_in[5];
    const float* Wc  = (const float*)d_in[6];
    const float* bc  = (const float*)d_in[7];
    const float* Wp1 = (const float*)d_in[8];
    const float* bp1 = (const float*)d_in[9];
    const float* Wp2 = (const float*)d_in[10];
    const float* bp2 = (const float*)d_in[11];
    float* out = (float*)d_out;

    int N = in_sizes[0] / FIN;
    int E = in_sizes[1] / 2;
    int nb32 = (N + 31) / 32;
    int nb4  = (N + 3) / 4;
    int R = nb32 * 32;                   // padded rows for hpack buffers

    char* base = (char*)d_ws;
    short* actA = (short*)base;                          // [R,256] fp16 hpack
    short* actB = (short*)(base + (size_t)R * 512);      // [R,256] fp16 hpack
    short* aggb = (short*)(base + 2 * (size_t)R * 512);  // [R,256] fp16 agg
    int*   counts  = (int*)(base + 3 * (size_t)R * 512); // [N]
    int*   row_ptr = counts + N;                         // [N+1]
    int*   cursor  = row_ptr + (N + 1);                  // [N]
    int*   adj     = cursor + N;                         // [E]
    float* dinvp   = (float*)(adj + E);                  // [N]
    float* pool_sum = dinvp + N;                         // [HID]
    int*   pool_max = (int*)(pool_sum + HID);            // [HID]
    int*   chunkSums = pool_max + HID;                   // [<=64]
    float* hidbuf  = (float*)(chunkSums + 64);           // [HID]
    short* PH = (short*)((((uintptr_t)(hidbuf + HID)) + 15) & ~(uintptr_t)15);
    short* PL = PH + 278528;
    const int oW1 = 0, oW2 = 16384, oC0 = 81920, oC1 = 147456, oC2 = 212992;

    int nch = (N + 1023) / 1024;
    int nb256 = (N + 255) / 256;
    int eb256 = (E + 255) / 256;

    zero_pack<<<nb256 + 64 + 4 * 256, 256, 0, stream>>>(counts, N, pool_sum, pool_max, nb256,
                                                        W1, W2, Wc, PH, PL);
    hist_kernel<<<eb256, 256, 0, stream>>>(ei, E, counts);
    scan_partial<<<nch, 256, 0, stream>>>(counts, N, chunkSums, dinvp);
    scan_final<<<nch, 256, 0, stream>>>(counts, N, chunkSums, row_ptr, cursor);
    fill_kernel<<<eb256, 256, 0, stream>>>(ei, E, cursor, adj);

    // fused encoder: actA = hpack(dinv * (relu(x@W1+b1)@W2 + b2))
    encoder_fused<<<nb32, 256, 0, stream>>>(x, PH + oW1, PL + oW1, PH + oW2, PL + oW2,
                                            b1, b2, dinvp, actA, N);

    // GCN layers: agg = dinv*(S'@act) [standalone gather]; act' = relu(agg@Wc+bc)[*dinv]
    agg_fp16<<<nb4, 256, 0, stream>>>(actA, row_ptr, adj, dinvp, aggb, N);
    trans_mfma<true><<<nb32, 256, 0, stream>>>(aggb, PH + oC0, PL + oC0, bc + 0 * HID, dinvp, actB, N);
    agg_fp16<<<nb4, 256, 0, stream>>>(actB, row_ptr, adj, dinvp, aggb, N);
    trans_mfma<true><<<nb32, 256, 0, stream>>>(aggb, PH + oC1, PL + oC1, bc + 1 * HID, dinvp, actA, N);
    agg_fp16<<<nb4, 256, 0, stream>>>(actA, row_ptr, adj, dinvp, aggb, N);
    trans_mfma<false><<<nb32, 256, 0, stream>>>(aggb, PH + oC2, PL + oC2, bc + 2 * HID, dinvp, actB, N);

    // pooling + head
    pool_packed<<<256, 256, 0, stream>>>(actB, N, pool_sum, pool_max);
    head1<<<8, 256, 0, stream>>>(pool_sum, pool_max, Wp1, bp1, hidbuf, 1.0f / (float)N);
    head2<<<1, 128, 0, stream>>>(hidbuf, Wp2, bp2, out);
}

// Round 18
// 438.306 us; speedup vs baseline: 1.1755x; 1.0831x over previous
//
#include <hip/hip_runtime.h>
#include <hip/hip_fp16.h>

#define FIN 64
#define HID 256
#define DEMB 128
#define NLAYERS 3
#define TPAD 264

typedef __attribute__((ext_vector_type(8))) short bf16x8;
typedef __attribute__((ext_vector_type(4))) float f32x4;

__device__ inline short f2bf(float x) {               // RNE fp32 -> bf16 bits
    unsigned u = __float_as_uint(x);
    u += 0x7fff + ((u >> 16) & 1);
    return (short)(u >> 16);
}
__device__ inline float bf2f(short h) {
    return __uint_as_float(((unsigned)(unsigned short)h) << 16);
}

// Activation layout "hpack": per row r, 256 fp16 (512B contiguous), linear cols.
// Values PRE-SCALED by dinv[row] except after the last layer.

// add 4 fp16 cols (uint2) into fp32 acc
#define HADD(V) do { \
    __half2 p0 = *(__half2*)&(V).x, p1 = *(__half2*)&(V).y; \
    float2 f0 = __half22float2(p0), f1 = __half22float2(p1); \
    acc.x += f0.x; acc.y += f0.y; acc.z += f1.x; acc.w += f1.y; } while (0)

__device__ inline void split2(float a0, float a1, float a2, float a3, uint2& hw, uint2& lw) {
    short h0 = f2bf(a0), h1 = f2bf(a1), h2 = f2bf(a2), h3 = f2bf(a3);
    short l0 = f2bf(a0 - bf2f(h0)), l1 = f2bf(a1 - bf2f(h1));
    short l2 = f2bf(a2 - bf2f(h2)), l3 = f2bf(a3 - bf2f(h3));
    hw.x = (unsigned short)h0 | ((unsigned)(unsigned short)h1 << 16);
    hw.y = (unsigned short)h2 | ((unsigned)(unsigned short)h3 << 16);
    lw.x = (unsigned short)l0 | ((unsigned)(unsigned short)l1 << 16);
    lw.y = (unsigned short)l2 | ((unsigned)(unsigned short)l3 << 16);
}

// 8 fp16 (uint4) -> split-bf16 pair (ah, al), exact (fp16 subset of fp32)
__device__ inline void h8_to_bf16pair(uint4 V, bf16x8& ah, bf16x8& al) {
    const unsigned* w = (const unsigned*)&V;
    short hh[8], ll[8];
#pragma unroll
    for (int q = 0; q < 4; q++) {
        __half2 p = *(__half2*)&w[q];
        float2 f = __half22float2(p);
        short h0 = f2bf(f.x), h1 = f2bf(f.y);
        hh[2 * q] = h0; hh[2 * q + 1] = h1;
        ll[2 * q] = f2bf(f.x - bf2f(h0));
        ll[2 * q + 1] = f2bf(f.y - bf2f(h1));
    }
#pragma unroll
    for (int q = 0; q < 8; q++) { ah[q] = hh[q]; al[q] = ll[q]; }
}

// ---------------- zero + weight-pack combined ----------------

__global__ __launch_bounds__(256) void zero_pack(int* counts, int n, float* pool_sum, int* pool_max, int nzb,
                                                 const float* __restrict__ W1, const float* __restrict__ W2,
                                                 const float* __restrict__ Wc,
                                                 short* __restrict__ PH, short* __restrict__ PL) {
    if ((int)blockIdx.x < nzb) {
        int i = blockIdx.x * 256 + threadIdx.x;
        if (i < n) counts[i] = 0;
        if (i < HID) { pool_sum[i] = 0.0f; pool_max[i] = 0; }
        return;
    }
    int b = blockIdx.x - nzb, nn = threadIdx.x;
    const float* src; int k; size_t dst;
    if (b < 64) { src = W1; k = b; dst = 0; }
    else {
        int m = (b - 64) >> 8; k = (b - 64) & 255;
        src = (m == 0) ? W2 : (Wc + (size_t)(m - 1) * 65536);
        dst = 16384 + (size_t)m * 65536;
    }
    float w = src[(size_t)k * 256 + nn];
    short h = f2bf(w);
    short l = f2bf(w - bf2f(h));
    int o = ((k >> 3) * 256 + nn) * 8 + (k & 7);
    PH[dst + o] = h; PL[dst + o] = l;
}

// hist + per-edge rank (atomicAdd return) in one pass
__global__ __launch_bounds__(256) void hist_kernel(const int* __restrict__ ei, int E,
                                                   int* __restrict__ counts, int* __restrict__ rank) {
    int e = blockIdx.x * 256 + threadIdx.x;
    if (e < E) rank[e] = atomicAdd(&counts[ei[E + e]], 1);
}

__global__ __launch_bounds__(256) void scan_partial(const int* __restrict__ counts, int n,
                                                    int* __restrict__ chunkSums, float* __restrict__ dinv) {
    __shared__ int s[256];
    int t = threadIdx.x, base = blockIdx.x * 1024;
    int sum = 0;
#pragma unroll
    for (int j = 0; j < 4; j++) {
        int i = base + t * 4 + j;
        if (i < n) {
            int c = counts[i];
            sum += c;
            dinv[i] = rsqrtf((float)(c + 1));
        }
    }
    s[t] = sum; __syncthreads();
    for (int off = 128; off > 0; off >>= 1) { if (t < off) s[t] += s[t + off]; __syncthreads(); }
    if (t == 0) chunkSums[blockIdx.x] = s[0];
}

__global__ __launch_bounds__(256) void scan_final(const int* __restrict__ counts, int n,
                                                  const int* __restrict__ chunkSums, int* __restrict__ row_ptr) {
    __shared__ int s[256];
    __shared__ int base_s;
    int t = threadIdx.x, base = blockIdx.x * 1024;
    if (t == 0) {
        int a = 0;
        for (int i = 0; i < (int)blockIdx.x; i++) a += chunkSums[i];
        base_s = a;
    }
    int v[4]; int sum = 0;
#pragma unroll
    for (int j = 0; j < 4; j++) { int i = base + t * 4 + j; v[j] = (i < n) ? counts[i] : 0; sum += v[j]; }
    s[t] = sum; __syncthreads();
    for (int off = 1; off < 256; off <<= 1) {
        int x = (t >= off) ? s[t - off] : 0;
        __syncthreads();
        s[t] += x;
        __syncthreads();
    }
    int run = base_s + (s[t] - sum);
#pragma unroll
    for (int j = 0; j < 4; j++) {
        int i = base + t * 4 + j;
        if (i < n) {
            row_ptr[i] = run; run += v[j];
            if (i == n - 1) row_ptr[n] = run;
        }
    }
}

// atomic-free fill: position = row_ptr[dst] + rank[e]
__global__ __launch_bounds__(256) void fill_kernel(const int* __restrict__ ei, int E,
                                                   const int* __restrict__ row_ptr, const int* __restrict__ rank,
                                                   int* __restrict__ adj) {
    int e = blockIdx.x * 256 + threadIdx.x;
    if (e < E) {
        int s = ei[e], d = ei[E + e];
        adj[row_ptr[d] + rank[e]] = s;
    }
}

// ---------------- fused encoder: out = hpack(dinv * (relu(x@W1+b1)@W2 + b2)) --
// BM=32 rows/block, 4 waves. LDS LB[8448] shorts (16896 B).

__global__ __launch_bounds__(256) void encoder_fused(const float* __restrict__ x,
                                                     const short* __restrict__ PB1h, const short* __restrict__ PB1l,
                                                     const short* __restrict__ PB2h, const short* __restrict__ PB2l,
                                                     const float* __restrict__ b1, const float* __restrict__ b2,
                                                     const float* __restrict__ dinv,
                                                     short* __restrict__ Aout, int n) {
    __shared__ short LB[8448];
    int t = threadIdx.x, lane = t & 63, wv = t >> 6;
    int lr = lane & 15, lg = lane >> 4;
    int brow = blockIdx.x * 32;
    int bcol = wv * 64;

#pragma unroll
    for (int l = 0; l < 2; l++) {
        int lin = t + l * 256;
        int r = lin >> 4, kq = (lin & 15) * 4;
        int row = brow + r;
        float4 v = (row < n) ? *(const float4*)(x + (size_t)row * FIN + kq)
                             : make_float4(0.f, 0.f, 0.f, 0.f);
        uint2 hw, lw; split2(v.x, v.y, v.z, v.w, hw, lw);
        int g = kq >> 3, i0 = kq & 7;
        *(uint2*)&LB[(g * 33 + r) * 8 + i0] = hw;
        *(uint2*)&LB[2112 + (g * 33 + r) * 8 + i0] = lw;
    }
    __syncthreads();

    f32x4 acc1[2][4] = {};
#pragma unroll
    for (int s = 0; s < 2; s++) {
        int sl = s * 4 + lg;
        bf16x8 ah[2], al[2], bh[4], bl[4];
#pragma unroll
        for (int mi = 0; mi < 2; mi++) {
            ah[mi] = *(bf16x8*)&LB[(sl * 33 + mi * 16 + lr) * 8];
            al[mi] = *(bf16x8*)&LB[2112 + (sl * 33 + mi * 16 + lr) * 8];
        }
        const short* pbh = PB1h + ((size_t)sl * 256 + bcol + lr) * 8;
        const short* pbl = PB1l + ((size_t)sl * 256 + bcol + lr) * 8;
#pragma unroll
        for (int ni = 0; ni < 4; ni++) {
            bh[ni] = *(const bf16x8*)(pbh + ni * 128);
            bl[ni] = *(const bf16x8*)(pbl + ni * 128);
        }
#pragma unroll
        for (int mi = 0; mi < 2; mi++)
#pragma unroll
            for (int ni = 0; ni < 4; ni++) {
                acc1[mi][ni] = __builtin_amdgcn_mfma_f32_16x16x32_bf16(ah[mi], bh[ni], acc1[mi][ni], 0, 0, 0);
                acc1[mi][ni] = __builtin_amdgcn_mfma_f32_16x16x32_bf16(ah[mi], bl[ni], acc1[mi][ni], 0, 0, 0);
                acc1[mi][ni] = __builtin_amdgcn_mfma_f32_16x16x32_bf16(al[mi], bh[ni], acc1[mi][ni], 0, 0, 0);
            }
    }
    __syncthreads();

#pragma unroll
    for (int ni = 0; ni < 4; ni++) {
        int col = bcol + ni * 16 + lr;
        float bv = b1[col];
#pragma unroll
        for (int mi = 0; mi < 2; mi++)
#pragma unroll
            for (int j = 0; j < 4; j++) {
                int r = mi * 16 + lg * 4 + j;
                float o = fmaxf(acc1[mi][ni][j] + bv, 0.f);
                *(__half*)&LB[r * TPAD + col] = __float2half_rn(o);
            }
    }
    __syncthreads();

    f32x4 acc2[2][4] = {};
#pragma unroll
    for (int s = 0; s < 8; s++) {
        int sl = s * 4 + lg;
        bf16x8 ah[2], al[2], bh[4], bl[4];
#pragma unroll
        for (int mi = 0; mi < 2; mi++) {
            uint4 V = *(uint4*)&LB[(mi * 16 + lr) * TPAD + sl * 8];
            h8_to_bf16pair(V, ah[mi], al[mi]);
        }
        const short* pbh = PB2h + ((size_t)sl * 256 + bcol + lr) * 8;
        const short* pbl = PB2l + ((size_t)sl * 256 + bcol + lr) * 8;
#pragma unroll
        for (int ni = 0; ni < 4; ni++) {
            bh[ni] = *(const bf16x8*)(pbh + ni * 128);
            bl[ni] = *(const bf16x8*)(pbl + ni * 128);
        }
#pragma unroll
        for (int mi = 0; mi < 2; mi++)
#pragma unroll
            for (int ni = 0; ni < 4; ni++) {
                acc2[mi][ni] = __builtin_amdgcn_mfma_f32_16x16x32_bf16(ah[mi], bh[ni], acc2[mi][ni], 0, 0, 0);
                acc2[mi][ni] = __builtin_amdgcn_mfma_f32_16x16x32_bf16(ah[mi], bl[ni], acc2[mi][ni], 0, 0, 0);
                acc2[mi][ni] = __builtin_amdgcn_mfma_f32_16x16x32_bf16(al[mi], bh[ni], acc2[mi][ni], 0, 0, 0);
            }
    }
    __syncthreads();

    float dvo[2][4];
#pragma unroll
    for (int mi = 0; mi < 2; mi++)
#pragma unroll
        for (int j = 0; j < 4; j++) {
            int row = brow + mi * 16 + lg * 4 + j;
            dvo[mi][j] = (row < n) ? dinv[row] : 0.f;
        }
#pragma unroll
    for (int ni = 0; ni < 4; ni++) {
        int col = bcol + ni * 16 + lr;
        float bv = b2[col];
#pragma unroll
        for (int mi = 0; mi < 2; mi++)
#pragma unroll
            for (int j = 0; j < 4; j++) {
                int r = mi * 16 + lg * 4 + j;
                float o = (acc2[mi][ni][j] + bv) * dvo[mi][j];
                *(__half*)&LB[r * TPAD + col] = __float2half_rn(o);
            }
    }
    __syncthreads();

#pragma unroll
    for (int q = 0; q < 4; q++) {
        int idx = t + q * 256;          // [0,1024)
        int row = idx >> 5, c = idx & 31;
        int vv = brow + row;
        if (vv < n)
            *(uint4*)(Aout + (size_t)vv * 256 + c * 8) = *(const uint4*)&LB[row * TPAD + c * 8];
    }
}

// ---------------- standalone gather: agg[v] = dinv[v] * (self + sum nbrs) ------
// One wave per dst node, no LDS, no barriers. Input prescaled by dinv.

__global__ __launch_bounds__(256) void agg_fp16(const short* __restrict__ Ain,
                                                const int* __restrict__ row_ptr, const int* __restrict__ adj,
                                                const float* __restrict__ dinv,
                                                short* __restrict__ Agg, int n) {
    int t = threadIdx.x;
    int v = blockIdx.x * 4 + (t >> 6);
    if (v >= n) return;
    int lane = t & 63;
    int loff = lane * 4;                            // fp16 col base (4 cols/lane)
    float dv = dinv[v];
    uint2 V0 = *(const uint2*)(Ain + (size_t)v * 256 + loff);
    float4 acc = make_float4(0.f, 0.f, 0.f, 0.f);
    HADD(V0);
    int e = row_ptr[v], end = row_ptr[v + 1];
    for (; e + 8 <= end; e += 8) {
        int s8[8]; uint2 V[8];
#pragma unroll
        for (int j = 0; j < 8; j++) s8[j] = adj[e + j];
#pragma unroll
        for (int j = 0; j < 8; j++) V[j] = *(const uint2*)(Ain + (size_t)s8[j] * 256 + loff);
#pragma unroll
        for (int j = 0; j < 8; j++) HADD(V[j]);
    }
    for (; e + 4 <= end; e += 4) {
        int s4[4]; uint2 V[4];
#pragma unroll
        for (int j = 0; j < 4; j++) s4[j] = adj[e + j];
#pragma unroll
        for (int j = 0; j < 4; j++) V[j] = *(const uint2*)(Ain + (size_t)s4[j] * 256 + loff);
#pragma unroll
        for (int j = 0; j < 4; j++) HADD(V[j]);
    }
    for (; e < end; e++) {
        uint2 V = *(const uint2*)(Ain + (size_t)adj[e] * 256 + loff);
        HADD(V);
    }
    __half2 q0 = __floats2half2_rn(dv * acc.x, dv * acc.y);
    __half2 q1 = __floats2half2_rn(dv * acc.z, dv * acc.w);
    uint2 pw;
    pw.x = *(unsigned*)&q0; pw.y = *(unsigned*)&q1;
    *(uint2*)(Agg + (size_t)v * 256 + loff) = pw;
}

// ---------------- transform: act = relu(agg @ Wc + bc) [*dinv] ----------------

template<bool SCALE_OUT>
__global__ __launch_bounds__(256) void trans_mfma(const short* __restrict__ Agg,
                                                  const short* __restrict__ PBh, const short* __restrict__ PBl,
                                                  const float* __restrict__ bias, const float* __restrict__ dinv,
                                                  short* __restrict__ Aout, int n) {
    __shared__ short LB[8448];
    int t = threadIdx.x, lane = t & 63, wv = t >> 6;
    int lr = lane & 15, lg = lane >> 4;
    int brow = blockIdx.x * 32;
    int bcol = wv * 64;

#pragma unroll
    for (int q = 0; q < 4; q++) {
        int idx = t + q * 256;          // [0,1024)
        int row = idx >> 5, c = idx & 31;
        *(uint4*)&LB[row * TPAD + c * 8] = *(const uint4*)(Agg + (size_t)(brow + row) * 256 + c * 8);
    }
    __syncthreads();

    f32x4 acc2[2][4] = {};
#pragma unroll
    for (int s = 0; s < 8; s++) {
        int sl = s * 4 + lg;
        bf16x8 ah[2], al[2], bh[4], bl[4];
#pragma unroll
        for (int mi = 0; mi < 2; mi++) {
            uint4 V = *(uint4*)&LB[(mi * 16 + lr) * TPAD + sl * 8];
            h8_to_bf16pair(V, ah[mi], al[mi]);
        }
        const short* pbh = PBh + ((size_t)sl * 256 + bcol + lr) * 8;
        const short* pbl = PBl + ((size_t)sl * 256 + bcol + lr) * 8;
#pragma unroll
        for (int ni = 0; ni < 4; ni++) {
            bh[ni] = *(const bf16x8*)(pbh + ni * 128);
            bl[ni] = *(const bf16x8*)(pbl + ni * 128);
        }
#pragma unroll
        for (int mi = 0; mi < 2; mi++)
#pragma unroll
            for (int ni = 0; ni < 4; ni++) {
                acc2[mi][ni] = __builtin_amdgcn_mfma_f32_16x16x32_bf16(ah[mi], bh[ni], acc2[mi][ni], 0, 0, 0);
                acc2[mi][ni] = __builtin_amdgcn_mfma_f32_16x16x32_bf16(ah[mi], bl[ni], acc2[mi][ni], 0, 0, 0);
                acc2[mi][ni] = __builtin_amdgcn_mfma_f32_16x16x32_bf16(al[mi], bh[ni], acc2[mi][ni], 0, 0, 0);
            }
    }
    __syncthreads();

    float dvo[2][4];
    if (SCALE_OUT) {
#pragma unroll
        for (int mi = 0; mi < 2; mi++)
#pragma unroll
            for (int j = 0; j < 4; j++) {
                int row = brow + mi * 16 + lg * 4 + j;
                dvo[mi][j] = (row < n) ? dinv[row] : 0.f;
            }
    }
#pragma unroll
    for (int ni = 0; ni < 4; ni++) {
        int col = bcol + ni * 16 + lr;
        float bv = bias[col];
#pragma unroll
        for (int mi = 0; mi < 2; mi++)
#pragma unroll
            for (int j = 0; j < 4; j++) {
                int r = mi * 16 + lg * 4 + j;
                float o = fmaxf(acc2[mi][ni][j] + bv, 0.f);
                if (SCALE_OUT) o *= dvo[mi][j];
                *(__half*)&LB[r * TPAD + col] = __float2half_rn(o);
            }
    }
    __syncthreads();

#pragma unroll
    for (int q = 0; q < 4; q++) {
        int idx = t + q * 256;          // [0,1024)
        int row = idx >> 5, c = idx & 31;
        int vv = brow + row;
        if (vv < n)
            *(uint4*)(Aout + (size_t)vv * 256 + c * 8) = *(const uint4*)&LB[row * TPAD + c * 8];
    }
}

// ---------------- pooling (mean + max over rows) from hpack fp16 --------------

__global__ __launch_bounds__(256) void pool_packed(const short* __restrict__ P, int n,
                                                   float* __restrict__ pool_sum, int* __restrict__ pool_max) {
    int t = threadIdx.x;   // column
    int chunk = (n + gridDim.x - 1) / gridDim.x;
    int r0 = blockIdx.x * chunk, r1 = min(n, r0 + chunk);
    float s = 0.f, mx = 0.f;
    for (int r = r0; r < r1; r++) {
        float v = __half2float(*(const __half*)&P[(size_t)r * 256 + t]);
        s += v;
        mx = fmaxf(mx, v);
    }
    atomicAdd(&pool_sum[t], s);
    atomicMax(&pool_max[t], __float_as_int(mx));
}

// ---------------- MLP head ----------------

__global__ __launch_bounds__(256) void head1(const float* __restrict__ pool_sum, const int* __restrict__ pool_max,
                                             const float* __restrict__ Wp1, const float* __restrict__ bp1,
                                             float* __restrict__ hid, float invn) {
    __shared__ float red[8][33];
    int t = threadIdx.x, cl = t & 31, w = t >> 5;
    int col = blockIdx.x * 32 + cl;
    float p = 0.f;
    for (int j = w * 64; j < w * 64 + 64; j++) {
        float g = (j < HID) ? pool_sum[j] * invn : __int_as_float(pool_max[j - HID]);
        p = fmaf(g, Wp1[(size_t)j * HID + col], p);
    }
    red[w][cl] = p;
    __syncthreads();
    if (w == 0) {
        float a = 0.f;
#pragma unroll
        for (int k = 0; k < 8; k++) a += red[k][cl];
        hid[col] = fmaxf(a + bp1[col], 0.f);
    }
}

__global__ __launch_bounds__(128) void head2(const float* __restrict__ hid,
                                             const float* __restrict__ Wp2, const float* __restrict__ bp2,
                                             float* __restrict__ out) {
    int t = threadIdx.x;   // 128
    float a = bp2[t];
#pragma unroll 8
    for (int j = 0; j < HID; j++) a = fmaf(hid[j], Wp2[(size_t)j * DEMB + t], a);
    out[t] = a;
}

// ---------------- launcher ----------------

extern "C" void kernel_launch(void* const* d_in, const int* in_sizes, int n_in,
                              void* d_out, int out_size, void* d_ws, size_t ws_size,
                              hipStream_t stream) {
    const float* x   = (const float*)d_in[0];
    const int*   ei  = (const int*)d_in[1];
    const float* W1  = (const float*)d_in[2];
    const float* b1  = (const float*)d_in[3];
    const float* W2  = (const float*)d_in[4];
    const float* b2  = (const float*)d_in[5];
    const float* Wc  = (const float*)d_in[6];
    const float* bc  = (const float*)d_in[7];
    const float* Wp1 = (const float*)d_in[8];
    const float* bp1 = (const float*)d_in[9];
    const float* Wp2 = (const float*)d_in[10];
    const float* bp2 = (const float*)d_in[11];
    float* out = (float*)d_out;

    int N = in_sizes[0] / FIN;
    int E = in_sizes[1] / 2;
    int nb32 = (N + 31) / 32;
    int nb4  = (N + 3) / 4;
    int R = nb32 * 32;                   // padded rows for hpack buffers

    char* base = (char*)d_ws;
    short* actA = (short*)base;                          // [R,256] fp16 hpack
    short* actB = (short*)(base + (size_t)R * 512);      // [R,256] fp16 hpack
    short* aggb = (short*)(base + 2 * (size_t)R * 512);  // [R,256] fp16 agg
    int*   counts  = (int*)(base + 3 * (size_t)R * 512); // [N]
    int*   row_ptr = counts + N;                         // [N+1]
    int*   rank    = row_ptr + (N + 1);                  // [E]
    int*   adj     = rank + E;                           // [E]
    float* dinvp   = (float*)(adj + E);                  // [N]
    float* pool_sum = dinvp + N;                         // [HID]
    int*   pool_max = (int*)(pool_sum + HID);            // [HID]
    int*   chunkSums = pool_max + HID;                   // [<=64]
    float* hidbuf  = (float*)(chunkSums + 64);           // [HID]
    short* PH = (short*)((((uintptr_t)(hidbuf + HID)) + 15) & ~(uintptr_t)15);
    short* PL = PH + 278528;
    const int oW1 = 0, oW2 = 16384, oC0 = 81920, oC1 = 147456, oC2 = 212992;

    int nch = (N + 1023) / 1024;
    int nb256 = (N + 255) / 256;
    int eb256 = (E + 255) / 256;

    zero_pack<<<nb256 + 64 + 4 * 256, 256, 0, stream>>>(counts, N, pool_sum, pool_max, nb256,
                                                        W1, W2, Wc, PH, PL);
    hist_kernel<<<eb256, 256, 0, stream>>>(ei, E, counts, rank);
    scan_partial<<<nch, 256, 0, stream>>>(counts, N, chunkSums, dinvp);
    scan_final<<<nch, 256, 0, stream>>>(counts, N, chunkSums, row_ptr);
    fill_kernel<<<eb256, 256, 0, stream>>>(ei, E, row_ptr, rank, adj);

    // fused encoder: actA = hpack(dinv * (relu(x@W1+b1)@W2 + b2))
    encoder_fused<<<nb32, 256, 0, stream>>>(x, PH + oW1, PL + oW1, PH + oW2, PL + oW2,
                                            b1, b2, dinvp, actA, N);

    // GCN layers: agg = dinv*(S'@act); act' = relu(agg@Wc+bc)[*dinv]
    agg_fp16<<<nb4, 256, 0, stream>>>(actA, row_ptr, adj, dinvp, aggb, N);
    trans_mfma<true><<<nb32, 256, 0, stream>>>(aggb, PH + oC0, PL + oC0, bc + 0 * HID, dinvp, actB, N);
    agg_fp16<<<nb4, 256, 0, stream>>>(actB, row_ptr, adj, dinvp, aggb, N);
    trans_mfma<true><<<nb32, 256, 0, stream>>>(aggb, PH + oC1, PL + oC1, bc + 1 * HID, dinvp, actA, N);
    agg_fp16<<<nb4, 256, 0, stream>>>(actA, row_ptr, adj, dinvp, aggb, N);
    trans_mfma<false><<<nb32, 256, 0, stream>>>(aggb, PH + oC2, PL + oC2, bc + 2 * HID, dinvp, actB, N);

    // pooling + head
    pool_packed<<<256, 256, 0, stream>>>(actB, N, pool_sum, pool_max);
    head1<<<8, 256, 0, stream>>>(pool_sum, pool_max, Wp1, bp1, hidbuf, 1.0f / (float)N);
    head2<<<1, 128, 0, stream>>>(hidbuf, Wp2, bp2, out);
}

// Round 19
// 419.901 us; speedup vs baseline: 1.2270x; 1.0438x over previous
//
#include <hip/hip_runtime.h>
#include <hip/hip_fp16.h>

#define FIN 64
#define HID 256
#define DEMB 128
#define NLAYERS 3
#define TPAD 264

typedef __attribute__((ext_vector_type(8))) short bf16x8;
typedef __attribute__((ext_vector_type(4))) float f32x4;

__device__ inline short f2bf(float x) {               // RNE fp32 -> bf16 bits
    unsigned u = __float_as_uint(x);
    u += 0x7fff + ((u >> 16) & 1);
    return (short)(u >> 16);
}
__device__ inline float bf2f(short h) {
    return __uint_as_float(((unsigned)(unsigned short)h) << 16);
}

// Activation layout "hpack": per row r, 256 fp16 (512B contiguous), linear cols.
// Values PRE-SCALED by dinv[row] except after the last layer.

// add 4 fp16 cols (uint2) into fp32 acc
#define HADD(V) do { \
    __half2 p0 = *(__half2*)&(V).x, p1 = *(__half2*)&(V).y; \
    float2 f0 = __half22float2(p0), f1 = __half22float2(p1); \
    acc.x += f0.x; acc.y += f0.y; acc.z += f1.x; acc.w += f1.y; } while (0)

__device__ inline void split2(float a0, float a1, float a2, float a3, uint2& hw, uint2& lw) {
    short h0 = f2bf(a0), h1 = f2bf(a1), h2 = f2bf(a2), h3 = f2bf(a3);
    short l0 = f2bf(a0 - bf2f(h0)), l1 = f2bf(a1 - bf2f(h1));
    short l2 = f2bf(a2 - bf2f(h2)), l3 = f2bf(a3 - bf2f(h3));
    hw.x = (unsigned short)h0 | ((unsigned)(unsigned short)h1 << 16);
    hw.y = (unsigned short)h2 | ((unsigned)(unsigned short)h3 << 16);
    lw.x = (unsigned short)l0 | ((unsigned)(unsigned short)l1 << 16);
    lw.y = (unsigned short)l2 | ((unsigned)(unsigned short)l3 << 16);
}

// 8 fp16 (uint4) -> split-bf16 pair (ah, al), exact (fp16 subset of fp32)
__device__ inline void h8_to_bf16pair(uint4 V, bf16x8& ah, bf16x8& al) {
    const unsigned* w = (const unsigned*)&V;
    short hh[8], ll[8];
#pragma unroll
    for (int q = 0; q < 4; q++) {
        __half2 p = *(__half2*)&w[q];
        float2 f = __half22float2(p);
        short h0 = f2bf(f.x), h1 = f2bf(f.y);
        hh[2 * q] = h0; hh[2 * q + 1] = h1;
        ll[2 * q] = f2bf(f.x - bf2f(h0));
        ll[2 * q + 1] = f2bf(f.y - bf2f(h1));
    }
#pragma unroll
    for (int q = 0; q < 8; q++) { ah[q] = hh[q]; al[q] = ll[q]; }
}

// ---------------- zero + weight-pack combined ----------------

__global__ __launch_bounds__(256) void zero_pack(int* counts, int n, float* pool_sum, int* pool_max, int nzb,
                                                 const float* __restrict__ W1, const float* __restrict__ W2,
                                                 const float* __restrict__ Wc,
                                                 short* __restrict__ PH, short* __restrict__ PL) {
    if ((int)blockIdx.x < nzb) {
        int i = blockIdx.x * 256 + threadIdx.x;
        if (i < n) counts[i] = 0;
        if (i < HID) { pool_sum[i] = 0.0f; pool_max[i] = 0; }
        return;
    }
    int b = blockIdx.x - nzb, nn = threadIdx.x;
    const float* src; int k; size_t dst;
    if (b < 64) { src = W1; k = b; dst = 0; }
    else {
        int m = (b - 64) >> 8; k = (b - 64) & 255;
        src = (m == 0) ? W2 : (Wc + (size_t)(m - 1) * 65536);
        dst = 16384 + (size_t)m * 65536;
    }
    float w = src[(size_t)k * 256 + nn];
    short h = f2bf(w);
    short l = f2bf(w - bf2f(h));
    int o = ((k >> 3) * 256 + nn) * 8 + (k & 7);
    PH[dst + o] = h; PL[dst + o] = l;
}

// hist + per-edge rank (atomicAdd return) in one pass
__global__ __launch_bounds__(256) void hist_kernel(const int* __restrict__ ei, int E,
                                                   int* __restrict__ counts, int* __restrict__ rank) {
    int e = blockIdx.x * 256 + threadIdx.x;
    if (e < E) rank[e] = atomicAdd(&counts[ei[E + e]], 1);
}

__global__ __launch_bounds__(256) void scan_partial(const int* __restrict__ counts, int n,
                                                    int* __restrict__ chunkSums, float* __restrict__ dinv) {
    __shared__ int s[256];
    int t = threadIdx.x, base = blockIdx.x * 1024;
    int sum = 0;
#pragma unroll
    for (int j = 0; j < 4; j++) {
        int i = base + t * 4 + j;
        if (i < n) {
            int c = counts[i];
            sum += c;
            dinv[i] = rsqrtf((float)(c + 1));
        }
    }
    s[t] = sum; __syncthreads();
    for (int off = 128; off > 0; off >>= 1) { if (t < off) s[t] += s[t + off]; __syncthreads(); }
    if (t == 0) chunkSums[blockIdx.x] = s[0];
}

__global__ __launch_bounds__(256) void scan_final(const int* __restrict__ counts, int n,
                                                  const int* __restrict__ chunkSums, int* __restrict__ row_ptr) {
    __shared__ int s[256];
    __shared__ int base_s;
    int t = threadIdx.x, base = blockIdx.x * 1024;
    if (t == 0) {
        int a = 0;
        for (int i = 0; i < (int)blockIdx.x; i++) a += chunkSums[i];
        base_s = a;
    }
    int v[4]; int sum = 0;
#pragma unroll
    for (int j = 0; j < 4; j++) { int i = base + t * 4 + j; v[j] = (i < n) ? counts[i] : 0; sum += v[j]; }
    s[t] = sum; __syncthreads();
    for (int off = 1; off < 256; off <<= 1) {
        int x = (t >= off) ? s[t - off] : 0;
        __syncthreads();
        s[t] += x;
        __syncthreads();
    }
    int run = base_s + (s[t] - sum);
#pragma unroll
    for (int j = 0; j < 4; j++) {
        int i = base + t * 4 + j;
        if (i < n) {
            row_ptr[i] = run; run += v[j];
            if (i == n - 1) row_ptr[n] = run;
        }
    }
}

// atomic-free fill: position = row_ptr[dst] + rank[e]
__global__ __launch_bounds__(256) void fill_kernel(const int* __restrict__ ei, int E,
                                                   const int* __restrict__ row_ptr, const int* __restrict__ rank,
                                                   int* __restrict__ adj) {
    int e = blockIdx.x * 256 + threadIdx.x;
    if (e < E) {
        int s = ei[e], d = ei[E + e];
        adj[row_ptr[d] + rank[e]] = s;
    }
}

// ---------------- fused encoder: out = hpack(dinv * (relu(x@W1+b1)@W2 + b2)) --
// BM=32 rows/block, 4 waves. LDS LB[8448] shorts (16896 B).

__global__ __launch_bounds__(256) void encoder_fused(const float* __restrict__ x,
                                                     const short* __restrict__ PB1h, const short* __restrict__ PB1l,
                                                     const short* __restrict__ PB2h, const short* __restrict__ PB2l,
                                                     const float* __restrict__ b1, const float* __restrict__ b2,
                                                     const float* __restrict__ dinv,
                                                     short* __restrict__ Aout, int n) {
    __shared__ short LB[8448];
    int t = threadIdx.x, lane = t & 63, wv = t >> 6;
    int lr = lane & 15, lg = lane >> 4;
    int brow = blockIdx.x * 32;
    int bcol = wv * 64;

#pragma unroll
    for (int l = 0; l < 2; l++) {
        int lin = t + l * 256;
        int r = lin >> 4, kq = (lin & 15) * 4;
        int row = brow + r;
        float4 v = (row < n) ? *(const float4*)(x + (size_t)row * FIN + kq)
                             : make_float4(0.f, 0.f, 0.f, 0.f);
        uint2 hw, lw; split2(v.x, v.y, v.z, v.w, hw, lw);
        int g = kq >> 3, i0 = kq & 7;
        *(uint2*)&LB[(g * 33 + r) * 8 + i0] = hw;
        *(uint2*)&LB[2112 + (g * 33 + r) * 8 + i0] = lw;
    }
    __syncthreads();

    f32x4 acc1[2][4] = {};
#pragma unroll
    for (int s = 0; s < 2; s++) {
        int sl = s * 4 + lg;
        bf16x8 ah[2], al[2], bh[4], bl[4];
#pragma unroll
        for (int mi = 0; mi < 2; mi++) {
            ah[mi] = *(bf16x8*)&LB[(sl * 33 + mi * 16 + lr) * 8];
            al[mi] = *(bf16x8*)&LB[2112 + (sl * 33 + mi * 16 + lr) * 8];
        }
        const short* pbh = PB1h + ((size_t)sl * 256 + bcol + lr) * 8;
        const short* pbl = PB1l + ((size_t)sl * 256 + bcol + lr) * 8;
#pragma unroll
        for (int ni = 0; ni < 4; ni++) {
            bh[ni] = *(const bf16x8*)(pbh + ni * 128);
            bl[ni] = *(const bf16x8*)(pbl + ni * 128);
        }
#pragma unroll
        for (int mi = 0; mi < 2; mi++)
#pragma unroll
            for (int ni = 0; ni < 4; ni++) {
                acc1[mi][ni] = __builtin_amdgcn_mfma_f32_16x16x32_bf16(ah[mi], bh[ni], acc1[mi][ni], 0, 0, 0);
                acc1[mi][ni] = __builtin_amdgcn_mfma_f32_16x16x32_bf16(ah[mi], bl[ni], acc1[mi][ni], 0, 0, 0);
                acc1[mi][ni] = __builtin_amdgcn_mfma_f32_16x16x32_bf16(al[mi], bh[ni], acc1[mi][ni], 0, 0, 0);
            }
    }
    __syncthreads();

#pragma unroll
    for (int ni = 0; ni < 4; ni++) {
        int col = bcol + ni * 16 + lr;
        float bv = b1[col];
#pragma unroll
        for (int mi = 0; mi < 2; mi++)
#pragma unroll
            for (int j = 0; j < 4; j++) {
                int r = mi * 16 + lg * 4 + j;
                float o = fmaxf(acc1[mi][ni][j] + bv, 0.f);
                *(__half*)&LB[r * TPAD + col] = __float2half_rn(o);
            }
    }
    __syncthreads();

    f32x4 acc2[2][4] = {};
#pragma unroll
    for (int s = 0; s < 8; s++) {
        int sl = s * 4 + lg;
        bf16x8 ah[2], al[2], bh[4], bl[4];
#pragma unroll
        for (int mi = 0; mi < 2; mi++) {
            uint4 V = *(uint4*)&LB[(mi * 16 + lr) * TPAD + sl * 8];
            h8_to_bf16pair(V, ah[mi], al[mi]);
        }
        const short* pbh = PB2h + ((size_t)sl * 256 + bcol + lr) * 8;
        const short* pbl = PB2l + ((size_t)sl * 256 + bcol + lr) * 8;
#pragma unroll
        for (int ni = 0; ni < 4; ni++) {
            bh[ni] = *(const bf16x8*)(pbh + ni * 128);
            bl[ni] = *(const bf16x8*)(pbl + ni * 128);
        }
#pragma unroll
        for (int mi = 0; mi < 2; mi++)
#pragma unroll
            for (int ni = 0; ni < 4; ni++) {
                acc2[mi][ni] = __builtin_amdgcn_mfma_f32_16x16x32_bf16(ah[mi], bh[ni], acc2[mi][ni], 0, 0, 0);
                acc2[mi][ni] = __builtin_amdgcn_mfma_f32_16x16x32_bf16(ah[mi], bl[ni], acc2[mi][ni], 0, 0, 0);
                acc2[mi][ni] = __builtin_amdgcn_mfma_f32_16x16x32_bf16(al[mi], bh[ni], acc2[mi][ni], 0, 0, 0);
            }
    }
    __syncthreads();

    float dvo[2][4];
#pragma unroll
    for (int mi = 0; mi < 2; mi++)
#pragma unroll
        for (int j = 0; j < 4; j++) {
            int row = brow + mi * 16 + lg * 4 + j;
            dvo[mi][j] = (row < n) ? dinv[row] : 0.f;
        }
#pragma unroll
    for (int ni = 0; ni < 4; ni++) {
        int col = bcol + ni * 16 + lr;
        float bv = b2[col];
#pragma unroll
        for (int mi = 0; mi < 2; mi++)
#pragma unroll
            for (int j = 0; j < 4; j++) {
                int r = mi * 16 + lg * 4 + j;
                float o = (acc2[mi][ni][j] + bv) * dvo[mi][j];
                *(__half*)&LB[r * TPAD + col] = __float2half_rn(o);
            }
    }
    __syncthreads();

#pragma unroll
    for (int q = 0; q < 4; q++) {
        int idx = t + q * 256;          // [0,1024)
        int row = idx >> 5, c = idx & 31;
        int vv = brow + row;
        if (vv < n)
            *(uint4*)(Aout + (size_t)vv * 256 + c * 8) = *(const uint4*)&LB[row * TPAD + c * 8];
    }
}

// ---------------- standalone gather: agg[v] = dinv[v] * (self + sum nbrs) ------
// One wave per dst node, no LDS, no barriers. Input prescaled by dinv.

__global__ __launch_bounds__(256) void agg_fp16(const short* __restrict__ Ain,
                                                const int* __restrict__ row_ptr, const int* __restrict__ adj,
                                                const float* __restrict__ dinv,
                                                short* __restrict__ Agg, int n) {
    int t = threadIdx.x;
    int v = blockIdx.x * 4 + (t >> 6);
    if (v >= n) return;
    int lane = t & 63;
    int loff = lane * 4;                            // fp16 col base (4 cols/lane)
    float dv = dinv[v];
    uint2 V0 = *(const uint2*)(Ain + (size_t)v * 256 + loff);
    float4 acc = make_float4(0.f, 0.f, 0.f, 0.f);
    HADD(V0);
    int e = row_ptr[v], end = row_ptr[v + 1];
    for (; e + 8 <= end; e += 8) {
        int s8[8]; uint2 V[8];
#pragma unroll
        for (int j = 0; j < 8; j++) s8[j] = adj[e + j];
#pragma unroll
        for (int j = 0; j < 8; j++) V[j] = *(const uint2*)(Ain + (size_t)s8[j] * 256 + loff);
#pragma unroll
        for (int j = 0; j < 8; j++) HADD(V[j]);
    }
    for (; e + 4 <= end; e += 4) {
        int s4[4]; uint2 V[4];
#pragma unroll
        for (int j = 0; j < 4; j++) s4[j] = adj[e + j];
#pragma unroll
        for (int j = 0; j < 4; j++) V[j] = *(const uint2*)(Ain + (size_t)s4[j] * 256 + loff);
#pragma unroll
        for (int j = 0; j < 4; j++) HADD(V[j]);
    }
    for (; e < end; e++) {
        uint2 V = *(const uint2*)(Ain + (size_t)adj[e] * 256 + loff);
        HADD(V);
    }
    __half2 q0 = __floats2half2_rn(dv * acc.x, dv * acc.y);
    __half2 q1 = __floats2half2_rn(dv * acc.z, dv * acc.w);
    uint2 pw;
    pw.x = *(unsigned*)&q0; pw.y = *(unsigned*)&q1;
    *(uint2*)(Agg + (size_t)v * 256 + loff) = pw;
}

// ---------------- transform: act = relu(agg @ Wc + bc) [*dinv] ----------------
// SCALE_OUT=true: write prescaled fp16 act to Aout.
// SCALE_OUT=false (LAST layer): act consumed only by pooling -> reduce the LDS
// tile directly (col sum/max) + one atomicAdd/atomicMax per col per block;
// NO global act write.

template<bool SCALE_OUT>
__global__ __launch_bounds__(256) void trans_mfma(const short* __restrict__ Agg,
                                                  const short* __restrict__ PBh, const short* __restrict__ PBl,
                                                  const float* __restrict__ bias, const float* __restrict__ dinv,
                                                  short* __restrict__ Aout,
                                                  float* __restrict__ pool_sum, int* __restrict__ pool_max,
                                                  int n) {
    __shared__ short LB[8448];
    int t = threadIdx.x, lane = t & 63, wv = t >> 6;
    int lr = lane & 15, lg = lane >> 4;
    int brow = blockIdx.x * 32;
    int bcol = wv * 64;

#pragma unroll
    for (int q = 0; q < 4; q++) {
        int idx = t + q * 256;          // [0,1024)
        int row = idx >> 5, c = idx & 31;
        *(uint4*)&LB[row * TPAD + c * 8] = *(const uint4*)(Agg + (size_t)(brow + row) * 256 + c * 8);
    }
    __syncthreads();

    f32x4 acc2[2][4] = {};
#pragma unroll
    for (int s = 0; s < 8; s++) {
        int sl = s * 4 + lg;
        bf16x8 ah[2], al[2], bh[4], bl[4];
#pragma unroll
        for (int mi = 0; mi < 2; mi++) {
            uint4 V = *(uint4*)&LB[(mi * 16 + lr) * TPAD + sl * 8];
            h8_to_bf16pair(V, ah[mi], al[mi]);
        }
        const short* pbh = PBh + ((size_t)sl * 256 + bcol + lr) * 8;
        const short* pbl = PBl + ((size_t)sl * 256 + bcol + lr) * 8;
#pragma unroll
        for (int ni = 0; ni < 4; ni++) {
            bh[ni] = *(const bf16x8*)(pbh + ni * 128);
            bl[ni] = *(const bf16x8*)(pbl + ni * 128);
        }
#pragma unroll
        for (int mi = 0; mi < 2; mi++)
#pragma unroll
            for (int ni = 0; ni < 4; ni++) {
                acc2[mi][ni] = __builtin_amdgcn_mfma_f32_16x16x32_bf16(ah[mi], bh[ni], acc2[mi][ni], 0, 0, 0);
                acc2[mi][ni] = __builtin_amdgcn_mfma_f32_16x16x32_bf16(ah[mi], bl[ni], acc2[mi][ni], 0, 0, 0);
                acc2[mi][ni] = __builtin_amdgcn_mfma_f32_16x16x32_bf16(al[mi], bh[ni], acc2[mi][ni], 0, 0, 0);
            }
    }
    __syncthreads();

    float dvo[2][4];
    if (SCALE_OUT) {
#pragma unroll
        for (int mi = 0; mi < 2; mi++)
#pragma unroll
            for (int j = 0; j < 4; j++) {
                int row = brow + mi * 16 + lg * 4 + j;
                dvo[mi][j] = (row < n) ? dinv[row] : 0.f;
            }
    }
#pragma unroll
    for (int ni = 0; ni < 4; ni++) {
        int col = bcol + ni * 16 + lr;
        float bv = bias[col];
#pragma unroll
        for (int mi = 0; mi < 2; mi++)
#pragma unroll
            for (int j = 0; j < 4; j++) {
                int r = mi * 16 + lg * 4 + j;
                float o = fmaxf(acc2[mi][ni][j] + bv, 0.f);
                if (SCALE_OUT) o *= dvo[mi][j];
                *(__half*)&LB[r * TPAD + col] = __float2half_rn(o);
            }
    }
    __syncthreads();

    if (SCALE_OUT) {
        // coop write-out of prescaled act
#pragma unroll
        for (int q = 0; q < 4; q++) {
            int idx = t + q * 256;          // [0,1024)
            int row = idx >> 5, c = idx & 31;
            int vv = brow + row;
            if (vv < n)
                *(uint4*)(Aout + (size_t)vv * 256 + c * 8) = *(const uint4*)&LB[row * TPAD + c * 8];
        }
    } else {
        // fused pooling: column sum/max over this block's valid rows
        int nr = min(32, n - brow);       // rows valid in this block (>0 given grid)
        float s = 0.f, mx = 0.f;
        for (int r = 0; r < nr; r++) {
            float v = __half2float(*(const __half*)&LB[r * TPAD + t]);
            s += v;
            mx = fmaxf(mx, v);
        }
        atomicAdd(&pool_sum[t], s);
        atomicMax(&pool_max[t], __float_as_int(mx));   // valid: values >= 0
    }
}

// ---------------- MLP head ----------------

__global__ __launch_bounds__(256) void head1(const float* __restrict__ pool_sum, const int* __restrict__ pool_max,
                                             const float* __restrict__ Wp1, const float* __restrict__ bp1,
                                             float* __restrict__ hid, float invn) {
    __shared__ float red[8][33];
    int t = threadIdx.x, cl = t & 31, w = t >> 5;
    int col = blockIdx.x * 32 + cl;
    float p = 0.f;
    for (int j = w * 64; j < w * 64 + 64; j++) {
        float g = (j < HID) ? pool_sum[j] * invn : __int_as_float(pool_max[j - HID]);
        p = fmaf(g, Wp1[(size_t)j * HID + col], p);
    }
    red[w][cl] = p;
    __syncthreads();
    if (w == 0) {
        float a = 0.f;
#pragma unroll
        for (int k = 0; k < 8; k++) a += red[k][cl];
        hid[col] = fmaxf(a + bp1[col], 0.f);
    }
}

__global__ __launch_bounds__(128) void head2(const float* __restrict__ hid,
                                             const float* __restrict__ Wp2, const float* __restrict__ bp2,
                                             float* __restrict__ out) {
    int t = threadIdx.x;   // 128
    float a = bp2[t];
#pragma unroll 8
    for (int j = 0; j < HID; j++) a = fmaf(hid[j], Wp2[(size_t)j * DEMB + t], a);
    out[t] = a;
}

// ---------------- launcher ----------------

extern "C" void kernel_launch(void* const* d_in, const int* in_sizes, int n_in,
                              void* d_out, int out_size, void* d_ws, size_t ws_size,
                              hipStream_t stream) {
    const float* x   = (const float*)d_in[0];
    const int*   ei  = (const int*)d_in[1];
    const float* W1  = (const float*)d_in[2];
    const float* b1  = (const float*)d_in[3];
    const float* W2  = (const float*)d_in[4];
    const float* b2  = (const float*)d_in[5];
    const float* Wc  = (const float*)d_in[6];
    const float* bc  = (const float*)d_in[7];
    const float* Wp1 = (const float*)d_in[8];
    const float* bp1 = (const float*)d_in[9];
    const float* Wp2 = (const float*)d_in[10];
    const float* bp2 = (const float*)d_in[11];
    float* out = (float*)d_out;

    int N = in_sizes[0] / FIN;
    int E = in_sizes[1] / 2;
    int nb32 = (N + 31) / 32;
    int nb4  = (N + 3) / 4;
    int R = nb32 * 32;                   // padded rows for hpack buffers

    char* base = (char*)d_ws;
    short* actA = (short*)base;                          // [R,256] fp16 hpack
    short* actB = (short*)(base + (size_t)R * 512);      // [R,256] fp16 hpack
    short* aggb = (short*)(base + 2 * (size_t)R * 512);  // [R,256] fp16 agg
    int*   counts  = (int*)(base + 3 * (size_t)R * 512); // [N]
    int*   row_ptr = counts + N;                         // [N+1]
    int*   rank    = row_ptr + (N + 1);                  // [E]
    int*   adj     = rank + E;                           // [E]
    float* dinvp   = (float*)(adj + E);                  // [N]
    float* pool_sum = dinvp + N;                         // [HID]
    int*   pool_max = (int*)(pool_sum + HID);            // [HID]
    int*   chunkSums = pool_max + HID;                   // [<=64]
    float* hidbuf  = (float*)(chunkSums + 64);           // [HID]
    short* PH = (short*)((((uintptr_t)(hidbuf + HID)) + 15) & ~(uintptr_t)15);
    short* PL = PH + 278528;
    const int oW1 = 0, oW2 = 16384, oC0 = 81920, oC1 = 147456, oC2 = 212992;

    int nch = (N + 1023) / 1024;
    int nb256 = (N + 255) / 256;
    int eb256 = (E + 255) / 256;

    zero_pack<<<nb256 + 64 + 4 * 256, 256, 0, stream>>>(counts, N, pool_sum, pool_max, nb256,
                                                        W1, W2, Wc, PH, PL);
    hist_kernel<<<eb256, 256, 0, stream>>>(ei, E, counts, rank);
    scan_partial<<<nch, 256, 0, stream>>>(counts, N, chunkSums, dinvp);
    scan_final<<<nch, 256, 0, stream>>>(counts, N, chunkSums, row_ptr);
    fill_kernel<<<eb256, 256, 0, stream>>>(ei, E, row_ptr, rank, adj);

    // fused encoder: actA = hpack(dinv * (relu(x@W1+b1)@W2 + b2))
    encoder_fused<<<nb32, 256, 0, stream>>>(x, PH + oW1, PL + oW1, PH + oW2, PL + oW2,
                                            b1, b2, dinvp, actA, N);

    // GCN layers: agg = dinv*(S'@act); act' = relu(agg@Wc+bc)[*dinv]
    agg_fp16<<<nb4, 256, 0, stream>>>(actA, row_ptr, adj, dinvp, aggb, N);
    trans_mfma<true><<<nb32, 256, 0, stream>>>(aggb, PH + oC0, PL + oC0, bc + 0 * HID, dinvp, actB,
                                               nullptr, nullptr, N);
    agg_fp16<<<nb4, 256, 0, stream>>>(actB, row_ptr, adj, dinvp, aggb, N);
    trans_mfma<true><<<nb32, 256, 0, stream>>>(aggb, PH + oC1, PL + oC1, bc + 1 * HID, dinvp, actA,
                                               nullptr, nullptr, N);
    agg_fp16<<<nb4, 256, 0, stream>>>(actA, row_ptr, adj, dinvp, aggb, N);
    // last layer: pooling fused, no act write
    trans_mfma<false><<<nb32, 256, 0, stream>>>(aggb, PH + oC2, PL + oC2, bc + 2 * HID, dinvp, nullptr,
                                                pool_sum, pool_max, N);

    // head
    head1<<<8, 256, 0, stream>>>(pool_sum, pool_max, Wp1, bp1, hidbuf, 1.0f / (float)N);
    head2<<<1, 128, 0, stream>>>(hidbuf, Wp2, bp2, out);
}

// Round 20
// 397.767 us; speedup vs baseline: 1.2953x; 1.0556x over previous
//
#include <hip/hip_runtime.h>
#include <hip/hip_fp16.h>

#define FIN 64
#define HID 256
#define DEMB 128
#define NLAYERS 3
#define TPAD 264
#define NSLOT 16

typedef __attribute__((ext_vector_type(8))) short bf16x8;
typedef __attribute__((ext_vector_type(4))) float f32x4;

__device__ inline short f2bf(float x) {               // RNE fp32 -> bf16 bits
    unsigned u = __float_as_uint(x);
    u += 0x7fff + ((u >> 16) & 1);
    return (short)(u >> 16);
}
__device__ inline float bf2f(short h) {
    return __uint_as_float(((unsigned)(unsigned short)h) << 16);
}

// Activation layout "hpack": per row r, 256 fp16 (512B contiguous), linear cols.
// Values PRE-SCALED by dinv[row] except after the last layer.

// add 4 fp16 cols (uint2) into fp32 acc
#define HADD(V) do { \
    __half2 p0 = *(__half2*)&(V).x, p1 = *(__half2*)&(V).y; \
    float2 f0 = __half22float2(p0), f1 = __half22float2(p1); \
    acc.x += f0.x; acc.y += f0.y; acc.z += f1.x; acc.w += f1.y; } while (0)

__device__ inline void split2(float a0, float a1, float a2, float a3, uint2& hw, uint2& lw) {
    short h0 = f2bf(a0), h1 = f2bf(a1), h2 = f2bf(a2), h3 = f2bf(a3);
    short l0 = f2bf(a0 - bf2f(h0)), l1 = f2bf(a1 - bf2f(h1));
    short l2 = f2bf(a2 - bf2f(h2)), l3 = f2bf(a3 - bf2f(h3));
    hw.x = (unsigned short)h0 | ((unsigned)(unsigned short)h1 << 16);
    hw.y = (unsigned short)h2 | ((unsigned)(unsigned short)h3 << 16);
    lw.x = (unsigned short)l0 | ((unsigned)(unsigned short)l1 << 16);
    lw.y = (unsigned short)l2 | ((unsigned)(unsigned short)l3 << 16);
}

// 8 fp16 (uint4) -> split-bf16 pair (ah, al), exact (fp16 subset of fp32)
__device__ inline void h8_to_bf16pair(uint4 V, bf16x8& ah, bf16x8& al) {
    const unsigned* w = (const unsigned*)&V;
    short hh[8], ll[8];
#pragma unroll
    for (int q = 0; q < 4; q++) {
        __half2 p = *(__half2*)&w[q];
        float2 f = __half22float2(p);
        short h0 = f2bf(f.x), h1 = f2bf(f.y);
        hh[2 * q] = h0; hh[2 * q + 1] = h1;
        ll[2 * q] = f2bf(f.x - bf2f(h0));
        ll[2 * q + 1] = f2bf(f.y - bf2f(h1));
    }
#pragma unroll
    for (int q = 0; q < 8; q++) { ah[q] = hh[q]; al[q] = ll[q]; }
}

// ---------------- zero + weight-pack combined ----------------

__global__ __launch_bounds__(256) void zero_pack(int* counts, int n, float* pool_sum, int* pool_max, int nzb,
                                                 const float* __restrict__ W1, const float* __restrict__ W2,
                                                 const float* __restrict__ Wc,
                                                 short* __restrict__ PH, short* __restrict__ PL) {
    if ((int)blockIdx.x < nzb) {
        int i = blockIdx.x * 256 + threadIdx.x;
        if (i < n) counts[i] = 0;
        if (i < NSLOT * HID) { pool_sum[i] = 0.0f; pool_max[i] = 0; }
        return;
    }
    int b = blockIdx.x - nzb, nn = threadIdx.x;
    const float* src; int k; size_t dst;
    if (b < 64) { src = W1; k = b; dst = 0; }
    else {
        int m = (b - 64) >> 8; k = (b - 64) & 255;
        src = (m == 0) ? W2 : (Wc + (size_t)(m - 1) * 65536);
        dst = 16384 + (size_t)m * 65536;
    }
    float w = src[(size_t)k * 256 + nn];
    short h = f2bf(w);
    short l = f2bf(w - bf2f(h));
    int o = ((k >> 3) * 256 + nn) * 8 + (k & 7);
    PH[dst + o] = h; PL[dst + o] = l;
}

// hist + per-edge rank (atomicAdd return) in one pass
__global__ __launch_bounds__(256) void hist_kernel(const int* __restrict__ ei, int E,
                                                   int* __restrict__ counts, int* __restrict__ rank) {
    int e = blockIdx.x * 256 + threadIdx.x;
    if (e < E) rank[e] = atomicAdd(&counts[ei[E + e]], 1);
}

__global__ __launch_bounds__(256) void scan_partial(const int* __restrict__ counts, int n,
                                                    int* __restrict__ chunkSums, float* __restrict__ dinv) {
    __shared__ int s[256];
    int t = threadIdx.x, base = blockIdx.x * 1024;
    int sum = 0;
#pragma unroll
    for (int j = 0; j < 4; j++) {
        int i = base + t * 4 + j;
        if (i < n) {
            int c = counts[i];
            sum += c;
            dinv[i] = rsqrtf((float)(c + 1));
        }
    }
    s[t] = sum; __syncthreads();
    for (int off = 128; off > 0; off >>= 1) { if (t < off) s[t] += s[t + off]; __syncthreads(); }
    if (t == 0) chunkSums[blockIdx.x] = s[0];
}

__global__ __launch_bounds__(256) void scan_final(const int* __restrict__ counts, int n,
                                                  const int* __restrict__ chunkSums, int* __restrict__ row_ptr) {
    __shared__ int s[256];
    __shared__ int base_s;
    int t = threadIdx.x, base = blockIdx.x * 1024;
    if (t == 0) {
        int a = 0;
        for (int i = 0; i < (int)blockIdx.x; i++) a += chunkSums[i];
        base_s = a;
    }
    int v[4]; int sum = 0;
#pragma unroll
    for (int j = 0; j < 4; j++) { int i = base + t * 4 + j; v[j] = (i < n) ? counts[i] : 0; sum += v[j]; }
    s[t] = sum; __syncthreads();
    for (int off = 1; off < 256; off <<= 1) {
        int x = (t >= off) ? s[t - off] : 0;
        __syncthreads();
        s[t] += x;
        __syncthreads();
    }
    int run = base_s + (s[t] - sum);
#pragma unroll
    for (int j = 0; j < 4; j++) {
        int i = base + t * 4 + j;
        if (i < n) {
            row_ptr[i] = run; run += v[j];
            if (i == n - 1) row_ptr[n] = run;
        }
    }
}

// atomic-free fill: position = row_ptr[dst] + rank[e]
__global__ __launch_bounds__(256) void fill_kernel(const int* __restrict__ ei, int E,
                                                   const int* __restrict__ row_ptr, const int* __restrict__ rank,
                                                   int* __restrict__ adj) {
    int e = blockIdx.x * 256 + threadIdx.x;
    if (e < E) {
        int s = ei[e], d = ei[E + e];
        adj[row_ptr[d] + rank[e]] = s;
    }
}

// ---------------- fused encoder: out = hpack(dinv * (relu(x@W1+b1)@W2 + b2)) --
// BM=32 rows/block, 4 waves. LDS LB[8448] shorts (16896 B).

__global__ __launch_bounds__(256) void encoder_fused(const float* __restrict__ x,
                                                     const short* __restrict__ PB1h, const short* __restrict__ PB1l,
                                                     const short* __restrict__ PB2h, const short* __restrict__ PB2l,
                                                     const float* __restrict__ b1, const float* __restrict__ b2,
                                                     const float* __restrict__ dinv,
                                                     short* __restrict__ Aout, int n) {
    __shared__ short LB[8448];
    int t = threadIdx.x, lane = t & 63, wv = t >> 6;
    int lr = lane & 15, lg = lane >> 4;
    int brow = blockIdx.x * 32;
    int bcol = wv * 64;

#pragma unroll
    for (int l = 0; l < 2; l++) {
        int lin = t + l * 256;
        int r = lin >> 4, kq = (lin & 15) * 4;
        int row = brow + r;
        float4 v = (row < n) ? *(const float4*)(x + (size_t)row * FIN + kq)
                             : make_float4(0.f, 0.f, 0.f, 0.f);
        uint2 hw, lw; split2(v.x, v.y, v.z, v.w, hw, lw);
        int g = kq >> 3, i0 = kq & 7;
        *(uint2*)&LB[(g * 33 + r) * 8 + i0] = hw;
        *(uint2*)&LB[2112 + (g * 33 + r) * 8 + i0] = lw;
    }
    __syncthreads();

    f32x4 acc1[2][4] = {};
#pragma unroll
    for (int s = 0; s < 2; s++) {
        int sl = s * 4 + lg;
        bf16x8 ah[2], al[2], bh[4], bl[4];
#pragma unroll
        for (int mi = 0; mi < 2; mi++) {
            ah[mi] = *(bf16x8*)&LB[(sl * 33 + mi * 16 + lr) * 8];
            al[mi] = *(bf16x8*)&LB[2112 + (sl * 33 + mi * 16 + lr) * 8];
        }
        const short* pbh = PB1h + ((size_t)sl * 256 + bcol + lr) * 8;
        const short* pbl = PB1l + ((size_t)sl * 256 + bcol + lr) * 8;
#pragma unroll
        for (int ni = 0; ni < 4; ni++) {
            bh[ni] = *(const bf16x8*)(pbh + ni * 128);
            bl[ni] = *(const bf16x8*)(pbl + ni * 128);
        }
#pragma unroll
        for (int mi = 0; mi < 2; mi++)
#pragma unroll
            for (int ni = 0; ni < 4; ni++) {
                acc1[mi][ni] = __builtin_amdgcn_mfma_f32_16x16x32_bf16(ah[mi], bh[ni], acc1[mi][ni], 0, 0, 0);
                acc1[mi][ni] = __builtin_amdgcn_mfma_f32_16x16x32_bf16(ah[mi], bl[ni], acc1[mi][ni], 0, 0, 0);
                acc1[mi][ni] = __builtin_amdgcn_mfma_f32_16x16x32_bf16(al[mi], bh[ni], acc1[mi][ni], 0, 0, 0);
            }
    }
    __syncthreads();

#pragma unroll
    for (int ni = 0; ni < 4; ni++) {
        int col = bcol + ni * 16 + lr;
        float bv = b1[col];
#pragma unroll
        for (int mi = 0; mi < 2; mi++)
#pragma unroll
            for (int j = 0; j < 4; j++) {
                int r = mi * 16 + lg * 4 + j;
                float o = fmaxf(acc1[mi][ni][j] + bv, 0.f);
                *(__half*)&LB[r * TPAD + col] = __float2half_rn(o);
            }
    }
    __syncthreads();

    f32x4 acc2[2][4] = {};
#pragma unroll
    for (int s = 0; s < 8; s++) {
        int sl = s * 4 + lg;
        bf16x8 ah[2], al[2], bh[4], bl[4];
#pragma unroll
        for (int mi = 0; mi < 2; mi++) {
            uint4 V = *(uint4*)&LB[(mi * 16 + lr) * TPAD + sl * 8];
            h8_to_bf16pair(V, ah[mi], al[mi]);
        }
        const short* pbh = PB2h + ((size_t)sl * 256 + bcol + lr) * 8;
        const short* pbl = PB2l + ((size_t)sl * 256 + bcol + lr) * 8;
#pragma unroll
        for (int ni = 0; ni < 4; ni++) {
            bh[ni] = *(const bf16x8*)(pbh + ni * 128);
            bl[ni] = *(const bf16x8*)(pbl + ni * 128);
        }
#pragma unroll
        for (int mi = 0; mi < 2; mi++)
#pragma unroll
            for (int ni = 0; ni < 4; ni++) {
                acc2[mi][ni] = __builtin_amdgcn_mfma_f32_16x16x32_bf16(ah[mi], bh[ni], acc2[mi][ni], 0, 0, 0);
                acc2[mi][ni] = __builtin_amdgcn_mfma_f32_16x16x32_bf16(ah[mi], bl[ni], acc2[mi][ni], 0, 0, 0);
                acc2[mi][ni] = __builtin_amdgcn_mfma_f32_16x16x32_bf16(al[mi], bh[ni], acc2[mi][ni], 0, 0, 0);
            }
    }
    __syncthreads();

    float dvo[2][4];
#pragma unroll
    for (int mi = 0; mi < 2; mi++)
#pragma unroll
        for (int j = 0; j < 4; j++) {
            int row = brow + mi * 16 + lg * 4 + j;
            dvo[mi][j] = (row < n) ? dinv[row] : 0.f;
        }
#pragma unroll
    for (int ni = 0; ni < 4; ni++) {
        int col = bcol + ni * 16 + lr;
        float bv = b2[col];
#pragma unroll
        for (int mi = 0; mi < 2; mi++)
#pragma unroll
            for (int j = 0; j < 4; j++) {
                int r = mi * 16 + lg * 4 + j;
                float o = (acc2[mi][ni][j] + bv) * dvo[mi][j];
                *(__half*)&LB[r * TPAD + col] = __float2half_rn(o);
            }
    }
    __syncthreads();

#pragma unroll
    for (int q = 0; q < 4; q++) {
        int idx = t + q * 256;          // [0,1024)
        int row = idx >> 5, c = idx & 31;
        int vv = brow + row;
        if (vv < n)
            *(uint4*)(Aout + (size_t)vv * 256 + c * 8) = *(const uint4*)&LB[row * TPAD + c * 8];
    }
}

// ---------------- standalone gather: agg[v] = dinv[v] * (self + sum nbrs) ------
// One wave per dst node, no LDS, no barriers. Input prescaled by dinv.

__global__ __launch_bounds__(256) void agg_fp16(const short* __restrict__ Ain,
                                                const int* __restrict__ row_ptr, const int* __restrict__ adj,
                                                const float* __restrict__ dinv,
                                                short* __restrict__ Agg, int n) {
    int t = threadIdx.x;
    int v = blockIdx.x * 4 + (t >> 6);
    if (v >= n) return;
    int lane = t & 63;
    int loff = lane * 4;                            // fp16 col base (4 cols/lane)
    float dv = dinv[v];
    uint2 V0 = *(const uint2*)(Ain + (size_t)v * 256 + loff);
    float4 acc = make_float4(0.f, 0.f, 0.f, 0.f);
    HADD(V0);
    int e = row_ptr[v], end = row_ptr[v + 1];
    for (; e + 8 <= end; e += 8) {
        int s8[8]; uint2 V[8];
#pragma unroll
        for (int j = 0; j < 8; j++) s8[j] = adj[e + j];
#pragma unroll
        for (int j = 0; j < 8; j++) V[j] = *(const uint2*)(Ain + (size_t)s8[j] * 256 + loff);
#pragma unroll
        for (int j = 0; j < 8; j++) HADD(V[j]);
    }
    for (; e + 4 <= end; e += 4) {
        int s4[4]; uint2 V[4];
#pragma unroll
        for (int j = 0; j < 4; j++) s4[j] = adj[e + j];
#pragma unroll
        for (int j = 0; j < 4; j++) V[j] = *(const uint2*)(Ain + (size_t)s4[j] * 256 + loff);
#pragma unroll
        for (int j = 0; j < 4; j++) HADD(V[j]);
    }
    for (; e < end; e++) {
        uint2 V = *(const uint2*)(Ain + (size_t)adj[e] * 256 + loff);
        HADD(V);
    }
    __half2 q0 = __floats2half2_rn(dv * acc.x, dv * acc.y);
    __half2 q1 = __floats2half2_rn(dv * acc.z, dv * acc.w);
    uint2 pw;
    pw.x = *(unsigned*)&q0; pw.y = *(unsigned*)&q1;
    *(uint2*)(Agg + (size_t)v * 256 + loff) = pw;
}

// ---------------- transform: act = relu(agg @ Wc + bc) [*dinv] ----------------
// A-frags read DIRECTLY from global aggb (L2/L3-hot, lane-group broadcast);
// LDS used only for the epilogue tile -> single barrier.
// SCALE_OUT=false (last layer): fused pooling into NSLOT-sliced accumulators.

template<bool SCALE_OUT>
__global__ __launch_bounds__(256) void trans_mfma(const short* __restrict__ Agg,
                                                  const short* __restrict__ PBh, const short* __restrict__ PBl,
                                                  const float* __restrict__ bias, const float* __restrict__ dinv,
                                                  short* __restrict__ Aout,
                                                  float* __restrict__ pool_sum, int* __restrict__ pool_max,
                                                  int n) {
    __shared__ short LB[8448];
    int t = threadIdx.x, lane = t & 63, wv = t >> 6;
    int lr = lane & 15, lg = lane >> 4;
    int brow = blockIdx.x * 32;
    int bcol = wv * 64;

    f32x4 acc2[2][4] = {};
#pragma unroll
    for (int s = 0; s < 8; s++) {
        int sl = s * 4 + lg;
        bf16x8 ah[2], al[2], bh[4], bl[4];
#pragma unroll
        for (int mi = 0; mi < 2; mi++) {
            uint4 V = *(const uint4*)(Agg + ((size_t)(brow + mi * 16 + lr) * 256 + sl * 8));
            h8_to_bf16pair(V, ah[mi], al[mi]);
        }
        const short* pbh = PBh + ((size_t)sl * 256 + bcol + lr) * 8;
        const short* pbl = PBl + ((size_t)sl * 256 + bcol + lr) * 8;
#pragma unroll
        for (int ni = 0; ni < 4; ni++) {
            bh[ni] = *(const bf16x8*)(pbh + ni * 128);
            bl[ni] = *(const bf16x8*)(pbl + ni * 128);
        }
#pragma unroll
        for (int mi = 0; mi < 2; mi++)
#pragma unroll
            for (int ni = 0; ni < 4; ni++) {
                acc2[mi][ni] = __builtin_amdgcn_mfma_f32_16x16x32_bf16(ah[mi], bh[ni], acc2[mi][ni], 0, 0, 0);
                acc2[mi][ni] = __builtin_amdgcn_mfma_f32_16x16x32_bf16(ah[mi], bl[ni], acc2[mi][ni], 0, 0, 0);
                acc2[mi][ni] = __builtin_amdgcn_mfma_f32_16x16x32_bf16(al[mi], bh[ni], acc2[mi][ni], 0, 0, 0);
            }
    }

    // epilogue: relu(acc+bias)[*dinv] -> fp16 tile in LDS
    float dvo[2][4];
    if (SCALE_OUT) {
#pragma unroll
        for (int mi = 0; mi < 2; mi++)
#pragma unroll
            for (int j = 0; j < 4; j++) {
                int row = brow + mi * 16 + lg * 4 + j;
                dvo[mi][j] = (row < n) ? dinv[row] : 0.f;
            }
    }
#pragma unroll
    for (int ni = 0; ni < 4; ni++) {
        int col = bcol + ni * 16 + lr;
        float bv = bias[col];
#pragma unroll
        for (int mi = 0; mi < 2; mi++)
#pragma unroll
            for (int j = 0; j < 4; j++) {
                int r = mi * 16 + lg * 4 + j;
                float o = fmaxf(acc2[mi][ni][j] + bv, 0.f);
                if (SCALE_OUT) o *= dvo[mi][j];
                *(__half*)&LB[r * TPAD + col] = __float2half_rn(o);
            }
    }
    __syncthreads();

    if (SCALE_OUT) {
#pragma unroll
        for (int q = 0; q < 4; q++) {
            int idx = t + q * 256;          // [0,1024)
            int row = idx >> 5, c = idx & 31;
            int vv = brow + row;
            if (vv < n)
                *(uint4*)(Aout + (size_t)vv * 256 + c * 8) = *(const uint4*)&LB[row * TPAD + c * 8];
        }
    } else {
        // fused pooling: column sum/max over this block's valid rows -> slot
        int nr = min(32, n - brow);
        float s = 0.f, mx = 0.f;
        for (int r = 0; r < nr; r++) {
            float v = __half2float(*(const __half*)&LB[r * TPAD + t]);
            s += v;
            mx = fmaxf(mx, v);
        }
        int slot = blockIdx.x & (NSLOT - 1);
        atomicAdd(&pool_sum[slot * HID + t], s);
        atomicMax(&pool_max[slot * HID + t], __float_as_int(mx));   // values >= 0
    }
}

// ---------------- MLP head ----------------
// head1: reduce NSLOT pool slices, then hid = relu(g @ Wp1 + bp1)

__global__ __launch_bounds__(256) void head1(const float* __restrict__ pool_sum, const int* __restrict__ pool_max,
                                             const float* __restrict__ Wp1, const float* __restrict__ bp1,
                                             float* __restrict__ hid, float invn) {
    __shared__ float g[2 * HID];
    __shared__ float red[8][33];
    int t = threadIdx.x, cl = t & 31, w = t >> 5;
    // slot reduction: thread t -> columns t (sum) and t (max)
    {
        float a = 0.f, m = 0.f;
#pragma unroll
        for (int k = 0; k < NSLOT; k++) {
            a += pool_sum[k * HID + t];
            m = fmaxf(m, __int_as_float(pool_max[k * HID + t]));
        }
        g[t] = a * invn;
        g[HID + t] = m;
    }
    __syncthreads();
    int col = blockIdx.x * 32 + cl;
    float p = 0.f;
    for (int j = w * 64; j < w * 64 + 64; j++)
        p = fmaf(g[j], Wp1[(size_t)j * HID + col], p);
    red[w][cl] = p;
    __syncthreads();
    if (w == 0) {
        float a = 0.f;
#pragma unroll
        for (int k = 0; k < 8; k++) a += red[k][cl];
        hid[col] = fmaxf(a + bp1[col], 0.f);
    }
}

__global__ __launch_bounds__(128) void head2(const float* __restrict__ hid,
                                             const float* __restrict__ Wp2, const float* __restrict__ bp2,
                                             float* __restrict__ out) {
    int t = threadIdx.x;   // 128
    float a = bp2[t];
#pragma unroll 8
    for (int j = 0; j < HID; j++) a = fmaf(hid[j], Wp2[(size_t)j * DEMB + t], a);
    out[t] = a;
}

// ---------------- launcher ----------------

extern "C" void kernel_launch(void* const* d_in, const int* in_sizes, int n_in,
                              void* d_out, int out_size, void* d_ws, size_t ws_size,
                              hipStream_t stream) {
    const float* x   = (const float*)d_in[0];
    const int*   ei  = (const int*)d_in[1];
    const float* W1  = (const float*)d_in[2];
    const float* b1  = (const float*)d_in[3];
    const float* W2  = (const float*)d_in[4];
    const float* b2  = (const float*)d_in[5];
    const float* Wc  = (const float*)d_in[6];
    const float* bc  = (const float*)d_in[7];
    const float* Wp1 = (const float*)d_in[8];
    const float* bp1 = (const float*)d_in[9];
    const float* Wp2 = (const float*)d_in[10];
    const float* bp2 = (const float*)d_in[11];
    float* out = (float*)d_out;

    int N = in_sizes[0] / FIN;
    int E = in_sizes[1] / 2;
    int nb32 = (N + 31) / 32;
    int nb4  = (N + 3) / 4;
    int R = nb32 * 32;                   // padded rows for hpack buffers

    char* base = (char*)d_ws;
    short* actA = (short*)base;                          // [R,256] fp16 hpack
    short* actB = (short*)(base + (size_t)R * 512);      // [R,256] fp16 hpack
    short* aggb = (short*)(base + 2 * (size_t)R * 512);  // [R,256] fp16 agg
    int*   counts  = (int*)(base + 3 * (size_t)R * 512); // [N]
    int*   row_ptr = counts + N;                         // [N+1]
    int*   rank    = row_ptr + (N + 1);                  // [E]
    int*   adj     = rank + E;                           // [E]
    float* dinvp   = (float*)(adj + E);                  // [N]
    float* pool_sum = dinvp + N;                         // [NSLOT*HID]
    int*   pool_max = (int*)(pool_sum + NSLOT * HID);    // [NSLOT*HID]
    int*   chunkSums = pool_max + NSLOT * HID;           // [<=64]
    float* hidbuf  = (float*)(chunkSums + 64);           // [HID]
    short* PH = (short*)((((uintptr_t)(hidbuf + HID)) + 15) & ~(uintptr_t)15);
    short* PL = PH + 278528;
    const int oW1 = 0, oW2 = 16384, oC0 = 81920, oC1 = 147456, oC2 = 212992;

    int nch = (N + 1023) / 1024;
    int nb256 = (N + 255) / 256;
    int eb256 = (E + 255) / 256;

    zero_pack<<<nb256 + 64 + 4 * 256, 256, 0, stream>>>(counts, N, pool_sum, pool_max, nb256,
                                                        W1, W2, Wc, PH, PL);
    hist_kernel<<<eb256, 256, 0, stream>>>(ei, E, counts, rank);
    scan_partial<<<nch, 256, 0, stream>>>(counts, N, chunkSums, dinvp);
    scan_final<<<nch, 256, 0, stream>>>(counts, N, chunkSums, row_ptr);
    fill_kernel<<<eb256, 256, 0, stream>>>(ei, E, row_ptr, rank, adj);

    // fused encoder: actA = hpack(dinv * (relu(x@W1+b1)@W2 + b2))
    encoder_fused<<<nb32, 256, 0, stream>>>(x, PH + oW1, PL + oW1, PH + oW2, PL + oW2,
                                            b1, b2, dinvp, actA, N);

    // GCN layers: agg = dinv*(S'@act); act' = relu(agg@Wc+bc)[*dinv]
    agg_fp16<<<nb4, 256, 0, stream>>>(actA, row_ptr, adj, dinvp, aggb, N);
    trans_mfma<true><<<nb32, 256, 0, stream>>>(aggb, PH + oC0, PL + oC0, bc + 0 * HID, dinvp, actB,
                                               nullptr, nullptr, N);
    agg_fp16<<<nb4, 256, 0, stream>>>(actB, row_ptr, adj, dinvp, aggb, N);
    trans_mfma<true><<<nb32, 256, 0, stream>>>(aggb, PH + oC1, PL + oC1, bc + 1 * HID, dinvp, actA,
                                               nullptr, nullptr, N);
    agg_fp16<<<nb4, 256, 0, stream>>>(actA, row_ptr, adj, dinvp, aggb, N);
    // last layer: pooling fused (slot-sliced atomics), no act write
    trans_mfma<false><<<nb32, 256, 0, stream>>>(aggb, PH + oC2, PL + oC2, bc + 2 * HID, dinvp, nullptr,
                                                pool_sum, pool_max, N);

    // head
    head1<<<8, 256, 0, stream>>>(pool_sum, pool_max, Wp1, bp1, hidbuf, 1.0f / (float)N);
    head2<<<1, 128, 0, stream>>>(hidbuf, Wp2, bp2, out);
}